// Round 2
// baseline (859.150 us; speedup 1.0000x reference)
//
#include <hip/hip_runtime.h>
#include <hip/hip_bf16.h>

// ---------------------------------------------------------------------------
// CrossGatingBlock on MI355X (gfx950).
// Inputs fp32; OUTPUT fp32 (reference returns jnp.float32; out_npz ~= 4B/elem).
// Intermediates bf16 NHWC in d_ws; fp32 accumulation in MFMA.
// d_out (33.5M fp32 = 134MB) doubles as u16 scratch for the 2C gating tensor
// (dead before the final fp32 NCHW writes).
// ---------------------------------------------------------------------------

typedef unsigned short u16;
typedef __bf16 bf16x8 __attribute__((ext_vector_type(8)));
typedef u16    u16x8  __attribute__((ext_vector_type(8)));
typedef float  f32x4  __attribute__((ext_vector_type(4)));

__device__ __forceinline__ float bf2f(u16 u) {
  union { float f; unsigned int i; } v; v.i = ((unsigned int)u) << 16; return v.f;
}
__device__ __forceinline__ u16 f2bf(float f) {   // RNE
  union { float f; unsigned int i; } v; v.f = f;
  unsigned int x = v.i;
  return (u16)((x + 0x7fffu + ((x >> 16) & 1u)) >> 16);
}
__device__ __forceinline__ f32x4 mfma16(u16x8 a, u16x8 b, f32x4 c) {
  return __builtin_amdgcn_mfma_f32_16x16x32_bf16(
      __builtin_bit_cast(bf16x8, a), __builtin_bit_cast(bf16x8, b), c, 0, 0, 0);
}
__device__ __forceinline__ float gelu_erf(float v) {
  return 0.5f * v * (1.0f + erff(v * 0.70710678118654752f));
}

// ---------------------------------------------------------------------------
// NCHW(fp32) -> NHWC(bf16).  grid (HW/64, C/32, N), block 256.
__global__ __launch_bounds__(256) void tr_k(const float* __restrict__ in,
                                            u16* __restrict__ out,
                                            const int C, const int lgHW) {
  __shared__ u16 t[32 * 72];
  const int p0 = blockIdx.x * 64, c0 = blockIdx.y * 32, n = blockIdx.z;
  const int tid = threadIdx.x;
  {
    const int c = tid >> 3, e0 = (tid & 7) * 8;
    const float* ip = in + (((n * C + c0 + c) << lgHW) + p0 + e0);
    f32x4 v0 = *(const f32x4*)ip;
    f32x4 v1 = *(const f32x4*)(ip + 4);
    u16* tp = t + c * 72 + e0;
#pragma unroll
    for (int j = 0; j < 4; ++j) { tp[j] = f2bf(v0[j]); tp[4 + j] = f2bf(v1[j]); }
  }
  __syncthreads();
  {
    const int c8 = tid & 3, p = tid >> 2;
    u16x8 v;
#pragma unroll
    for (int j = 0; j < 8; ++j) v[j] = t[(c8 * 8 + j) * 72 + p];
    *(u16x8*)(out + ((n << lgHW) + p0 + p) * C + c0 + c8 * 8) = v;
  }
}

// wt (Cy,F,2,2) fp32 -> wt2 [c][kl*128+o] fp32.  grid 512, block 256.
__global__ __launch_bounds__(256) void wtre_k(const float* __restrict__ wt,
                                              float* __restrict__ wt2) {
  const int idx = blockIdx.x * 256 + threadIdx.x;     // < 131072
  const int c = idx >> 9, r = idx & 511, o = r >> 2, kl = r & 3;
  wt2[(c << 9) + (kl << 7) + o] = wt[idx];
}

// column sums of a weight (for LN folding), on bf16-rounded values.
__global__ __launch_bounds__(256) void colsum_k(const float* __restrict__ w,
                                                const int cin, const int cout,
                                                float* __restrict__ out) {
  const int d = threadIdx.x;
  if (d < cout) {
    float s = 0.f;
    for (int c = 0; c < cin; ++c) s += bf2f(f2bf(w[c * cout + d]));
    out[d] = s;
  }
}

// per-sample sum/sumsq partials over NHWC bf16 tensor [8][2^21].
// grid 512 (= 8 samples x 64 chunks), block 256.
__global__ __launch_bounds__(256) void stats_part_k(const u16* __restrict__ x,
                                                    float* __restrict__ part) {
  const int s = blockIdx.x >> 6, ch = blockIdx.x & 63;
  const u16* p = x + ((s << 21) + (ch << 15));
  float sum = 0.f, sq = 0.f;
#pragma unroll
  for (int it = 0; it < 16; ++it) {
    u16x8 v = *(const u16x8*)(p + ((threadIdx.x + (it << 8)) << 3));
#pragma unroll
    for (int j = 0; j < 8; ++j) { float f = bf2f(v[j]); sum += f; sq += f * f; }
  }
#pragma unroll
  for (int off = 32; off > 0; off >>= 1) {
    sum += __shfl_down(sum, off); sq += __shfl_down(sq, off);
  }
  __shared__ float a1[4], a2[4];
  const int wid = threadIdx.x >> 6, lane = threadIdx.x & 63;
  if (lane == 0) { a1[wid] = sum; a2[wid] = sq; }
  __syncthreads();
  if (threadIdx.x == 0) {
    part[blockIdx.x * 2]     = a1[0] + a1[1] + a1[2] + a1[3];
    part[blockIdx.x * 2 + 1] = a2[0] + a2[1] + a2[2] + a2[3];
  }
}

// finalize: st[2s]=alpha=1/sqrt(var+eps), st[2s+1]=-mean*alpha. grid 8, block 64.
__global__ __launch_bounds__(64) void stats_fin_k(const float* __restrict__ part,
                                                  float* __restrict__ st) {
  const int s = blockIdx.x, t = threadIdx.x;
  float a = part[(s * 64 + t) * 2], b = part[(s * 64 + t) * 2 + 1];
#pragma unroll
  for (int off = 32; off > 0; off >>= 1) {
    a += __shfl_down(a, off); b += __shfl_down(b, off);
  }
  if (t == 0) {
    const float inv_n = 1.f / 2097152.f;
    const float mean = a * inv_n;
    const float var = b * inv_n - mean * mean;
    const float al = rsqrtf(var + 1e-5f);
    st[2 * s] = al; st[2 * s + 1] = -mean * al;
  }
}

// ---------------------------------------------------------------------------
// Generic token-channel GEMM: out[t][d] = EPI( sum_c A[t][c] * W[c][d] ).
// block 256 (4 waves), tile 128 tokens x 128 cols, K chunked by 64 in LDS.
// A,B fragments both staged k-minor with the SAME slot->k bijection, so the
// MFMA result is independent of the HW's exact per-lane K ordering.
// Template: CIN, LNF(LN fold), ACT(0/1 relu/2 gelu), AMUL(A=A1*A2),
//           MULST(store v*out[]), NSC shortcuts, ONCHW(0 nhwc bf16,
//           1 fp32 NCHW only, 2 both), CONVT (transposed-conv scatter).
// ---------------------------------------------------------------------------
template <int CIN, int LNF, int ACT, int AMUL, int MULST, int NSC, int ONCHW, int CONVT>
__global__ __launch_bounds__(256, 2) void gemm_k(
    const u16* __restrict__ A1, const u16* __restrict__ A2,
    const float* __restrict__ W, const int wstride,
    const float* __restrict__ bias,
    const float* __restrict__ st, const float* __restrict__ cs,
    const u16* __restrict__ sc1, const u16* __restrict__ sc2,
    u16* __restrict__ out, const int ostride, float* __restrict__ outf) {
  constexpr int KP = 72;                      // 64 + 8 pad (16B aligned rows)
  __shared__ u16 sm[2 * 128 * KP];
  u16* As = sm;
  u16* Bs = sm + 128 * KP;
  const int tid = threadIdx.x;
  const int m0 = blockIdx.x * 128;
  const int n0g = blockIdx.y * 128;
  const int wid = tid >> 6, lane = tid & 63, fr = lane & 15, fg = lane >> 4;
  const int wm = (wid >> 1) * 64, wn = (wid & 1) * 64;

  f32x4 acc[4][4] = {};

  for (int kc = 0; kc < CIN; kc += 64) {
    if (kc) __syncthreads();
    // stage A chunk: 128 rows x 64 k (NHWC: contiguous 16B loads)
#pragma unroll
    for (int it = 0; it < 4; ++it) {
      const int idx = tid + it * 256;         // < 1024
      const int m = idx >> 3, c8 = idx & 7;
      const int ga = (m0 + m) * CIN + kc + c8 * 8;
      u16x8 v = *(const u16x8*)(A1 + ga);
      if constexpr (AMUL) {
        u16x8 v2 = *(const u16x8*)(A2 + ga);
#pragma unroll
        for (int j = 0; j < 8; ++j) v[j] = f2bf(bf2f(v[j]) * bf2f(v2[j]));
      }
      *(u16x8*)(As + m * KP + c8 * 8) = v;
    }
    // stage B chunk transposed: Bs[n][k] = bf16(W[kc+k][n0g+n]) (fp32 weights)
#pragma unroll
    for (int it = 0; it < 8; ++it) {
      const int idx = tid + it * 256;         // < 2048 = 32 n4 x 64 k
      const int n4 = idx >> 6, k = idx & 63;
      f32x4 wv = *(const f32x4*)(W + (kc + k) * wstride + n0g + n4 * 4);
#pragma unroll
      for (int j = 0; j < 4; ++j) Bs[(n4 * 4 + j) * KP + k] = f2bf(wv[j]);
    }
    __syncthreads();
#pragma unroll
    for (int ks = 0; ks < 2; ++ks) {
      const int kb = ks * 32 + fg * 8;
      u16x8 a_[4], b_[4];
#pragma unroll
      for (int i = 0; i < 4; ++i) a_[i] = *(const u16x8*)(As + (wm + i * 16 + fr) * KP + kb);
#pragma unroll
      for (int j = 0; j < 4; ++j) b_[j] = *(const u16x8*)(Bs + (wn + j * 16 + fr) * KP + kb);
#pragma unroll
      for (int i = 0; i < 4; ++i)
#pragma unroll
        for (int j = 0; j < 4; ++j) acc[i][j] = mfma16(a_[i], b_[j], acc[i][j]);
    }
  }

  // epilogue. C/D layout: col = lane&15, row = (lane>>4)*4 + r (HW-verified).
  float alpha = 1.f, beta = 0.f;
  if constexpr (LNF) { const int s = m0 >> 14; alpha = st[2 * s]; beta = st[2 * s + 1]; }
#pragma unroll
  for (int i = 0; i < 4; ++i) {
#pragma unroll
    for (int j = 0; j < 4; ++j) {
      const int col = wn + j * 16 + fr;
      const int dd = n0g + col;
      const float bz = bias[CONVT ? col : dd];
      float csv = 0.f;
      if constexpr (LNF) csv = cs[dd];
      f32x4 vv;
#pragma unroll
      for (int r = 0; r < 4; ++r) {
        const int m = wm + i * 16 + fg * 4 + r;
        const int token = m0 + m;
        float v = acc[i][j][r];
        if constexpr (LNF) v = v * alpha + beta * csv;
        v += bz;
        if constexpr (ACT == 1) v = fmaxf(v, 0.f);
        if constexpr (ACT == 2) v = gelu_erf(v);
        if constexpr (NSC >= 1) v += bf2f(sc1[token * 128 + dd]);
        if constexpr (NSC >= 2) v += bf2f(sc2[token * 128 + dd]);
        if constexpr (MULST) v *= bf2f(out[token * ostride + dd]);
        vv[r] = v;
        if constexpr (CONVT) {
          const int ns = token >> 12, hy = (token >> 6) & 63, wy = token & 63;
          const int kl = blockIdx.y;
          const int opix = ((ns * 128 + 2 * hy + (kl >> 1)) << 7) + 2 * wy + (kl & 1);
          out[opix * 128 + col] = f2bf(v);
        } else if constexpr (ONCHW != 1) {
          out[token * ostride + dd] = f2bf(v);
        }
      }
      if constexpr (ONCHW >= 1) {               // direct fp32 NCHW store (x4)
        const int token0 = m0 + wm + i * 16 + fg * 4;
        const int ns = token0 >> 14;
        *(f32x4*)(outf + (((size_t)(ns * 128 + dd)) << 14) + (token0 & 16383)) = vv;
      }
    }
  }
}

// ---------------------------------------------------------------------------
// Spatial gating MLPs on NHWC 't' [131072][256].
// MODE 0 (grid): out[.,c,d,p2] = sum_g u[.,c,g,p2] w[g,d] + b[d], channels 0:128
// MODE 1 (block): out[.,c,g,d] = sum_p v[.,c,g,p] w[p,d] + b[d], channels 128:256
// One HIP block per (sample, p2-or-g). block 512 (8 waves), M=256(d) N=128(c),
// K=256 chunked by 64.
// ---------------------------------------------------------------------------
template <int MODE>
__global__ __launch_bounds__(512, 2) void mlp_k(const u16* __restrict__ tin,
                                                const float* __restrict__ w,
                                                const float* __restrict__ b,
                                                u16* __restrict__ uvout) {
  constexpr int KP = 72;
  __shared__ u16 sm[(256 + 128) * KP];
  u16* Ws = sm;                 // [256 d][KP]
  u16* Vs = sm + 256 * KP;      // [128 c][KP]
  const int q2 = blockIdx.x, ns = blockIdx.y;
  const int tid = threadIdx.x;
  constexpr int coff = MODE ? 128 : 0;
  const int wid = tid >> 6, lane = tid & 63, fr = lane & 15, fg = lane >> 4;
  const int wm = (wid >> 1) * 64, wn = (wid & 1) * 64;

  int pbase, prow, pcol;
  if constexpr (MODE == 0) {    // grid cells: q=(gh*16+gw), fixed p2=(ph*8+pw)
    pbase = ns * 16384 + (q2 >> 3) * 128 + (q2 & 7);
    prow = 8 * 128; pcol = 8;
  } else {                      // block g fixed, q = (ph*16+pw)
    pbase = ns * 16384 + (q2 >> 3) * 16 * 128 + (q2 & 7) * 16;
    prow = 128; pcol = 1;
  }
  auto pix = [&](int q) { return pbase + (q >> 4) * prow + (q & 15) * pcol; };

  f32x4 acc[4][4] = {};

  for (int kc = 0; kc < 256; kc += 64) {
    if (kc) __syncthreads();
    // Ws[d][k] = bf16(w[(kc+k)][d])  (transpose of fp32 weight)
#pragma unroll
    for (int it = 0; it < 8; ++it) {
      const int idx = tid + it * 512;     // < 4096 = 64 d4 x 64 k
      const int d4 = idx >> 6, k = idx & 63;
      f32x4 wv = *(const f32x4*)(w + (kc + k) * 256 + d4 * 4);
#pragma unroll
      for (int j = 0; j < 4; ++j) Ws[(d4 * 4 + j) * KP + k] = f2bf(wv[j]);
    }
    // Vs[c][k] = tin[pix(kc+k)][coff+c]   (transpose-stage)
#pragma unroll
    for (int it = 0; it < 2; ++it) {
      const int idx = tid + it * 512;     // < 1024 = 16 c8 x 64 k
      const int c8 = idx >> 6, k = idx & 63;
      u16x8 tv = *(const u16x8*)(tin + pix(kc + k) * 256 + coff + c8 * 8);
#pragma unroll
      for (int j = 0; j < 8; ++j) Vs[(c8 * 8 + j) * KP + k] = tv[j];
    }
    __syncthreads();
#pragma unroll
    for (int ks = 0; ks < 2; ++ks) {
      const int kb = ks * 32 + fg * 8;
      u16x8 a_[4], b_[4];
#pragma unroll
      for (int i = 0; i < 4; ++i) a_[i] = *(const u16x8*)(Ws + (wm + i * 16 + fr) * KP + kb);
#pragma unroll
      for (int j = 0; j < 4; ++j) b_[j] = *(const u16x8*)(Vs + (wn + j * 16 + fr) * KP + kb);
#pragma unroll
      for (int i = 0; i < 4; ++i)
#pragma unroll
        for (int j = 0; j < 4; ++j) acc[i][j] = mfma16(a_[i], b_[j], acc[i][j]);
    }
  }
#pragma unroll
  for (int i = 0; i < 4; ++i) {
#pragma unroll
    for (int j = 0; j < 4; ++j) {
      const int c = wn + j * 16 + fr;
#pragma unroll
      for (int r = 0; r < 4; ++r) {
        const int d = wm + i * 16 + fg * 4 + r;
        uvout[pix(d) * 256 + coff + c] = f2bf(acc[i][j][r] + b[d]);
      }
    }
  }
}

// ---------------------------------------------------------------------------
extern "C" void kernel_launch(void* const* d_in, const int* in_sizes, int n_in,
                              void* d_out, int out_size, void* d_ws, size_t ws_size,
                              hipStream_t stream) {
  (void)in_sizes; (void)n_in; (void)out_size; (void)ws_size;
  // inputs (fp32), setup_inputs order
  const float* xf   = (const float*)d_in[0];
  const float* yf   = (const float*)d_in[1];
  const float* wtf  = (const float*)d_in[2];
  const float* btf  = (const float*)d_in[3];
  const float* wc1f = (const float*)d_in[4];
  const float* bc1f = (const float*)d_in[5];
  const float* wc2f = (const float*)d_in[6];
  const float* bc2f = (const float*)d_in[7];
  const float* wl1f = (const float*)d_in[8];
  const float* bl1f = (const float*)d_in[9];
  const float* wl2f = (const float*)d_in[10];
  const float* bl2f = (const float*)d_in[11];
  const float* wl3f = (const float*)d_in[12];
  const float* bl3f = (const float*)d_in[13];
  const float* wl4f = (const float*)d_in[14];
  const float* bl4f = (const float*)d_in[15];
  const float* g1w1 = (const float*)d_in[16];
  const float* g1b1 = (const float*)d_in[17];
  const float* g1w2 = (const float*)d_in[18];
  const float* g1b2 = (const float*)d_in[19];
  const float* g1w3 = (const float*)d_in[20];
  const float* g1b3 = (const float*)d_in[21];
  const float* g1w4 = (const float*)d_in[22];
  const float* g1b4 = (const float*)d_in[23];
  const float* g2w1 = (const float*)d_in[24];
  const float* g2b1 = (const float*)d_in[25];
  const float* g2w2 = (const float*)d_in[26];
  const float* g2b2 = (const float*)d_in[27];
  const float* g2w3 = (const float*)d_in[28];
  const float* g2b3 = (const float*)d_in[29];
  const float* g2w4 = (const float*)d_in[30];
  const float* g2b4 = (const float*)d_in[31];

  constexpr int T16 = 16777216;   // one NCHW/NHWC big tensor, elems
  u16* WS  = (u16*)d_ws;
  u16* x0b = WS;                  // shortcut_x (relu conv1x1) NHWC
  u16* x1b = WS + (size_t)T16;    // gelu(LN(x0)@wl1)
  u16* y0b = WS + (size_t)2 * T16;
  u16* y1b = WS + (size_t)3 * T16; // later: y1*gx in place
  u16* gyb = WS + (size_t)4 * T16;
  u16* uvb = WS + (size_t)5 * T16; // 2*T16: MLP out; early aliases xh/yh; late yout NHWC
  u16* xh  = uvb;                  // x NHWC (early)
  u16* yh  = uvb + (size_t)T16;    // y NHWC (early, 8.4M)
  u16* youtH = uvb;                // y_out NHWC (late)
  float* fb   = (float*)(WS + (size_t)7 * T16);
  float* cs0  = fb;                // colsum wl1 [256]
  float* cs1  = fb + 256;          // wl2
  float* cs2  = fb + 512;          // g1_w1
  float* cs3  = fb + 768;          // g2_w1
  float* st   = fb + 1024;         // 4 slots x 8 samples x {alpha,beta}
  float* part = fb + 1024 + 64;    // 512 x float2
  float* wt2  = fb + 1024 + 64 + 1024; // reordered ConvT weight [256][512]

  u16* tb    = (u16*)d_out;        // u16 scratch: yup, then gating tensor t
  float* outx = (float*)d_out;                 // final x NCHW fp32
  float* outy = (float*)d_out + (size_t)T16;   // final y NCHW fp32

  const dim3 B256(256), B512(512), B64(64);

  // 1) layout transforms + weight prep
  tr_k<<<dim3(256, 4, 8), B256, 0, stream>>>(xf, xh, 128, 14);
  tr_k<<<dim3(64, 8, 8),  B256, 0, stream>>>(yf, yh, 256, 12);
  wtre_k<<<dim3(512), B256, 0, stream>>>(wtf, wt2);
  colsum_k<<<dim3(1), B256, 0, stream>>>(wl1f, 128, 128, cs0);
  colsum_k<<<dim3(1), B256, 0, stream>>>(wl2f, 128, 128, cs1);
  colsum_k<<<dim3(1), B256, 0, stream>>>(g1w1, 128, 256, cs2);
  colsum_k<<<dim3(1), B256, 0, stream>>>(g2w1, 128, 256, cs3);

  // 2) ConvT(k=2,s=2)+bt+relu -> yup (tb[0:T16], NHWC)
  gemm_k<256, 0, 1, 0, 0, 0, 0, 1><<<dim3(256, 4), B256, 0, stream>>>(
      yh, nullptr, wt2, 512, btf, nullptr, nullptr, nullptr, nullptr, tb, 128, nullptr);
  // 3) x0 = relu(xh@wc1+bc1); y0 = relu(yup@wc2+bc2)
  gemm_k<128, 0, 1, 0, 0, 0, 0, 0><<<dim3(1024, 1), B256, 0, stream>>>(
      xh, nullptr, wc1f, 128, bc1f, nullptr, nullptr, nullptr, nullptr, x0b, 128, nullptr);
  gemm_k<128, 0, 1, 0, 0, 0, 0, 0><<<dim3(1024, 1), B256, 0, stream>>>(
      tb, nullptr, wc2f, 128, bc2f, nullptr, nullptr, nullptr, nullptr, y0b, 128, nullptr);

  // 4) y branch: y1 = gelu(LN(y0)@wl2+bl2)
  stats_part_k<<<dim3(512), B256, 0, stream>>>(y0b, part);
  stats_fin_k<<<dim3(8), B64, 0, stream>>>(part, st + 0);
  gemm_k<128, 1, 2, 0, 0, 0, 0, 0><<<dim3(1024, 1), B256, 0, stream>>>(
      y0b, nullptr, wl2f, 128, bl2f, st + 0, cs1, nullptr, nullptr, y1b, 128, nullptr);
  // 5) y gating (g2): t = gelu(LN(y1)@g2_w1+g2_b1) (2C wide, in d_out scratch)
  stats_part_k<<<dim3(512), B256, 0, stream>>>(y1b, part);
  stats_fin_k<<<dim3(8), B64, 0, stream>>>(part, st + 16);
  gemm_k<128, 1, 2, 0, 0, 0, 0, 0><<<dim3(1024, 2), B256, 0, stream>>>(
      y1b, nullptr, g2w1, 256, g2b1, st + 16, cs3, nullptr, nullptr, tb, 256, nullptr);
  mlp_k<0><<<dim3(64, 8), B512, 0, stream>>>(tb, g2w2, g2b2, uvb);
  mlp_k<1><<<dim3(64, 8), B512, 0, stream>>>(tb, g2w3, g2b3, uvb);
  gemm_k<256, 0, 0, 0, 0, 0, 0, 0><<<dim3(1024, 1), B256, 0, stream>>>(
      uvb, nullptr, g2w4, 128, g2b4, nullptr, nullptr, nullptr, nullptr, gyb, 128, nullptr);

  // 6) x branch: x1 = gelu(LN(x0)@wl1+bl1)
  stats_part_k<<<dim3(512), B256, 0, stream>>>(x0b, part);
  stats_fin_k<<<dim3(8), B64, 0, stream>>>(part, st + 32);
  gemm_k<128, 1, 2, 0, 0, 0, 0, 0><<<dim3(1024, 1), B256, 0, stream>>>(
      x0b, nullptr, wl1f, 128, bl1f, st + 32, cs0, nullptr, nullptr, x1b, 128, nullptr);
  // 7) x gating (g1)
  stats_part_k<<<dim3(512), B256, 0, stream>>>(x1b, part);
  stats_fin_k<<<dim3(8), B64, 0, stream>>>(part, st + 48);
  gemm_k<128, 1, 2, 0, 0, 0, 0, 0><<<dim3(1024, 2), B256, 0, stream>>>(
      x1b, nullptr, g1w1, 256, g1b1, st + 48, cs2, nullptr, nullptr, tb, 256, nullptr);
  mlp_k<0><<<dim3(64, 8), B512, 0, stream>>>(tb, g1w2, g1b2, uvb);
  mlp_k<1><<<dim3(64, 8), B512, 0, stream>>>(tb, g1w3, g1b3, uvb);
  // 8) y1 <- (uv@g1_w4 + g1_b4) * y1   (gx applied in place; gx never stored)
  gemm_k<256, 0, 0, 0, 1, 0, 0, 0><<<dim3(1024, 1), B256, 0, stream>>>(
      uvb, nullptr, g1w4, 128, g1b4, nullptr, nullptr, nullptr, nullptr, y1b, 128, nullptr);

  // 9) y_out = (y1*gx)@wl3 + bl3 + y0 -> NHWC (youtH) + fp32 NCHW (outy)
  gemm_k<128, 0, 0, 0, 0, 1, 2, 0><<<dim3(1024, 1), B256, 0, stream>>>(
      y1b, nullptr, wl3f, 128, bl3f, nullptr, nullptr, y0b, nullptr, youtH, 128, outy);
  // 10) x_out = (x1*gy)@wl4 + bl4 + y_out + x0 -> fp32 NCHW (outx)
  gemm_k<128, 0, 0, 1, 0, 2, 1, 0><<<dim3(1024, 1), B256, 0, stream>>>(
      x1b, gyb, wl4f, 128, bl4f, nullptr, nullptr, youtH, x0b, youtH, 128, outx);
}

// Round 3
// 827.109 us; speedup vs baseline: 1.0387x; 1.0387x over previous
//
#include <hip/hip_runtime.h>
#include <hip/hip_bf16.h>

// ---------------------------------------------------------------------------
// CrossGatingBlock on MI355X (gfx950).  Round 3.
// Inputs fp32; OUTPUT fp32 NCHW.  Intermediates bf16 NHWC in d_ws.
// gemm_k v2: B(weights) staged to LDS once for full K; A fragments loaded
// DIRECTLY from global (NHWC k-minor = contiguous 16B per lane) -> no
// A-staging, no K-loop barriers.  LN stats fused into producer epilogues
// via per-block reduce + float atomicAdd; consumers derive alpha/beta.
// d_out doubles as u16 scratch for yup + the 2C gating tensor.
// ---------------------------------------------------------------------------

typedef unsigned short u16;
typedef __bf16 bf16x8 __attribute__((ext_vector_type(8)));
typedef u16    u16x8  __attribute__((ext_vector_type(8)));
typedef float  f32x4  __attribute__((ext_vector_type(4)));

__device__ __forceinline__ float bf2f(u16 u) {
  union { float f; unsigned int i; } v; v.i = ((unsigned int)u) << 16; return v.f;
}
__device__ __forceinline__ u16 f2bf(float f) {   // RNE
  union { float f; unsigned int i; } v; v.f = f;
  unsigned int x = v.i;
  return (u16)((x + 0x7fffu + ((x >> 16) & 1u)) >> 16);
}
__device__ __forceinline__ f32x4 mfma16(u16x8 a, u16x8 b, f32x4 c) {
  return __builtin_amdgcn_mfma_f32_16x16x32_bf16(
      __builtin_bit_cast(bf16x8, a), __builtin_bit_cast(bf16x8, b), c, 0, 0, 0);
}
__device__ __forceinline__ float gelu_erf(float v) {
  return 0.5f * v * (1.0f + erff(v * 0.70710678118654752f));
}

// ---------------------------------------------------------------------------
// NCHW(fp32) -> NHWC(bf16).  grid (HW/64, C/32, N), block 256.
__global__ __launch_bounds__(256) void tr_k(const float* __restrict__ in,
                                            u16* __restrict__ out,
                                            const int C, const int lgHW) {
  __shared__ u16 t[32 * 72];
  const int p0 = blockIdx.x * 64, c0 = blockIdx.y * 32, n = blockIdx.z;
  const int tid = threadIdx.x;
  {
    const int c = tid >> 3, e0 = (tid & 7) * 8;
    const float* ip = in + (((n * C + c0 + c) << lgHW) + p0 + e0);
    f32x4 v0 = *(const f32x4*)ip;
    f32x4 v1 = *(const f32x4*)(ip + 4);
    u16* tp = t + c * 72 + e0;
#pragma unroll
    for (int j = 0; j < 4; ++j) { tp[j] = f2bf(v0[j]); tp[4 + j] = f2bf(v1[j]); }
  }
  __syncthreads();
  {
    const int c8 = tid & 3, p = tid >> 2;
    u16x8 v;
#pragma unroll
    for (int j = 0; j < 8; ++j) v[j] = t[(c8 * 8 + j) * 72 + p];
    *(u16x8*)(out + ((n << lgHW) + p0 + p) * C + c0 + c8 * 8) = v;
  }
}

// wt (Cy,F,2,2) fp32 -> wt2 [c][kl*128+o] fp32.  grid 512, block 256.
__global__ __launch_bounds__(256) void wtre_k(const float* __restrict__ wt,
                                              float* __restrict__ wt2) {
  const int idx = blockIdx.x * 256 + threadIdx.x;     // < 131072
  const int c = idx >> 9, r = idx & 511, o = r >> 2, kl = r & 3;
  wt2[(c << 9) + (kl << 7) + o] = wt[idx];
}

// column sums of 4 weights (LN folding), on bf16-rounded values. grid 4.
__global__ __launch_bounds__(256) void colsum4_k(const float* __restrict__ w0,
                                                 const float* __restrict__ w1,
                                                 const float* __restrict__ w2,
                                                 const float* __restrict__ w3,
                                                 float* __restrict__ out) {
  const float* w = blockIdx.x == 0 ? w0 : blockIdx.x == 1 ? w1
                 : blockIdx.x == 2 ? w2 : w3;
  const int cout = blockIdx.x < 2 ? 128 : 256;
  const int d = threadIdx.x;
  if (d < cout) {
    float s = 0.f;
    for (int c = 0; c < 128; ++c) s += bf2f(f2bf(w[c * cout + d]));
    out[blockIdx.x * 256 + d] = s;
  }
}

// zero the 4 stats-accumulator slots (8 samples x {sum,sumsq} each).
__global__ __launch_bounds__(64) void zero_k(float* __restrict__ p) {
  p[threadIdx.x] = 0.f;
}

// ---------------------------------------------------------------------------
// Token-channel GEMM v2: out[t][d] = EPI( sum_c A[t][c] * W[c][d] ).
// block 256 (4 waves), tile 128 tokens x 128 cols.  B staged to LDS once
// (full K, bf16, padded rows); A fragments loaded directly from global.
// A,B fragment k-slots use the SAME (fg,slot)->k bijection -> layout-safe.
// LNF: alpha/beta derived from fused-stats slot.  STATS: epilogue reduce ->
// atomicAdd into pso[2*sample +{0,1}].
// ---------------------------------------------------------------------------
template <int CIN, int LNF, int ACT, int AMUL, int MULST, int NSC, int ONCHW,
          int CONVT, int STATS>
__global__ __launch_bounds__(256, 2) void gemm_k(
    const u16* __restrict__ A1, const u16* __restrict__ A2,
    const float* __restrict__ W, const int wstride,
    const float* __restrict__ bias,
    const float* __restrict__ pst, const float* __restrict__ cs,
    const u16* __restrict__ sc1, const u16* __restrict__ sc2,
    u16* __restrict__ out, const int ostride, float* __restrict__ outf,
    float* __restrict__ pso) {
  constexpr int KPB = CIN + 8;                // u16 row pitch (16B-aligned)
  __shared__ u16 Bs[128 * KPB];
  __shared__ float red[8];
  const int tid = threadIdx.x;
  const int m0 = blockIdx.x * 128;
  const int n0g = blockIdx.y * 128;
  const int wid = tid >> 6, lane = tid & 63, fr = lane & 15, fg = lane >> 4;
  const int wm = (wid >> 1) * 64, wn = (wid & 1) * 64;

  // stage B once: Bs[n][k] = bf16(W[k][n0g+n])
#pragma unroll
  for (int it = 0; it < CIN / 8; ++it) {
    const int idx = tid + it * 256;           // < 32 * CIN
    const int n4 = idx / CIN, k = idx % CIN;
    f32x4 wv = *(const f32x4*)(W + k * wstride + n0g + n4 * 4);
#pragma unroll
    for (int j = 0; j < 4; ++j) Bs[(n4 * 4 + j) * KPB + k] = f2bf(wv[j]);
  }
  __syncthreads();

  f32x4 acc[4][4] = {};
  const u16* Arow = A1 + (size_t)(m0 + wm + fr) * CIN;
  const u16* Arow2 = AMUL ? A2 + (size_t)(m0 + wm + fr) * CIN : nullptr;

#pragma unroll
  for (int ks = 0; ks < CIN / 32; ++ks) {
    const int kb = ks * 32 + fg * 8;
    u16x8 a_[4], b_[4];
#pragma unroll
    for (int i = 0; i < 4; ++i) {
      a_[i] = *(const u16x8*)(Arow + i * 16 * CIN + kb);
      if constexpr (AMUL) {
        u16x8 v2 = *(const u16x8*)(Arow2 + i * 16 * CIN + kb);
#pragma unroll
        for (int j = 0; j < 8; ++j) a_[i][j] = f2bf(bf2f(a_[i][j]) * bf2f(v2[j]));
      }
    }
#pragma unroll
    for (int j = 0; j < 4; ++j) b_[j] = *(const u16x8*)(Bs + (wn + j * 16 + fr) * KPB + kb);
#pragma unroll
    for (int i = 0; i < 4; ++i)
#pragma unroll
      for (int j = 0; j < 4; ++j) acc[i][j] = mfma16(a_[i], b_[j], acc[i][j]);
  }

  // epilogue. C/D layout: col = lane&15, row = (lane>>4)*4 + r (HW-verified).
  float alpha = 1.f, beta = 0.f;
  if constexpr (LNF) {
    const int s = m0 >> 14;
    const float inv_n = 1.f / 2097152.f;
    const float mean = pst[2 * s] * inv_n;
    const float var = pst[2 * s + 1] * inv_n - mean * mean;
    alpha = rsqrtf(var + 1e-5f);
    beta = -mean * alpha;
  }
  float s1 = 0.f, s2 = 0.f;
#pragma unroll
  for (int i = 0; i < 4; ++i) {
#pragma unroll
    for (int j = 0; j < 4; ++j) {
      const int col = wn + j * 16 + fr;
      const int dd = n0g + col;
      const float bz = bias[CONVT ? col : dd];
      float csv = 0.f;
      if constexpr (LNF) csv = cs[dd];
      f32x4 vv;
#pragma unroll
      for (int r = 0; r < 4; ++r) {
        const int m = wm + i * 16 + fg * 4 + r;
        const int token = m0 + m;
        float v = acc[i][j][r];
        if constexpr (LNF) v = v * alpha + beta * csv;
        v += bz;
        if constexpr (ACT == 1) v = fmaxf(v, 0.f);
        if constexpr (ACT == 2) v = gelu_erf(v);
        if constexpr (NSC >= 1) v += bf2f(sc1[token * 128 + dd]);
        if constexpr (NSC >= 2) v += bf2f(sc2[token * 128 + dd]);
        if constexpr (MULST) v *= bf2f(out[token * ostride + dd]);
        if constexpr (STATS) { s1 += v; s2 += v * v; }
        vv[r] = v;
        if constexpr (CONVT) {
          const int ns = token >> 12, hy = (token >> 6) & 63, wy = token & 63;
          const int kl = blockIdx.y;
          const int opix = ((ns * 128 + 2 * hy + (kl >> 1)) << 7) + 2 * wy + (kl & 1);
          out[opix * 128 + col] = f2bf(v);
        } else if constexpr (ONCHW != 1) {
          out[token * ostride + dd] = f2bf(v);
        }
      }
      if constexpr (ONCHW >= 1) {               // direct fp32 NCHW store (x4)
        const int token0 = m0 + wm + i * 16 + fg * 4;
        const int ns = token0 >> 14;
        *(f32x4*)(outf + (((size_t)(ns * 128 + dd)) << 14) + (token0 & 16383)) = vv;
      }
    }
  }
  if constexpr (STATS) {
#pragma unroll
    for (int off = 32; off > 0; off >>= 1) {
      s1 += __shfl_down(s1, off); s2 += __shfl_down(s2, off);
    }
    if (lane == 0) { red[wid] = s1; red[4 + wid] = s2; }
    __syncthreads();
    const int s = m0 >> 14;
    if (tid == 0)  atomicAdd(&pso[2 * s],     red[0] + red[1] + red[2] + red[3]);
    if (tid == 64) atomicAdd(&pso[2 * s + 1], red[4] + red[5] + red[6] + red[7]);
  }
}

// ---------------------------------------------------------------------------
// Spatial gating MLPs on NHWC 't' [131072][256].
// MODE 0 (grid): mixes gh*gw grid positions, channels 0:128
// MODE 1 (block): mixes fh*fw in-block positions, channels 128:256
// ---------------------------------------------------------------------------
template <int MODE>
__global__ __launch_bounds__(512, 2) void mlp_k(const u16* __restrict__ tin,
                                                const float* __restrict__ w,
                                                const float* __restrict__ b,
                                                u16* __restrict__ uvout) {
  constexpr int KP = 72;
  __shared__ u16 sm[(256 + 128) * KP];
  u16* Ws = sm;                 // [256 d][KP]
  u16* Vs = sm + 256 * KP;      // [128 c][KP]
  const int q2 = blockIdx.x, ns = blockIdx.y;
  const int tid = threadIdx.x;
  constexpr int coff = MODE ? 128 : 0;
  const int wid = tid >> 6, lane = tid & 63, fr = lane & 15, fg = lane >> 4;
  const int wm = (wid >> 1) * 64, wn = (wid & 1) * 64;

  int pbase, prow, pcol;
  if constexpr (MODE == 0) {    // grid cells: q=(gh*16+gw), fixed p2=(ph*8+pw)
    pbase = ns * 16384 + (q2 >> 3) * 128 + (q2 & 7);
    prow = 8 * 128; pcol = 8;
  } else {                      // block g fixed, q = (ph*16+pw)
    pbase = ns * 16384 + (q2 >> 3) * 16 * 128 + (q2 & 7) * 16;
    prow = 128; pcol = 1;
  }
  auto pix = [&](int q) { return pbase + (q >> 4) * prow + (q & 15) * pcol; };

  f32x4 acc[4][4] = {};

  for (int kc = 0; kc < 256; kc += 64) {
    if (kc) __syncthreads();
    // Ws[d][k] = bf16(w[(kc+k)][d])  (transpose of fp32 weight)
#pragma unroll
    for (int it = 0; it < 8; ++it) {
      const int idx = tid + it * 512;     // < 4096 = 64 d4 x 64 k
      const int d4 = idx >> 6, k = idx & 63;
      f32x4 wv = *(const f32x4*)(w + (kc + k) * 256 + d4 * 4);
#pragma unroll
      for (int j = 0; j < 4; ++j) Ws[(d4 * 4 + j) * KP + k] = f2bf(wv[j]);
    }
    // Vs[c][k] = tin[pix(kc+k)][coff+c]   (transpose-stage)
#pragma unroll
    for (int it = 0; it < 2; ++it) {
      const int idx = tid + it * 512;     // < 1024 = 16 c8 x 64 k
      const int c8 = idx >> 6, k = idx & 63;
      u16x8 tv = *(const u16x8*)(tin + pix(kc + k) * 256 + coff + c8 * 8);
#pragma unroll
      for (int j = 0; j < 8; ++j) Vs[(c8 * 8 + j) * KP + k] = tv[j];
    }
    __syncthreads();
#pragma unroll
    for (int ks = 0; ks < 2; ++ks) {
      const int kb = ks * 32 + fg * 8;
      u16x8 a_[4], b_[4];
#pragma unroll
      for (int i = 0; i < 4; ++i) a_[i] = *(const u16x8*)(Ws + (wm + i * 16 + fr) * KP + kb);
#pragma unroll
      for (int j = 0; j < 4; ++j) b_[j] = *(const u16x8*)(Vs + (wn + j * 16 + fr) * KP + kb);
#pragma unroll
      for (int i = 0; i < 4; ++i)
#pragma unroll
        for (int j = 0; j < 4; ++j) acc[i][j] = mfma16(a_[i], b_[j], acc[i][j]);
    }
  }
#pragma unroll
  for (int i = 0; i < 4; ++i) {
#pragma unroll
    for (int j = 0; j < 4; ++j) {
      const int c = wn + j * 16 + fr;
#pragma unroll
      for (int r = 0; r < 4; ++r) {
        const int d = wm + i * 16 + fg * 4 + r;
        uvout[pix(d) * 256 + coff + c] = f2bf(acc[i][j][r] + b[d]);
      }
    }
  }
}

// ---------------------------------------------------------------------------
extern "C" void kernel_launch(void* const* d_in, const int* in_sizes, int n_in,
                              void* d_out, int out_size, void* d_ws, size_t ws_size,
                              hipStream_t stream) {
  (void)in_sizes; (void)n_in; (void)out_size; (void)ws_size;
  const float* xf   = (const float*)d_in[0];
  const float* yf   = (const float*)d_in[1];
  const float* wtf  = (const float*)d_in[2];
  const float* btf  = (const float*)d_in[3];
  const float* wc1f = (const float*)d_in[4];
  const float* bc1f = (const float*)d_in[5];
  const float* wc2f = (const float*)d_in[6];
  const float* bc2f = (const float*)d_in[7];
  const float* wl1f = (const float*)d_in[8];
  const float* bl1f = (const float*)d_in[9];
  const float* wl2f = (const float*)d_in[10];
  const float* bl2f = (const float*)d_in[11];
  const float* wl3f = (const float*)d_in[12];
  const float* bl3f = (const float*)d_in[13];
  const float* wl4f = (const float*)d_in[14];
  const float* bl4f = (const float*)d_in[15];
  const float* g1w1 = (const float*)d_in[16];
  const float* g1b1 = (const float*)d_in[17];
  const float* g1w2 = (const float*)d_in[18];
  const float* g1b2 = (const float*)d_in[19];
  const float* g1w3 = (const float*)d_in[20];
  const float* g1b3 = (const float*)d_in[21];
  const float* g1w4 = (const float*)d_in[22];
  const float* g1b4 = (const float*)d_in[23];
  const float* g2w1 = (const float*)d_in[24];
  const float* g2b1 = (const float*)d_in[25];
  const float* g2w2 = (const float*)d_in[26];
  const float* g2b2 = (const float*)d_in[27];
  const float* g2w3 = (const float*)d_in[28];
  const float* g2b3 = (const float*)d_in[29];
  const float* g2w4 = (const float*)d_in[30];
  const float* g2b4 = (const float*)d_in[31];

  constexpr int T16 = 16777216;   // one NCHW/NHWC big tensor, elems
  u16* WS  = (u16*)d_ws;
  u16* x0b = WS;                  // shortcut_x (relu conv1x1) NHWC
  u16* x1b = WS + (size_t)T16;    // gelu(LN(x0)@wl1)
  u16* y0b = WS + (size_t)2 * T16;
  u16* y1b = WS + (size_t)3 * T16; // later: y1*gx in place
  u16* gyb = WS + (size_t)4 * T16;
  u16* uvb = WS + (size_t)5 * T16; // 2*T16: MLP out; early aliases xh/yh; late yout NHWC
  u16* xh  = uvb;                  // x NHWC (early)
  u16* yh  = uvb + (size_t)T16;    // y NHWC (early, 8.4M)
  u16* youtH = uvb;                // y_out NHWC (late)
  float* fb   = (float*)(WS + (size_t)7 * T16);
  float* cs   = fb;                // colsums: [0]=wl1 [256]=wl2 [512]=g1w1 [768]=g2w1
  float* ps   = fb + 1024;         // 4 stats slots x 16 floats (sum,sumsq per sample)
  float* wt2  = fb + 1024 + 64;    // reordered ConvT weight [256][512]
  float* ps0 = ps, *ps1 = ps + 16, *ps2 = ps + 32, *ps3 = ps + 48;

  u16* tb    = (u16*)d_out;        // u16 scratch: yup, then gating tensor t
  float* outx = (float*)d_out;                 // final x NCHW fp32
  float* outy = (float*)d_out + (size_t)T16;   // final y NCHW fp32

  const dim3 B256(256), B512(512), B64(64);

  // 1) layout transforms + weight prep + stats-slot zeroing
  tr_k<<<dim3(256, 4, 8), B256, 0, stream>>>(xf, xh, 128, 14);
  tr_k<<<dim3(64, 8, 8),  B256, 0, stream>>>(yf, yh, 256, 12);
  wtre_k<<<dim3(512), B256, 0, stream>>>(wtf, wt2);
  colsum4_k<<<dim3(4), B256, 0, stream>>>(wl1f, wl2f, g1w1, g2w1, cs);
  zero_k<<<dim3(1), B64, 0, stream>>>(ps);

  // 2) ConvT(k=2,s=2)+bt+relu -> yup (tb[0:T16], NHWC)
  gemm_k<256, 0, 1, 0, 0, 0, 0, 1, 0><<<dim3(256, 4), B256, 0, stream>>>(
      yh, nullptr, wt2, 512, btf, nullptr, nullptr, nullptr, nullptr, tb, 128, nullptr, nullptr);
  // 3) x0 = relu(xh@wc1+bc1) [stats->ps0]; y0 = relu(yup@wc2+bc2) [stats->ps1]
  gemm_k<128, 0, 1, 0, 0, 0, 0, 0, 1><<<dim3(1024, 1), B256, 0, stream>>>(
      xh, nullptr, wc1f, 128, bc1f, nullptr, nullptr, nullptr, nullptr, x0b, 128, nullptr, ps0);
  gemm_k<128, 0, 1, 0, 0, 0, 0, 0, 1><<<dim3(1024, 1), B256, 0, stream>>>(
      tb, nullptr, wc2f, 128, bc2f, nullptr, nullptr, nullptr, nullptr, y0b, 128, nullptr, ps1);

  // 4) y1 = gelu(LN(y0)@wl2+bl2) [stats->ps3]
  gemm_k<128, 1, 2, 0, 0, 0, 0, 0, 1><<<dim3(1024, 1), B256, 0, stream>>>(
      y0b, nullptr, wl2f, 128, bl2f, ps1, cs + 256, nullptr, nullptr, y1b, 128, nullptr, ps3);
  // 5) y gating (g2): t = gelu(LN(y1)@g2_w1+g2_b1) (2C wide, d_out scratch)
  gemm_k<128, 1, 2, 0, 0, 0, 0, 0, 0><<<dim3(1024, 2), B256, 0, stream>>>(
      y1b, nullptr, g2w1, 256, g2b1, ps3, cs + 768, nullptr, nullptr, tb, 256, nullptr, nullptr);
  mlp_k<0><<<dim3(64, 8), B512, 0, stream>>>(tb, g2w2, g2b2, uvb);
  mlp_k<1><<<dim3(64, 8), B512, 0, stream>>>(tb, g2w3, g2b3, uvb);
  gemm_k<256, 0, 0, 0, 0, 0, 0, 0, 0><<<dim3(1024, 1), B256, 0, stream>>>(
      uvb, nullptr, g2w4, 128, g2b4, nullptr, nullptr, nullptr, nullptr, gyb, 128, nullptr, nullptr);

  // 6) x1 = gelu(LN(x0)@wl1+bl1) [stats->ps2]
  gemm_k<128, 1, 2, 0, 0, 0, 0, 0, 1><<<dim3(1024, 1), B256, 0, stream>>>(
      x0b, nullptr, wl1f, 128, bl1f, ps0, cs, nullptr, nullptr, x1b, 128, nullptr, ps2);
  // 7) x gating (g1)
  gemm_k<128, 1, 2, 0, 0, 0, 0, 0, 0><<<dim3(1024, 2), B256, 0, stream>>>(
      x1b, nullptr, g1w1, 256, g1b1, ps2, cs + 512, nullptr, nullptr, tb, 256, nullptr, nullptr);
  mlp_k<0><<<dim3(64, 8), B512, 0, stream>>>(tb, g1w2, g1b2, uvb);
  mlp_k<1><<<dim3(64, 8), B512, 0, stream>>>(tb, g1w3, g1b3, uvb);
  // 8) y1 <- (uv@g1_w4 + g1_b4) * y1   (gx applied in place)
  gemm_k<256, 0, 0, 0, 1, 0, 0, 0, 0><<<dim3(1024, 1), B256, 0, stream>>>(
      uvb, nullptr, g1w4, 128, g1b4, nullptr, nullptr, nullptr, nullptr, y1b, 128, nullptr, nullptr);

  // 9) y_out = (y1*gx)@wl3 + bl3 + y0 -> NHWC (youtH) + fp32 NCHW (outy)
  gemm_k<128, 0, 0, 0, 0, 1, 2, 0, 0><<<dim3(1024, 1), B256, 0, stream>>>(
      y1b, nullptr, wl3f, 128, bl3f, nullptr, nullptr, y0b, nullptr, youtH, 128, outy, nullptr);
  // 10) x_out = (x1*gy)@wl4 + bl4 + y_out + x0 -> fp32 NCHW (outx)
  gemm_k<128, 0, 0, 1, 0, 2, 1, 0, 0><<<dim3(1024, 1), B256, 0, stream>>>(
      x1b, gyb, wl4f, 128, bl4f, nullptr, nullptr, youtH, x0b, youtH, 128, outx, nullptr);
}

// Round 4
// 754.084 us; speedup vs baseline: 1.1393x; 1.0968x over previous
//
#include <hip/hip_runtime.h>
#include <hip/hip_bf16.h>

// ---------------------------------------------------------------------------
// CrossGatingBlock on MI355X (gfx950).  Round 4.
// Key change vs r3: SWAPPED MFMA orientation (result row=channel, col=token)
// so each lane holds 4 consecutive channels of one token -> all NHWC
// epilogue traffic is vectorized (u16x4 / f32x4).  Steps 9+10 merged into
// dual_k (y_out kept in fp32 registers; youtH round-trip eliminated; NCHW
// fp32 stores are 64B-coalesced scalar stores).
// ---------------------------------------------------------------------------

typedef unsigned short u16;
typedef __bf16 bf16x8 __attribute__((ext_vector_type(8)));
typedef u16    u16x8  __attribute__((ext_vector_type(8)));
typedef u16    u16x4  __attribute__((ext_vector_type(4)));
typedef float  f32x4  __attribute__((ext_vector_type(4)));

__device__ __forceinline__ float bf2f(u16 u) {
  union { float f; unsigned int i; } v; v.i = ((unsigned int)u) << 16; return v.f;
}
__device__ __forceinline__ u16 f2bf(float f) {   // RNE
  union { float f; unsigned int i; } v; v.f = f;
  unsigned int x = v.i;
  return (u16)((x + 0x7fffu + ((x >> 16) & 1u)) >> 16);
}
__device__ __forceinline__ f32x4 mfma16(u16x8 a, u16x8 b, f32x4 c) {
  return __builtin_amdgcn_mfma_f32_16x16x32_bf16(
      __builtin_bit_cast(bf16x8, a), __builtin_bit_cast(bf16x8, b), c, 0, 0, 0);
}
__device__ __forceinline__ float gelu_erf(float v) {
  return 0.5f * v * (1.0f + erff(v * 0.70710678118654752f));
}

// ---------------------------------------------------------------------------
// NCHW(fp32) -> NHWC(bf16).  grid (HW/64, C/32, N), block 256.
__global__ __launch_bounds__(256) void tr_k(const float* __restrict__ in,
                                            u16* __restrict__ out,
                                            const int C, const int lgHW) {
  __shared__ u16 t[32 * 72];
  const int p0 = blockIdx.x * 64, c0 = blockIdx.y * 32, n = blockIdx.z;
  const int tid = threadIdx.x;
  {
    const int c = tid >> 3, e0 = (tid & 7) * 8;
    const float* ip = in + (((n * C + c0 + c) << lgHW) + p0 + e0);
    f32x4 v0 = *(const f32x4*)ip;
    f32x4 v1 = *(const f32x4*)(ip + 4);
    u16* tp = t + c * 72 + e0;
#pragma unroll
    for (int j = 0; j < 4; ++j) { tp[j] = f2bf(v0[j]); tp[4 + j] = f2bf(v1[j]); }
  }
  __syncthreads();
  {
    const int c8 = tid & 3, p = tid >> 2;
    u16x8 v;
#pragma unroll
    for (int j = 0; j < 8; ++j) v[j] = t[(c8 * 8 + j) * 72 + p];
    *(u16x8*)(out + ((n << lgHW) + p0 + p) * C + c0 + c8 * 8) = v;
  }
}

// wt (Cy,F,2,2) fp32 -> wt2 [c][kl*128+o] fp32.  grid 512, block 256.
__global__ __launch_bounds__(256) void wtre_k(const float* __restrict__ wt,
                                              float* __restrict__ wt2) {
  const int idx = blockIdx.x * 256 + threadIdx.x;     // < 131072
  const int c = idx >> 9, r = idx & 511, o = r >> 2, kl = r & 3;
  wt2[(c << 9) + (kl << 7) + o] = wt[idx];
}

// column sums of 4 weights (LN folding), on bf16-rounded values. grid 4.
__global__ __launch_bounds__(256) void colsum4_k(const float* __restrict__ w0,
                                                 const float* __restrict__ w1,
                                                 const float* __restrict__ w2,
                                                 const float* __restrict__ w3,
                                                 float* __restrict__ out) {
  const float* w = blockIdx.x == 0 ? w0 : blockIdx.x == 1 ? w1
                 : blockIdx.x == 2 ? w2 : w3;
  const int cout = blockIdx.x < 2 ? 128 : 256;
  const int d = threadIdx.x;
  if (d < cout) {
    float s = 0.f;
    for (int c = 0; c < 128; ++c) s += bf2f(f2bf(w[c * cout + d]));
    out[blockIdx.x * 256 + d] = s;
  }
}

// zero the 4 stats-accumulator slots (8 samples x {sum,sumsq} each).
__global__ __launch_bounds__(64) void zero_k(float* __restrict__ p) {
  p[threadIdx.x] = 0.f;
}

// ---------------------------------------------------------------------------
// Token-channel GEMM v3 (swapped orientation): out[t][d]=EPI(sum_c A[t][c]W[c][d])
// Result fragment: row = channel (fg*4+r), col = token (fr)  -> each lane
// holds 4 CONSECUTIVE CHANNELS of one token: all NHWC traffic is u16x4.
// B staged once to LDS (full K); A fragments direct 16B global loads with
// 1-deep prefetch.  STATS: fused LN-stats atomicAdd.  LNF: consume stats.
// ---------------------------------------------------------------------------
template <int CIN, int LNF, int ACT, int AMUL, int MULST, int CONVT, int STATS>
__global__ __launch_bounds__(256, 3) void gemm3_k(
    const u16* __restrict__ A1, const u16* __restrict__ A2,
    const float* __restrict__ W, const int wstride,
    const float* __restrict__ bias,
    const float* __restrict__ pst, const float* __restrict__ cs,
    u16* __restrict__ out, const int ostride,
    float* __restrict__ pso) {
  constexpr int KPB = CIN + 8;
  __shared__ u16 Bs[128 * KPB];
  __shared__ float red[8];
  const int tid = threadIdx.x;
  const int m0 = blockIdx.x * 128;
  const int n0g = blockIdx.y * 128;
  const int wid = tid >> 6, lane = tid & 63, fr = lane & 15, fg = lane >> 4;
  const int wmt = (wid & 1) * 64;     // wave token offset
  const int wnc = (wid >> 1) * 64;    // wave channel offset

  // stage B once: Bs[n][k] = bf16(W[k][n0g+n])
#pragma unroll
  for (int it = 0; it < CIN / 8; ++it) {
    const int idx = tid + it * 256;           // < 32 * CIN
    const int n4 = idx / CIN, k = idx % CIN;
    f32x4 wv = *(const f32x4*)(W + k * wstride + n0g + n4 * 4);
#pragma unroll
    for (int j = 0; j < 4; ++j) Bs[(n4 * 4 + j) * KPB + k] = f2bf(wv[j]);
  }
  __syncthreads();

  f32x4 acc[4][4] = {};
  const u16* Arow = A1 + (size_t)(m0 + wmt + fr) * CIN;
  const u16* Arow2 = AMUL ? A2 + (size_t)(m0 + wmt + fr) * CIN : nullptr;

  auto lda = [&](u16x8* a, int ks) {
    const int kb = ks * 32 + fg * 8;
#pragma unroll
    for (int i = 0; i < 4; ++i) {
      a[i] = *(const u16x8*)(Arow + i * 16 * CIN + kb);
      if constexpr (AMUL) {
        u16x8 v2 = *(const u16x8*)(Arow2 + i * 16 * CIN + kb);
#pragma unroll
        for (int j = 0; j < 8; ++j) a[i][j] = f2bf(bf2f(a[i][j]) * bf2f(v2[j]));
      }
    }
  };

  u16x8 a_[4], an[4];
  lda(a_, 0);
#pragma unroll
  for (int ks = 0; ks < CIN / 32; ++ks) {
    if (ks + 1 < CIN / 32) lda(an, ks + 1);
    const int kb = ks * 32 + fg * 8;
    u16x8 b_[4];
#pragma unroll
    for (int j = 0; j < 4; ++j) b_[j] = *(const u16x8*)(Bs + (wnc + j * 16 + fr) * KPB + kb);
#pragma unroll
    for (int i = 0; i < 4; ++i)
#pragma unroll
      for (int j = 0; j < 4; ++j) acc[i][j] = mfma16(b_[j], a_[i], acc[i][j]);
#pragma unroll
    for (int i = 0; i < 4; ++i) a_[i] = an[i];
  }

  // epilogue: lane holds channels ch0..ch0+3 of token (swapped C/D layout)
  float alpha = 1.f, beta = 0.f;
  if constexpr (LNF) {
    const int s = m0 >> 14;
    const float inv_n = 1.f / 2097152.f;
    const float mean = pst[2 * s] * inv_n;
    const float var = pst[2 * s + 1] * inv_n - mean * mean;
    alpha = rsqrtf(var + 1e-5f);
    beta = -mean * alpha;
  }
  float s1 = 0.f, s2 = 0.f;
#pragma unroll
  for (int i = 0; i < 4; ++i) {
    const int token = m0 + wmt + i * 16 + fr;
#pragma unroll
    for (int j = 0; j < 4; ++j) {
      const int ch0 = wnc + j * 16 + fg * 4;
      const int dd0 = n0g + ch0;
      const f32x4 bz = *(const f32x4*)(bias + (CONVT ? ch0 : dd0));
      f32x4 v = acc[i][j];
      if constexpr (LNF) {
        const f32x4 csv = *(const f32x4*)(cs + dd0);
#pragma unroll
        for (int r = 0; r < 4; ++r) v[r] = v[r] * alpha + beta * csv[r];
      }
      v += bz;
      if constexpr (ACT == 1) {
#pragma unroll
        for (int r = 0; r < 4; ++r) v[r] = fmaxf(v[r], 0.f);
      }
      if constexpr (ACT == 2) {
#pragma unroll
        for (int r = 0; r < 4; ++r) v[r] = gelu_erf(v[r]);
      }
      if constexpr (MULST) {
        u16x4 mv = *(const u16x4*)(out + (size_t)token * ostride + dd0);
#pragma unroll
        for (int r = 0; r < 4; ++r) v[r] *= bf2f(mv[r]);
      }
      if constexpr (STATS) {
#pragma unroll
        for (int r = 0; r < 4; ++r) { s1 += v[r]; s2 += v[r] * v[r]; }
      }
      u16x4 sv;
#pragma unroll
      for (int r = 0; r < 4; ++r) sv[r] = f2bf(v[r]);
      if constexpr (CONVT) {
        const int ns = token >> 12, hy = (token >> 6) & 63, wy = token & 63;
        const int kl = blockIdx.y;
        const int opix = ((ns * 128 + 2 * hy + (kl >> 1)) << 7) + 2 * wy + (kl & 1);
        *(u16x4*)(out + (size_t)opix * 128 + ch0) = sv;
      } else {
        *(u16x4*)(out + (size_t)token * ostride + dd0) = sv;
      }
    }
  }
  if constexpr (STATS) {
#pragma unroll
    for (int off = 32; off > 0; off >>= 1) {
      s1 += __shfl_down(s1, off); s2 += __shfl_down(s2, off);
    }
    if (lane == 0) { red[wid] = s1; red[4 + wid] = s2; }
    __syncthreads();
    const int s = m0 >> 14;
    if (tid == 0)  atomicAdd(&pso[2 * s],     red[0] + red[1] + red[2] + red[3]);
    if (tid == 64) atomicAdd(&pso[2 * s + 1], red[4] + red[5] + red[6] + red[7]);
  }
}

// ---------------------------------------------------------------------------
// dual_k: fused final two GEMMs.
//   y_out = (y1*gx)@w3 + b3 + y0      -> outy fp32 NCHW
//   x_out = (x1*gy)@w4 + b4 + y_out + x0 -> outx fp32 NCHW
// Two sequential K-loops sharing one Bs buffer; y_out kept in fp32 regs.
// Swapped orientation; NCHW stores are scalar f32 (16 lanes = 64B line).
// ---------------------------------------------------------------------------
__global__ __launch_bounds__(256, 2) void dual_k(
    const u16* __restrict__ y1g, const u16* __restrict__ x1,
    const u16* __restrict__ gy,
    const float* __restrict__ w3, const float* __restrict__ w4,
    const float* __restrict__ b3, const float* __restrict__ b4,
    const u16* __restrict__ y0, const u16* __restrict__ x0,
    float* __restrict__ outy, float* __restrict__ outx) {
  constexpr int KPB = 136;
  __shared__ u16 Bs[128 * KPB];
  const int tid = threadIdx.x;
  const int m0 = blockIdx.x * 128;
  const int wid = tid >> 6, lane = tid & 63, fr = lane & 15, fg = lane >> 4;
  const int wmt = (wid & 1) * 64, wnc = (wid >> 1) * 64;

  auto stageB = [&](const float* Wp) {
#pragma unroll
    for (int it = 0; it < 16; ++it) {
      const int idx = tid + it * 256;
      const int n4 = idx >> 7, k = idx & 127;
      f32x4 wv = *(const f32x4*)(Wp + k * 128 + n4 * 4);
#pragma unroll
      for (int j = 0; j < 4; ++j) Bs[(n4 * 4 + j) * KPB + k] = f2bf(wv[j]);
    }
  };

  f32x4 acc[4][4] = {};
  f32x4 v9[4][4];

  // ---- pass 1: acc = y1g @ w3
  stageB(w3);
  __syncthreads();
  {
    const u16* Arow = y1g + (size_t)(m0 + wmt + fr) * 128;
#pragma unroll
    for (int ks = 0; ks < 4; ++ks) {
      const int kb = ks * 32 + fg * 8;
      u16x8 a_[4], b_[4];
#pragma unroll
      for (int i = 0; i < 4; ++i) a_[i] = *(const u16x8*)(Arow + i * 16 * 128 + kb);
#pragma unroll
      for (int j = 0; j < 4; ++j) b_[j] = *(const u16x8*)(Bs + (wnc + j * 16 + fr) * KPB + kb);
#pragma unroll
      for (int i = 0; i < 4; ++i)
#pragma unroll
        for (int j = 0; j < 4; ++j) acc[i][j] = mfma16(b_[j], a_[i], acc[i][j]);
    }
  }
  // epilogue 9: v9 = acc + b3 + y0 ; store outy NCHW fp32
#pragma unroll
  for (int i = 0; i < 4; ++i) {
    const int token = m0 + wmt + i * 16 + fr;
    const int ns = token >> 14, p = token & 16383;
#pragma unroll
    for (int j = 0; j < 4; ++j) {
      const int ch0 = wnc + j * 16 + fg * 4;
      const f32x4 bz = *(const f32x4*)(b3 + ch0);
      const u16x4 sc = *(const u16x4*)(y0 + (size_t)token * 128 + ch0);
      f32x4 v = acc[i][j];
#pragma unroll
      for (int r = 0; r < 4; ++r) {
        v[r] += bz[r] + bf2f(sc[r]);
        outy[((size_t)(ns * 128 + ch0 + r) << 14) + p] = v[r];
      }
      v9[i][j] = v;
      acc[i][j] = f32x4{0.f, 0.f, 0.f, 0.f};
    }
  }
  __syncthreads();              // all pass-1 ds_reads done before restage
  stageB(w4);
  __syncthreads();
  // ---- pass 2: acc = (x1*gy) @ w4
  {
    const u16* Arow = x1 + (size_t)(m0 + wmt + fr) * 128;
    const u16* Arow2 = gy + (size_t)(m0 + wmt + fr) * 128;
#pragma unroll
    for (int ks = 0; ks < 4; ++ks) {
      const int kb = ks * 32 + fg * 8;
      u16x8 a_[4], b_[4];
#pragma unroll
      for (int i = 0; i < 4; ++i) {
        a_[i] = *(const u16x8*)(Arow + i * 16 * 128 + kb);
        u16x8 v2 = *(const u16x8*)(Arow2 + i * 16 * 128 + kb);
#pragma unroll
        for (int j = 0; j < 8; ++j) a_[i][j] = f2bf(bf2f(a_[i][j]) * bf2f(v2[j]));
      }
#pragma unroll
      for (int j = 0; j < 4; ++j) b_[j] = *(const u16x8*)(Bs + (wnc + j * 16 + fr) * KPB + kb);
#pragma unroll
      for (int i = 0; i < 4; ++i)
#pragma unroll
        for (int j = 0; j < 4; ++j) acc[i][j] = mfma16(b_[j], a_[i], acc[i][j]);
    }
  }
  // epilogue 10: x_out = acc + b4 + v9 + x0 -> outx NCHW fp32
#pragma unroll
  for (int i = 0; i < 4; ++i) {
    const int token = m0 + wmt + i * 16 + fr;
    const int ns = token >> 14, p = token & 16383;
#pragma unroll
    for (int j = 0; j < 4; ++j) {
      const int ch0 = wnc + j * 16 + fg * 4;
      const f32x4 bz = *(const f32x4*)(b4 + ch0);
      const u16x4 sc = *(const u16x4*)(x0 + (size_t)token * 128 + ch0);
      f32x4 v = acc[i][j];
#pragma unroll
      for (int r = 0; r < 4; ++r) {
        v[r] += bz[r] + v9[i][j][r] + bf2f(sc[r]);
        outx[((size_t)(ns * 128 + ch0 + r) << 14) + p] = v[r];
      }
    }
  }
}

// ---------------------------------------------------------------------------
// Spatial gating MLPs on NHWC 't' [131072][256].  (unchanged this round)
// ---------------------------------------------------------------------------
template <int MODE>
__global__ __launch_bounds__(512, 2) void mlp_k(const u16* __restrict__ tin,
                                                const float* __restrict__ w,
                                                const float* __restrict__ b,
                                                u16* __restrict__ uvout) {
  constexpr int KP = 72;
  __shared__ u16 sm[(256 + 128) * KP];
  u16* Ws = sm;                 // [256 d][KP]
  u16* Vs = sm + 256 * KP;      // [128 c][KP]
  const int q2 = blockIdx.x, ns = blockIdx.y;
  const int tid = threadIdx.x;
  constexpr int coff = MODE ? 128 : 0;
  const int wid = tid >> 6, lane = tid & 63, fr = lane & 15, fg = lane >> 4;
  const int wm = (wid >> 1) * 64, wn = (wid & 1) * 64;

  int pbase, prow, pcol;
  if constexpr (MODE == 0) {    // grid cells: q=(gh*16+gw), fixed p2=(ph*8+pw)
    pbase = ns * 16384 + (q2 >> 3) * 128 + (q2 & 7);
    prow = 8 * 128; pcol = 8;
  } else {                      // block g fixed, q = (ph*16+pw)
    pbase = ns * 16384 + (q2 >> 3) * 16 * 128 + (q2 & 7) * 16;
    prow = 128; pcol = 1;
  }
  auto pix = [&](int q) { return pbase + (q >> 4) * prow + (q & 15) * pcol; };

  f32x4 acc[4][4] = {};

  for (int kc = 0; kc < 256; kc += 64) {
    if (kc) __syncthreads();
#pragma unroll
    for (int it = 0; it < 8; ++it) {
      const int idx = tid + it * 512;     // < 4096 = 64 d4 x 64 k
      const int d4 = idx >> 6, k = idx & 63;
      f32x4 wv = *(const f32x4*)(w + (kc + k) * 256 + d4 * 4);
#pragma unroll
      for (int j = 0; j < 4; ++j) Ws[(d4 * 4 + j) * KP + k] = f2bf(wv[j]);
    }
#pragma unroll
    for (int it = 0; it < 2; ++it) {
      const int idx = tid + it * 512;     // < 1024 = 16 c8 x 64 k
      const int c8 = idx >> 6, k = idx & 63;
      u16x8 tv = *(const u16x8*)(tin + pix(kc + k) * 256 + coff + c8 * 8);
#pragma unroll
      for (int j = 0; j < 8; ++j) Vs[(c8 * 8 + j) * KP + k] = tv[j];
    }
    __syncthreads();
#pragma unroll
    for (int ks = 0; ks < 2; ++ks) {
      const int kb = ks * 32 + fg * 8;
      u16x8 a_[4], b_[4];
#pragma unroll
      for (int i = 0; i < 4; ++i) a_[i] = *(const u16x8*)(Ws + (wm + i * 16 + fr) * KP + kb);
#pragma unroll
      for (int j = 0; j < 4; ++j) b_[j] = *(const u16x8*)(Vs + (wn + j * 16 + fr) * KP + kb);
#pragma unroll
      for (int i = 0; i < 4; ++i)
#pragma unroll
        for (int j = 0; j < 4; ++j) acc[i][j] = mfma16(a_[i], b_[j], acc[i][j]);
    }
  }
#pragma unroll
  for (int i = 0; i < 4; ++i) {
#pragma unroll
    for (int j = 0; j < 4; ++j) {
      const int c = wn + j * 16 + fr;
#pragma unroll
      for (int r = 0; r < 4; ++r) {
        const int d = wm + i * 16 + fg * 4 + r;
        uvout[pix(d) * 256 + coff + c] = f2bf(acc[i][j][r] + b[d]);
      }
    }
  }
}

// ---------------------------------------------------------------------------
extern "C" void kernel_launch(void* const* d_in, const int* in_sizes, int n_in,
                              void* d_out, int out_size, void* d_ws, size_t ws_size,
                              hipStream_t stream) {
  (void)in_sizes; (void)n_in; (void)out_size; (void)ws_size;
  const float* xf   = (const float*)d_in[0];
  const float* yf   = (const float*)d_in[1];
  const float* wtf  = (const float*)d_in[2];
  const float* btf  = (const float*)d_in[3];
  const float* wc1f = (const float*)d_in[4];
  const float* bc1f = (const float*)d_in[5];
  const float* wc2f = (const float*)d_in[6];
  const float* bc2f = (const float*)d_in[7];
  const float* wl1f = (const float*)d_in[8];
  const float* bl1f = (const float*)d_in[9];
  const float* wl2f = (const float*)d_in[10];
  const float* bl2f = (const float*)d_in[11];
  const float* wl3f = (const float*)d_in[12];
  const float* bl3f = (const float*)d_in[13];
  const float* wl4f = (const float*)d_in[14];
  const float* bl4f = (const float*)d_in[15];
  const float* g1w1 = (const float*)d_in[16];
  const float* g1b1 = (const float*)d_in[17];
  const float* g1w2 = (const float*)d_in[18];
  const float* g1b2 = (const float*)d_in[19];
  const float* g1w3 = (const float*)d_in[20];
  const float* g1b3 = (const float*)d_in[21];
  const float* g1w4 = (const float*)d_in[22];
  const float* g1b4 = (const float*)d_in[23];
  const float* g2w1 = (const float*)d_in[24];
  const float* g2b1 = (const float*)d_in[25];
  const float* g2w2 = (const float*)d_in[26];
  const float* g2b2 = (const float*)d_in[27];
  const float* g2w3 = (const float*)d_in[28];
  const float* g2b3 = (const float*)d_in[29];
  const float* g2w4 = (const float*)d_in[30];
  const float* g2b4 = (const float*)d_in[31];

  constexpr int T16 = 16777216;   // one NCHW/NHWC big tensor, elems
  u16* WS  = (u16*)d_ws;
  u16* x0b = WS;                  // shortcut_x (relu conv1x1) NHWC
  u16* x1b = WS + (size_t)T16;    // gelu(LN(x0)@wl1)
  u16* y0b = WS + (size_t)2 * T16;
  u16* y1b = WS + (size_t)3 * T16; // later: y1*gx in place
  u16* gyb = WS + (size_t)4 * T16;
  u16* uvb = WS + (size_t)5 * T16; // 2*T16: MLP out; early aliases xh/yh
  u16* xh  = uvb;                  // x NHWC (early)
  u16* yh  = uvb + (size_t)T16;    // y NHWC (early)
  float* fb   = (float*)(WS + (size_t)7 * T16);
  float* cs   = fb;                // colsums: [0]=wl1 [256]=wl2 [512]=g1w1 [768]=g2w1
  float* ps   = fb + 1024;         // 4 stats slots x 16 floats
  float* wt2  = fb + 1024 + 64;    // reordered ConvT weight [256][512]
  float* ps0 = ps, *ps1 = ps + 16, *ps2 = ps + 32, *ps3 = ps + 48;

  u16* tb    = (u16*)d_out;        // u16 scratch: yup, then gating tensor t
  float* outx = (float*)d_out;                 // final x NCHW fp32
  float* outy = (float*)d_out + (size_t)T16;   // final y NCHW fp32

  const dim3 B256(256), B512(512), B64(64);

  // 1) layout transforms + weight prep + stats-slot zeroing
  tr_k<<<dim3(256, 4, 8), B256, 0, stream>>>(xf, xh, 128, 14);
  tr_k<<<dim3(64, 8, 8),  B256, 0, stream>>>(yf, yh, 256, 12);
  wtre_k<<<dim3(512), B256, 0, stream>>>(wtf, wt2);
  colsum4_k<<<dim3(4), B256, 0, stream>>>(wl1f, wl2f, g1w1, g2w1, cs);
  zero_k<<<dim3(1), B64, 0, stream>>>(ps);

  // 2) ConvT(k=2,s=2)+bt+relu -> yup (tb[0:T16], NHWC)
  gemm3_k<256, 0, 1, 0, 0, 1, 0><<<dim3(256, 4), B256, 0, stream>>>(
      yh, nullptr, wt2, 512, btf, nullptr, nullptr, tb, 128, nullptr);
  // 3) x0 = relu(xh@wc1+bc1) [stats->ps0]; y0 = relu(yup@wc2+bc2) [stats->ps1]
  gemm3_k<128, 0, 1, 0, 0, 0, 1><<<dim3(1024, 1), B256, 0, stream>>>(
      xh, nullptr, wc1f, 128, bc1f, nullptr, nullptr, x0b, 128, ps0);
  gemm3_k<128, 0, 1, 0, 0, 0, 1><<<dim3(1024, 1), B256, 0, stream>>>(
      tb, nullptr, wc2f, 128, bc2f, nullptr, nullptr, y0b, 128, ps1);

  // 4) y1 = gelu(LN(y0)@wl2+bl2) [stats->ps3]
  gemm3_k<128, 1, 2, 0, 0, 0, 1><<<dim3(1024, 1), B256, 0, stream>>>(
      y0b, nullptr, wl2f, 128, bl2f, ps1, cs + 256, y1b, 128, ps3);
  // 5) y gating (g2): t = gelu(LN(y1)@g2_w1+g2_b1) (2C wide, d_out scratch)
  gemm3_k<128, 1, 2, 0, 0, 0, 0><<<dim3(1024, 2), B256, 0, stream>>>(
      y1b, nullptr, g2w1, 256, g2b1, ps3, cs + 768, tb, 256, nullptr);
  mlp_k<0><<<dim3(64, 8), B512, 0, stream>>>(tb, g2w2, g2b2, uvb);
  mlp_k<1><<<dim3(64, 8), B512, 0, stream>>>(tb, g2w3, g2b3, uvb);
  gemm3_k<256, 0, 0, 0, 0, 0, 0><<<dim3(1024, 1), B256, 0, stream>>>(
      uvb, nullptr, g2w4, 128, g2b4, nullptr, nullptr, gyb, 128, nullptr);

  // 6) x1 = gelu(LN(x0)@wl1+bl1) [stats->ps2]
  gemm3_k<128, 1, 2, 0, 0, 0, 1><<<dim3(1024, 1), B256, 0, stream>>>(
      x0b, nullptr, wl1f, 128, bl1f, ps0, cs, x1b, 128, ps2);
  // 7) x gating (g1)
  gemm3_k<128, 1, 2, 0, 0, 0, 0><<<dim3(1024, 2), B256, 0, stream>>>(
      x1b, nullptr, g1w1, 256, g1b1, ps2, cs + 512, tb, 256, nullptr);
  mlp_k<0><<<dim3(64, 8), B512, 0, stream>>>(tb, g1w2, g1b2, uvb);
  mlp_k<1><<<dim3(64, 8), B512, 0, stream>>>(tb, g1w3, g1b3, uvb);
  // 8) y1 <- (uv@g1_w4 + g1_b4) * y1   (gx applied in place)
  gemm3_k<256, 0, 0, 0, 1, 0, 0><<<dim3(1024, 1), B256, 0, stream>>>(
      uvb, nullptr, g1w4, 128, g1b4, nullptr, nullptr, y1b, 128, nullptr);

  // 9+10) fused final: y_out -> outy, x_out -> outx (fp32 NCHW)
  dual_k<<<dim3(1024), B256, 0, stream>>>(
      y1b, x1b, gyb, wl3f, wl4f, bl3f, bl4f, y0b, x0b, outy, outx);
}

// Round 5
// 738.924 us; speedup vs baseline: 1.1627x; 1.0205x over previous
//
#include <hip/hip_runtime.h>
#include <hip/hip_bf16.h>

// ---------------------------------------------------------------------------
// CrossGatingBlock on MI355X (gfx950).  Round 5.
// All weights pre-transposed ONCE to bf16 k-minor [d][k] (prep_k, 1 dispatch).
// GEMMs are barrier-free: A and B fragments load directly from global
// (B is L2-hot weight), no LDS staging -> occupancy/latency-bound fix.
// mlp keeps only the activation transpose in LDS.  dual_k LDS-free.
// ---------------------------------------------------------------------------

typedef unsigned short u16;
typedef __bf16 bf16x8 __attribute__((ext_vector_type(8)));
typedef u16    u16x8  __attribute__((ext_vector_type(8)));
typedef u16    u16x4  __attribute__((ext_vector_type(4)));
typedef float  f32x4  __attribute__((ext_vector_type(4)));

__device__ __forceinline__ float bf2f(u16 u) {
  union { float f; unsigned int i; } v; v.i = ((unsigned int)u) << 16; return v.f;
}
__device__ __forceinline__ u16 f2bf(float f) {   // RNE
  union { float f; unsigned int i; } v; v.f = f;
  unsigned int x = v.i;
  return (u16)((x + 0x7fffu + ((x >> 16) & 1u)) >> 16);
}
__device__ __forceinline__ f32x4 mfma16(u16x8 a, u16x8 b, f32x4 c) {
  return __builtin_amdgcn_mfma_f32_16x16x32_bf16(
      __builtin_bit_cast(bf16x8, a), __builtin_bit_cast(bf16x8, b), c, 0, 0, 0);
}
__device__ __forceinline__ float gelu_erf(float v) {
  return 0.5f * v * (1.0f + erff(v * 0.70710678118654752f));
}

// ---------------------------------------------------------------------------
// NCHW(fp32) -> NHWC(bf16).  grid (HW/64, C/32, N), block 256.
__global__ __launch_bounds__(256) void tr_k(const float* __restrict__ in,
                                            u16* __restrict__ out,
                                            const int C, const int lgHW) {
  __shared__ u16 t[32 * 72];
  const int p0 = blockIdx.x * 64, c0 = blockIdx.y * 32, n = blockIdx.z;
  const int tid = threadIdx.x;
  {
    const int c = tid >> 3, e0 = (tid & 7) * 8;
    const float* ip = in + (((n * C + c0 + c) << lgHW) + p0 + e0);
    f32x4 v0 = *(const f32x4*)ip;
    f32x4 v1 = *(const f32x4*)(ip + 4);
    u16* tp = t + c * 72 + e0;
#pragma unroll
    for (int j = 0; j < 4; ++j) { tp[j] = f2bf(v0[j]); tp[4 + j] = f2bf(v1[j]); }
  }
  __syncthreads();
  {
    const int c8 = tid & 3, p = tid >> 2;
    u16x8 v;
#pragma unroll
    for (int j = 0; j < 8; ++j) v[j] = t[(c8 * 8 + j) * 72 + p];
    *(u16x8*)(out + ((n << lgHW) + p0 + p) * C + c0 + c8 * 8) = v;
  }
}

// ---------------------------------------------------------------------------
// prep_k: ONE dispatch doing all weight transposes (fp32 [k][d] -> bf16 [d][k]),
// the 4 LN colsums, and stats-slot zeroing.  grid 2437, block 256.
// wb offsets (u16 elems):
//   0 wc1b | 16384 wc2b | 32768 wl1b | 49152 wl2b | 65536 wl3b | 81920 wl4b
//   98304 g1w1b[256][128] | 131072 g2w1b | 163840 g1w4b[128][256] | 196608 g2w4b
//   229376 g1w2b[256][256] | 294912 g2w2b | 360448 g1w3b | 425984 g2w3b
//   491520 wtb[512][256]   (total 622592)
// ---------------------------------------------------------------------------
__global__ __launch_bounds__(256) void prep_k(
    const float* __restrict__ wc1f, const float* __restrict__ wc2f,
    const float* __restrict__ wl1f, const float* __restrict__ wl2f,
    const float* __restrict__ wl3f, const float* __restrict__ wl4f,
    const float* __restrict__ g1w1, const float* __restrict__ g2w1,
    const float* __restrict__ g1w4, const float* __restrict__ g2w4,
    const float* __restrict__ g1w2, const float* __restrict__ g2w2,
    const float* __restrict__ g1w3, const float* __restrict__ g2w3,
    const float* __restrict__ wtf,
    u16* __restrict__ wb, float* __restrict__ cs, float* __restrict__ ps) {
  const int b = blockIdx.x, t = threadIdx.x;
  if (b < 384) {                       // 6x [128][128]
    const float* src = b < 64 ? wc1f : b < 128 ? wc2f : b < 192 ? wl1f
                     : b < 256 ? wl2f : b < 320 ? wl3f : wl4f;
    const int w = b >> 6;
    const int i = ((b & 63) << 8) + t;           // < 16384
    const int d = i >> 7, c = i & 127;
    wb[w * 16384 + i] = f2bf(src[c * 128 + d]);
  } else if (b < 640) {                // g1w1/g2w1 [128][256] -> [256][128]
    const float* src = b < 512 ? g1w1 : g2w1;
    const int base = b < 512 ? 98304 : 131072;
    const int i = (((b - (b < 512 ? 384 : 512)) << 8) + t);  // < 32768
    const int d = i >> 7, c = i & 127;
    wb[base + i] = f2bf(src[c * 256 + d]);
  } else if (b < 896) {                // g1w4/g2w4 [256][128] -> [128][256]
    const float* src = b < 768 ? g1w4 : g2w4;
    const int base = b < 768 ? 163840 : 196608;
    const int i = (((b - (b < 768 ? 640 : 768)) << 8) + t);  // < 32768
    const int d = i >> 8, c = i & 255;
    wb[base + i] = f2bf(src[c * 128 + d]);
  } else if (b < 1920) {               // 4x [256][256] transpose
    const int w = (b - 896) >> 8;                 // 0..3
    const float* src = w == 0 ? g1w2 : w == 1 ? g2w2 : w == 2 ? g1w3 : g2w3;
    const int base = 229376 + w * 65536;
    const int i = (((b - 896) & 255) << 8) + t;   // < 65536
    const int d = i >> 8, g = i & 255;
    wb[base + i] = f2bf(src[g * 256 + d]);
  } else if (b < 2432) {               // wtb[kl*128+o][c] from wt(c,o,kh,kw)
    const int i = ((b - 1920) << 8) + t;          // < 131072
    const int c = i & 255, r = i >> 8, o = r & 127, kl = r >> 7;
    wb[491520 + i] = f2bf(wtf[(c * 128 + o) * 4 + kl]);
  } else if (b < 2436) {               // colsums (bf16-rounded)
    const int w = b - 2432;
    const float* src = w == 0 ? wl1f : w == 1 ? wl2f : w == 2 ? g1w1 : g2w1;
    const int cout = w < 2 ? 128 : 256;
    if (t < cout) {
      float s = 0.f;
      for (int c = 0; c < 128; ++c) s += bf2f(f2bf(src[c * cout + t]));
      cs[w * 256 + t] = s;
    }
  } else {                             // zero stats slots
    if (t < 64) ps[t] = 0.f;
  }
}

// ---------------------------------------------------------------------------
// gemm4_k: barrier-free GEMM.  out[t][d] = EPI( sum_c A[t][c] * W[c][d] ).
// Wt is bf16 k-minor [NOUT][CIN] (pre-transposed).  A and B fragments load
// directly from global; swapped MFMA orientation (lane holds 4 consecutive
// channels of one token).  Tile 128 tok x 128 ch, 4 waves.
// ---------------------------------------------------------------------------
template <int CIN, int LNF, int ACT, int AMUL, int MULST, int CONVT, int STATS>
__global__ __launch_bounds__(256, 4) void gemm4_k(
    const u16* __restrict__ A1, const u16* __restrict__ A2,
    const u16* __restrict__ Wt,
    const float* __restrict__ bias,
    const float* __restrict__ pst, const float* __restrict__ cs,
    u16* __restrict__ out, const int ostride,
    float* __restrict__ pso) {
  __shared__ float red[8];
  const int tid = threadIdx.x;
  const int m0 = blockIdx.x * 128, n0g = blockIdx.y * 128;
  const int wid = tid >> 6, lane = tid & 63, fr = lane & 15, fg = lane >> 4;
  const int wmt = (wid & 1) * 64;     // wave token offset
  const int wnc = (wid >> 1) * 64;    // wave channel offset

  f32x4 acc[4][4] = {};
  const u16* Arow  = A1 + (size_t)(m0 + wmt + fr) * CIN;
  const u16* Arow2 = AMUL ? A2 + (size_t)(m0 + wmt + fr) * CIN : nullptr;
  const u16* Brow  = Wt + (size_t)(n0g + wnc + fr) * CIN;

  auto lda = [&](u16x8* a, int ks) {
    const int kb = ks * 32 + fg * 8;
#pragma unroll
    for (int i = 0; i < 4; ++i) {
      a[i] = *(const u16x8*)(Arow + (size_t)i * 16 * CIN + kb);
      if constexpr (AMUL) {
        u16x8 v2 = *(const u16x8*)(Arow2 + (size_t)i * 16 * CIN + kb);
#pragma unroll
        for (int j = 0; j < 8; ++j) a[i][j] = f2bf(bf2f(a[i][j]) * bf2f(v2[j]));
      }
    }
  };

  u16x8 a_[4], an[4];
  lda(a_, 0);
#pragma unroll
  for (int ks = 0; ks < CIN / 32; ++ks) {
    if (ks + 1 < CIN / 32) lda(an, ks + 1);
    const int kb = ks * 32 + fg * 8;
    u16x8 b_[4];
#pragma unroll
    for (int j = 0; j < 4; ++j)
      b_[j] = *(const u16x8*)(Brow + (size_t)j * 16 * CIN + kb);
#pragma unroll
    for (int i = 0; i < 4; ++i)
#pragma unroll
      for (int j = 0; j < 4; ++j) acc[i][j] = mfma16(b_[j], a_[i], acc[i][j]);
#pragma unroll
    for (int i = 0; i < 4; ++i) a_[i] = an[i];
  }

  // epilogue: lane holds channels ch0..ch0+3 of one token
  float alpha = 1.f, beta = 0.f;
  if constexpr (LNF) {
    const int s = m0 >> 14;
    const float inv_n = 1.f / 2097152.f;
    const float mean = pst[2 * s] * inv_n;
    const float var = pst[2 * s + 1] * inv_n - mean * mean;
    alpha = rsqrtf(var + 1e-5f);
    beta = -mean * alpha;
  }
  float s1 = 0.f, s2 = 0.f;
#pragma unroll
  for (int i = 0; i < 4; ++i) {
    const int token = m0 + wmt + i * 16 + fr;
#pragma unroll
    for (int j = 0; j < 4; ++j) {
      const int ch0 = wnc + j * 16 + fg * 4;
      const int dd0 = n0g + ch0;
      const f32x4 bz = *(const f32x4*)(bias + (CONVT ? ch0 : dd0));
      f32x4 v = acc[i][j];
      if constexpr (LNF) {
        const f32x4 csv = *(const f32x4*)(cs + dd0);
#pragma unroll
        for (int r = 0; r < 4; ++r) v[r] = v[r] * alpha + beta * csv[r];
      }
      v += bz;
      if constexpr (ACT == 1) {
#pragma unroll
        for (int r = 0; r < 4; ++r) v[r] = fmaxf(v[r], 0.f);
      }
      if constexpr (ACT == 2) {
#pragma unroll
        for (int r = 0; r < 4; ++r) v[r] = gelu_erf(v[r]);
      }
      if constexpr (MULST) {
        u16x4 mv = *(const u16x4*)(out + (size_t)token * ostride + dd0);
#pragma unroll
        for (int r = 0; r < 4; ++r) v[r] *= bf2f(mv[r]);
      }
      if constexpr (STATS) {
#pragma unroll
        for (int r = 0; r < 4; ++r) { s1 += v[r]; s2 += v[r] * v[r]; }
      }
      u16x4 sv;
#pragma unroll
      for (int r = 0; r < 4; ++r) sv[r] = f2bf(v[r]);
      if constexpr (CONVT) {
        const int ns = token >> 12, hy = (token >> 6) & 63, wy = token & 63;
        const int kl = blockIdx.y;
        const int opix = ((ns * 128 + 2 * hy + (kl >> 1)) << 7) + 2 * wy + (kl & 1);
        *(u16x4*)(out + (size_t)opix * 128 + ch0) = sv;
      } else {
        *(u16x4*)(out + (size_t)token * ostride + dd0) = sv;
      }
    }
  }
  if constexpr (STATS) {
#pragma unroll
    for (int off = 32; off > 0; off >>= 1) {
      s1 += __shfl_down(s1, off); s2 += __shfl_down(s2, off);
    }
    if (lane == 0) { red[wid] = s1; red[4 + wid] = s2; }
    __syncthreads();
    const int s = m0 >> 14;
    if (tid == 0)  atomicAdd(&pso[2 * s],     red[0] + red[1] + red[2] + red[3]);
    if (tid == 64) atomicAdd(&pso[2 * s + 1], red[4] + red[5] + red[6] + red[7]);
  }
}

// ---------------------------------------------------------------------------
// dual2_k: fused final two GEMMs, LDS-free (weights bf16 k-minor from L2).
//   y_out = y1g@w3 + b3 + y0          -> outy fp32 NCHW
//   x_out = (x1*gy)@w4 + b4 + y_out + x0 -> outx fp32 NCHW
// y_out kept as bf16x4 in regs between passes (matches prior rounding).
// ---------------------------------------------------------------------------
__global__ __launch_bounds__(256, 2) void dual2_k(
    const u16* __restrict__ y1g, const u16* __restrict__ x1,
    const u16* __restrict__ gy,
    const u16* __restrict__ w3b, const u16* __restrict__ w4b,
    const float* __restrict__ b3, const float* __restrict__ b4,
    const u16* __restrict__ y0, const u16* __restrict__ x0,
    float* __restrict__ outy, float* __restrict__ outx) {
  const int tid = threadIdx.x;
  const int m0 = blockIdx.x * 128;
  const int wid = tid >> 6, lane = tid & 63, fr = lane & 15, fg = lane >> 4;
  const int wmt = (wid & 1) * 64, wnc = (wid >> 1) * 64;

  f32x4 acc[4][4] = {};
  u16x4 y9[4][4];

  // ---- pass 1: acc = y1g @ w3
  {
    const u16* Arow = y1g + (size_t)(m0 + wmt + fr) * 128;
    const u16* Brow = w3b + (size_t)(wnc + fr) * 128;
#pragma unroll
    for (int ks = 0; ks < 4; ++ks) {
      const int kb = ks * 32 + fg * 8;
      u16x8 a_[4], b_[4];
#pragma unroll
      for (int i = 0; i < 4; ++i) a_[i] = *(const u16x8*)(Arow + (size_t)i * 16 * 128 + kb);
#pragma unroll
      for (int j = 0; j < 4; ++j) b_[j] = *(const u16x8*)(Brow + (size_t)j * 16 * 128 + kb);
#pragma unroll
      for (int i = 0; i < 4; ++i)
#pragma unroll
        for (int j = 0; j < 4; ++j) acc[i][j] = mfma16(b_[j], a_[i], acc[i][j]);
    }
  }
  // epilogue 9: v = acc + b3 + y0 -> outy fp32 NCHW; keep bf16 copy
#pragma unroll
  for (int i = 0; i < 4; ++i) {
    const int token = m0 + wmt + i * 16 + fr;
    const int ns = token >> 14, p = token & 16383;
#pragma unroll
    for (int j = 0; j < 4; ++j) {
      const int ch0 = wnc + j * 16 + fg * 4;
      const f32x4 bz = *(const f32x4*)(b3 + ch0);
      const u16x4 sc = *(const u16x4*)(y0 + (size_t)token * 128 + ch0);
      f32x4 v = acc[i][j];
#pragma unroll
      for (int r = 0; r < 4; ++r) {
        v[r] += bz[r] + bf2f(sc[r]);
        outy[((size_t)(ns * 128 + ch0 + r) << 14) + p] = v[r];
        y9[i][j][r] = f2bf(v[r]);
      }
      acc[i][j] = f32x4{0.f, 0.f, 0.f, 0.f};
    }
  }
  // ---- pass 2: acc = (x1*gy) @ w4
  {
    const u16* Arow  = x1 + (size_t)(m0 + wmt + fr) * 128;
    const u16* Arow2 = gy + (size_t)(m0 + wmt + fr) * 128;
    const u16* Brow  = w4b + (size_t)(wnc + fr) * 128;
#pragma unroll
    for (int ks = 0; ks < 4; ++ks) {
      const int kb = ks * 32 + fg * 8;
      u16x8 a_[4], b_[4];
#pragma unroll
      for (int i = 0; i < 4; ++i) {
        a_[i] = *(const u16x8*)(Arow + (size_t)i * 16 * 128 + kb);
        u16x8 v2 = *(const u16x8*)(Arow2 + (size_t)i * 16 * 128 + kb);
#pragma unroll
        for (int j = 0; j < 8; ++j) a_[i][j] = f2bf(bf2f(a_[i][j]) * bf2f(v2[j]));
      }
#pragma unroll
      for (int j = 0; j < 4; ++j) b_[j] = *(const u16x8*)(Brow + (size_t)j * 16 * 128 + kb);
#pragma unroll
      for (int i = 0; i < 4; ++i)
#pragma unroll
        for (int j = 0; j < 4; ++j) acc[i][j] = mfma16(b_[j], a_[i], acc[i][j]);
    }
  }
  // epilogue 10: x_out = acc + b4 + y9 + x0 -> outx fp32 NCHW
#pragma unroll
  for (int i = 0; i < 4; ++i) {
    const int token = m0 + wmt + i * 16 + fr;
    const int ns = token >> 14, p = token & 16383;
#pragma unroll
    for (int j = 0; j < 4; ++j) {
      const int ch0 = wnc + j * 16 + fg * 4;
      const f32x4 bz = *(const f32x4*)(b4 + ch0);
      const u16x4 sc = *(const u16x4*)(x0 + (size_t)token * 128 + ch0);
      f32x4 v = acc[i][j];
#pragma unroll
      for (int r = 0; r < 4; ++r) {
        v[r] += bz[r] + bf2f(y9[i][j][r]) + bf2f(sc[r]);
        outx[((size_t)(ns * 128 + ch0 + r) << 14) + p] = v[r];
      }
    }
  }
}

// ---------------------------------------------------------------------------
// mlp2_k: spatial gating MLPs on NHWC 't' [131072][256].
// Weight fragments direct from global (bf16 [256][256] k-minor, L2-hot);
// only the activation transpose (Vs) goes through LDS.  Swapped orientation:
// lane holds 4 consecutive channels c of one output position d -> u16x4 store.
// MODE 0: mixes grid positions (ch 0:128); MODE 1: in-block positions (128:256).
// ---------------------------------------------------------------------------
template <int MODE>
__global__ __launch_bounds__(512, 4) void mlp2_k(const u16* __restrict__ tin,
                                                 const u16* __restrict__ Wtb,
                                                 const float* __restrict__ b,
                                                 u16* __restrict__ uvout) {
  constexpr int KP = 72;
  __shared__ u16 Vs[128 * KP];
  const int q2 = blockIdx.x, ns = blockIdx.y;
  const int tid = threadIdx.x;
  constexpr int coff = MODE ? 128 : 0;
  const int wid = tid >> 6, lane = tid & 63, fr = lane & 15, fg = lane >> 4;
  const int wdc = (wid >> 1) * 64;   // d offset (4 groups x 64 = 256)
  const int wcc = (wid & 1) * 64;    // c offset (2 groups x 64 = 128)

  int pbase, prow, pcol;
  if constexpr (MODE == 0) {    // q=(gh*16+gw), fixed p2=(ph*8+pw)
    pbase = ns * 16384 + (q2 >> 3) * 128 + (q2 & 7);
    prow = 8 * 128; pcol = 8;
  } else {                      // block g fixed, q=(ph*16+pw)
    pbase = ns * 16384 + (q2 >> 3) * 16 * 128 + (q2 & 7) * 16;
    prow = 128; pcol = 1;
  }
  auto pix = [&](int q) { return pbase + (q >> 4) * prow + (q & 15) * pcol; };

  f32x4 acc[4][4] = {};   // [i: c-subtile][j: d-subtile]

  for (int kc = 0; kc < 256; kc += 64) {
    if (kc) __syncthreads();
    // Vs[c][k] = tin[pix(kc+k)][coff+c]  (transpose-stage)
#pragma unroll
    for (int it = 0; it < 2; ++it) {
      const int idx = tid + it * 512;     // < 1024 = 16 c8 x 64 k
      const int c8 = idx >> 6, k = idx & 63;
      u16x8 tv = *(const u16x8*)(tin + (size_t)pix(kc + k) * 256 + coff + c8 * 8);
#pragma unroll
      for (int j = 0; j < 8; ++j) Vs[(c8 * 8 + j) * KP + k] = tv[j];
    }
    __syncthreads();
#pragma unroll
    for (int ks = 0; ks < 2; ++ks) {
      const int kbl = ks * 32 + fg * 8;
      const int kbg = kc + kbl;
      u16x8 v_[4], w_[4];
#pragma unroll
      for (int i = 0; i < 4; ++i) v_[i] = *(const u16x8*)(Vs + (wcc + i * 16 + fr) * KP + kbl);
#pragma unroll
      for (int j = 0; j < 4; ++j) w_[j] = *(const u16x8*)(Wtb + (size_t)(wdc + j * 16 + fr) * 256 + kbg);
#pragma unroll
      for (int i = 0; i < 4; ++i)
#pragma unroll
        for (int j = 0; j < 4; ++j) acc[i][j] = mfma16(v_[i], w_[j], acc[i][j]);
    }
  }
  // epilogue: c4 = 4 consecutive channels, d from fr -> u16x4 store
#pragma unroll
  for (int j = 0; j < 4; ++j) {
    const int d = wdc + j * 16 + fr;
    const float bd = b[d];
    const size_t obase = (size_t)pix(d) * 256 + coff;
#pragma unroll
    for (int i = 0; i < 4; ++i) {
      const int c4 = wcc + i * 16 + fg * 4;
      u16x4 sv;
#pragma unroll
      for (int r = 0; r < 4; ++r) sv[r] = f2bf(acc[i][j][r] + bd);
      *(u16x4*)(uvout + obase + c4) = sv;
    }
  }
}

// ---------------------------------------------------------------------------
extern "C" void kernel_launch(void* const* d_in, const int* in_sizes, int n_in,
                              void* d_out, int out_size, void* d_ws, size_t ws_size,
                              hipStream_t stream) {
  (void)in_sizes; (void)n_in; (void)out_size; (void)ws_size;
  const float* xf   = (const float*)d_in[0];
  const float* yf   = (const float*)d_in[1];
  const float* wtf  = (const float*)d_in[2];
  const float* btf  = (const float*)d_in[3];
  const float* wc1f = (const float*)d_in[4];
  const float* bc1f = (const float*)d_in[5];
  const float* wc2f = (const float*)d_in[6];
  const float* bc2f = (const float*)d_in[7];
  const float* wl1f = (const float*)d_in[8];
  const float* bl1f = (const float*)d_in[9];
  const float* wl2f = (const float*)d_in[10];
  const float* bl2f = (const float*)d_in[11];
  const float* wl3f = (const float*)d_in[12];
  const float* bl3f = (const float*)d_in[13];
  const float* wl4f = (const float*)d_in[14];
  const float* bl4f = (const float*)d_in[15];
  const float* g1w1 = (const float*)d_in[16];
  const float* g1b1 = (const float*)d_in[17];
  const float* g1w2 = (const float*)d_in[18];
  const float* g1b2 = (const float*)d_in[19];
  const float* g1w3 = (const float*)d_in[20];
  const float* g1b3 = (const float*)d_in[21];
  const float* g1w4 = (const float*)d_in[22];
  const float* g1b4 = (const float*)d_in[23];
  const float* g2w1 = (const float*)d_in[24];
  const float* g2b1 = (const float*)d_in[25];
  const float* g2w2 = (const float*)d_in[26];
  const float* g2b2 = (const float*)d_in[27];
  const float* g2w3 = (const float*)d_in[28];
  const float* g2b3 = (const float*)d_in[29];
  const float* g2w4 = (const float*)d_in[30];
  const float* g2b4 = (const float*)d_in[31];

  constexpr int T16 = 16777216;   // one big tensor, elems
  u16* WS  = (u16*)d_ws;
  u16* x0b = WS;                  // shortcut_x NHWC
  u16* x1b = WS + (size_t)T16;
  u16* y0b = WS + (size_t)2 * T16;
  u16* y1b = WS + (size_t)3 * T16;
  u16* gyb = WS + (size_t)4 * T16;
  u16* uvb = WS + (size_t)5 * T16; // 2*T16; early aliases xh/yh
  u16* xh  = uvb;
  u16* yh  = uvb + (size_t)T16;
  float* fb = (float*)(WS + (size_t)7 * T16);
  float* cs = fb;                  // [0]=wl1 [256]=wl2 [512]=g1w1 [768]=g2w1
  float* ps = fb + 1024;           // stats slots (64 floats)
  u16* wb   = (u16*)(fb + 1024 + 64);  // pre-transposed bf16 weights
  float* ps0 = ps, *ps1 = ps + 16, *ps2 = ps + 32, *ps3 = ps + 48;

  const u16* wc1b = wb;
  const u16* wc2b = wb + 16384;
  const u16* wl1b = wb + 32768;
  const u16* wl2b = wb + 49152;
  const u16* wl3b = wb + 65536;
  const u16* wl4b = wb + 81920;
  const u16* g1w1b = wb + 98304;
  const u16* g2w1b = wb + 131072;
  const u16* g1w4b = wb + 163840;
  const u16* g2w4b = wb + 196608;
  const u16* g1w2b = wb + 229376;
  const u16* g2w2b = wb + 294912;
  const u16* g1w3b = wb + 360448;
  const u16* g2w3b = wb + 425984;
  const u16* wtb   = wb + 491520;

  u16* tb    = (u16*)d_out;        // u16 scratch: yup, then gating tensor t
  float* outx = (float*)d_out;
  float* outy = (float*)d_out + (size_t)T16;

  const dim3 B256(256), B512(512);

  // 1) transforms + one-shot weight prep (transpose+colsum+zero)
  tr_k<<<dim3(256, 4, 8), B256, 0, stream>>>(xf, xh, 128, 14);
  tr_k<<<dim3(64, 8, 8),  B256, 0, stream>>>(yf, yh, 256, 12);
  prep_k<<<dim3(2437), B256, 0, stream>>>(
      wc1f, wc2f, wl1f, wl2f, wl3f, wl4f, g1w1, g2w1, g1w4, g2w4,
      g1w2, g2w2, g1w3, g2w3, wtf, wb, cs, ps);

  // 2) ConvT(k=2,s=2)+bt+relu -> yup (tb, NHWC)
  gemm4_k<256, 0, 1, 0, 0, 1, 0><<<dim3(256, 4), B256, 0, stream>>>(
      yh, nullptr, wtb, btf, nullptr, nullptr, tb, 128, nullptr);
  // 3) x0 = relu(xh@wc1+bc1); y0 = relu(yup@wc2+bc2)
  gemm4_k<128, 0, 1, 0, 0, 0, 1><<<dim3(1024, 1), B256, 0, stream>>>(
      xh, nullptr, wc1b, bc1f, nullptr, nullptr, x0b, 128, ps0);
  gemm4_k<128, 0, 1, 0, 0, 0, 1><<<dim3(1024, 1), B256, 0, stream>>>(
      tb, nullptr, wc2b, bc2f, nullptr, nullptr, y0b, 128, ps1);

  // 4) y1 = gelu(LN(y0)@wl2+bl2)
  gemm4_k<128, 1, 2, 0, 0, 0, 1><<<dim3(1024, 1), B256, 0, stream>>>(
      y0b, nullptr, wl2b, bl2f, ps1, cs + 256, y1b, 128, ps3);
  // 5) y gating (g2)
  gemm4_k<128, 1, 2, 0, 0, 0, 0><<<dim3(1024, 2), B256, 0, stream>>>(
      y1b, nullptr, g2w1b, g2b1, ps3, cs + 768, tb, 256, nullptr);
  mlp2_k<0><<<dim3(64, 8), B512, 0, stream>>>(tb, g2w2b, g2b2, uvb);
  mlp2_k<1><<<dim3(64, 8), B512, 0, stream>>>(tb, g2w3b, g2b3, uvb);
  gemm4_k<256, 0, 0, 0, 0, 0, 0><<<dim3(1024, 1), B256, 0, stream>>>(
      uvb, nullptr, g2w4b, g2b4, nullptr, nullptr, gyb, 128, nullptr);

  // 6) x1 = gelu(LN(x0)@wl1+bl1)
  gemm4_k<128, 1, 2, 0, 0, 0, 1><<<dim3(1024, 1), B256, 0, stream>>>(
      x0b, nullptr, wl1b, bl1f, ps0, cs, x1b, 128, ps2);
  // 7) x gating (g1)
  gemm4_k<128, 1, 2, 0, 0, 0, 0><<<dim3(1024, 2), B256, 0, stream>>>(
      x1b, nullptr, g1w1b, g1b1, ps2, cs + 512, tb, 256, nullptr);
  mlp2_k<0><<<dim3(64, 8), B512, 0, stream>>>(tb, g1w2b, g1b2, uvb);
  mlp2_k<1><<<dim3(64, 8), B512, 0, stream>>>(tb, g1w3b, g1b3, uvb);
  // 8) y1 <- (uv@g1_w4 + g1_b4) * y1  (gx applied in place)
  gemm4_k<256, 0, 0, 0, 1, 0, 0><<<dim3(1024, 1), B256, 0, stream>>>(
      uvb, nullptr, g1w4b, g1b4, nullptr, nullptr, y1b, 128, nullptr);

  // 9+10) fused final -> fp32 NCHW outputs
  dual2_k<<<dim3(1024), B256, 0, stream>>>(
      y1b, x1b, gyb, wl3b, wl4b, bl3f, bl4f, y0b, x0b, outy, outx);
}

// Round 6
// 678.136 us; speedup vs baseline: 1.2669x; 1.0896x over previous
//
#include <hip/hip_runtime.h>
#include <hip/hip_bf16.h>

// ---------------------------------------------------------------------------
// CrossGatingBlock on MI355X (gfx950).  Round 6.
// vs r5: (1) VGPR caps lifted (bounds (256,2)) + K-loop preloads a full
// 128-k half of A (16 loads in flight) before MFMAs; (2) epilogue shortcut
// loads hoisted; (3) step-8 gx GEMM fused into dual3_k pass0 (y1*gx staged
// via XOR-swizzled LDS tile); (4) dead template paths removed.
// ---------------------------------------------------------------------------

typedef unsigned short u16;
typedef __bf16 bf16x8 __attribute__((ext_vector_type(8)));
typedef u16    u16x8  __attribute__((ext_vector_type(8)));
typedef u16    u16x4  __attribute__((ext_vector_type(4)));
typedef float  f32x4  __attribute__((ext_vector_type(4)));

__device__ __forceinline__ float bf2f(u16 u) {
  union { float f; unsigned int i; } v; v.i = ((unsigned int)u) << 16; return v.f;
}
__device__ __forceinline__ u16 f2bf(float f) {   // RNE
  union { float f; unsigned int i; } v; v.f = f;
  unsigned int x = v.i;
  return (u16)((x + 0x7fffu + ((x >> 16) & 1u)) >> 16);
}
__device__ __forceinline__ f32x4 mfma16(u16x8 a, u16x8 b, f32x4 c) {
  return __builtin_amdgcn_mfma_f32_16x16x32_bf16(
      __builtin_bit_cast(bf16x8, a), __builtin_bit_cast(bf16x8, b), c, 0, 0, 0);
}
__device__ __forceinline__ float gelu_erf(float v) {
  return 0.5f * v * (1.0f + erff(v * 0.70710678118654752f));
}

// ---------------------------------------------------------------------------
// NCHW(fp32) -> NHWC(bf16).  grid (HW/64, C/32, N), block 256.
__global__ __launch_bounds__(256) void tr_k(const float* __restrict__ in,
                                            u16* __restrict__ out,
                                            const int C, const int lgHW) {
  __shared__ u16 t[32 * 72];
  const int p0 = blockIdx.x * 64, c0 = blockIdx.y * 32, n = blockIdx.z;
  const int tid = threadIdx.x;
  {
    const int c = tid >> 3, e0 = (tid & 7) * 8;
    const float* ip = in + (((n * C + c0 + c) << lgHW) + p0 + e0);
    f32x4 v0 = *(const f32x4*)ip;
    f32x4 v1 = *(const f32x4*)(ip + 4);
    u16* tp = t + c * 72 + e0;
#pragma unroll
    for (int j = 0; j < 4; ++j) { tp[j] = f2bf(v0[j]); tp[4 + j] = f2bf(v1[j]); }
  }
  __syncthreads();
  {
    const int c8 = tid & 3, p = tid >> 2;
    u16x8 v;
#pragma unroll
    for (int j = 0; j < 8; ++j) v[j] = t[(c8 * 8 + j) * 72 + p];
    *(u16x8*)(out + ((n << lgHW) + p0 + p) * C + c0 + c8 * 8) = v;
  }
}

// ---------------------------------------------------------------------------
// prep_k: all weight transposes (fp32 [k][d] -> bf16 [d][k]) + 4 LN colsums
// + stats zeroing in one dispatch.  grid 2437, block 256.
// ---------------------------------------------------------------------------
__global__ __launch_bounds__(256) void prep_k(
    const float* __restrict__ wc1f, const float* __restrict__ wc2f,
    const float* __restrict__ wl1f, const float* __restrict__ wl2f,
    const float* __restrict__ wl3f, const float* __restrict__ wl4f,
    const float* __restrict__ g1w1, const float* __restrict__ g2w1,
    const float* __restrict__ g1w4, const float* __restrict__ g2w4,
    const float* __restrict__ g1w2, const float* __restrict__ g2w2,
    const float* __restrict__ g1w3, const float* __restrict__ g2w3,
    const float* __restrict__ wtf,
    u16* __restrict__ wb, float* __restrict__ cs, float* __restrict__ ps) {
  const int b = blockIdx.x, t = threadIdx.x;
  if (b < 384) {                       // 6x [128][128]
    const float* src = b < 64 ? wc1f : b < 128 ? wc2f : b < 192 ? wl1f
                     : b < 256 ? wl2f : b < 320 ? wl3f : wl4f;
    const int w = b >> 6;
    const int i = ((b & 63) << 8) + t;           // < 16384
    const int d = i >> 7, c = i & 127;
    wb[w * 16384 + i] = f2bf(src[c * 128 + d]);
  } else if (b < 640) {                // g1w1/g2w1 [128][256] -> [256][128]
    const float* src = b < 512 ? g1w1 : g2w1;
    const int base = b < 512 ? 98304 : 131072;
    const int i = (((b - (b < 512 ? 384 : 512)) << 8) + t);  // < 32768
    const int d = i >> 7, c = i & 127;
    wb[base + i] = f2bf(src[c * 256 + d]);
  } else if (b < 896) {                // g1w4/g2w4 [256][128] -> [128][256]
    const float* src = b < 768 ? g1w4 : g2w4;
    const int base = b < 768 ? 163840 : 196608;
    const int i = (((b - (b < 768 ? 640 : 768)) << 8) + t);  // < 32768
    const int d = i >> 8, c = i & 255;
    wb[base + i] = f2bf(src[c * 128 + d]);
  } else if (b < 1920) {               // 4x [256][256] transpose
    const int w = (b - 896) >> 8;                 // 0..3
    const float* src = w == 0 ? g1w2 : w == 1 ? g2w2 : w == 2 ? g1w3 : g2w3;
    const int base = 229376 + w * 65536;
    const int i = (((b - 896) & 255) << 8) + t;   // < 65536
    const int d = i >> 8, g = i & 255;
    wb[base + i] = f2bf(src[g * 256 + d]);
  } else if (b < 2432) {               // wtb[kl*128+o][c] from wt(c,o,kh,kw)
    const int i = ((b - 1920) << 8) + t;          // < 131072
    const int c = i & 255, r = i >> 8, o = r & 127, kl = r >> 7;
    wb[491520 + i] = f2bf(wtf[(c * 128 + o) * 4 + kl]);
  } else if (b < 2436) {               // colsums (bf16-rounded)
    const int w = b - 2432;
    const float* src = w == 0 ? wl1f : w == 1 ? wl2f : w == 2 ? g1w1 : g2w1;
    const int cout = w < 2 ? 128 : 256;
    if (t < cout) {
      float s = 0.f;
      for (int c = 0; c < 128; ++c) s += bf2f(f2bf(src[c * cout + t]));
      cs[w * 256 + t] = s;
    }
  } else {                             // zero stats slots
    if (t < 64) ps[t] = 0.f;
  }
}

// ---------------------------------------------------------------------------
// gemm4_k v2: barrier-free GEMM, deep ILP.  out[t][d]=EPI(sum_c A[t][c]W[c][d]).
// Wt bf16 k-minor [NOUT][CIN].  Per 128-k half: ALL 16 A-fragment loads are
// issued before the MFMA stream (256B/lane in flight).  Swapped MFMA
// orientation (lane holds 4 consecutive channels of one token).
// ---------------------------------------------------------------------------
template <int CIN, int LNF, int ACT, int CONVT, int STATS>
__global__ __launch_bounds__(256, 2) void gemm4_k(
    const u16* __restrict__ A1,
    const u16* __restrict__ Wt,
    const float* __restrict__ bias,
    const float* __restrict__ pst, const float* __restrict__ cs,
    u16* __restrict__ out, const int ostride,
    float* __restrict__ pso) {
  __shared__ float red[8];
  const int tid = threadIdx.x;
  const int m0 = blockIdx.x * 128, n0g = blockIdx.y * 128;
  const int wid = tid >> 6, lane = tid & 63, fr = lane & 15, fg = lane >> 4;
  const int wmt = (wid & 1) * 64;     // wave token offset
  const int wnc = (wid >> 1) * 64;    // wave channel offset

  f32x4 acc[4][4] = {};
  const u16* Arow = A1 + (size_t)(m0 + wmt + fr) * CIN;
  const u16* Brow = Wt + (size_t)(n0g + wnc + fr) * CIN;

  constexpr int NH = CIN / 128;
  u16x8 a[4][4];
#pragma unroll
  for (int h = 0; h < NH; ++h) {
    // issue ALL 16 A loads for this 128-k half
#pragma unroll
    for (int ks = 0; ks < 4; ++ks) {
      const int kb = (h * 4 + ks) * 32 + fg * 8;
#pragma unroll
      for (int i = 0; i < 4; ++i)
        a[ks][i] = *(const u16x8*)(Arow + (size_t)i * 16 * CIN + kb);
    }
#pragma unroll
    for (int ks = 0; ks < 4; ++ks) {
      const int kb = (h * 4 + ks) * 32 + fg * 8;
      u16x8 b_[4];
#pragma unroll
      for (int j = 0; j < 4; ++j)
        b_[j] = *(const u16x8*)(Brow + (size_t)j * 16 * CIN + kb);
#pragma unroll
      for (int i = 0; i < 4; ++i)
#pragma unroll
        for (int j = 0; j < 4; ++j) acc[i][j] = mfma16(b_[j], a[ks][i], acc[i][j]);
    }
  }

  // epilogue: lane holds channels ch0..ch0+3 of one token
  float alpha = 1.f, beta = 0.f;
  if constexpr (LNF) {
    const int s = m0 >> 14;
    const float inv_n = 1.f / 2097152.f;
    const float mean = pst[2 * s] * inv_n;
    const float var = pst[2 * s + 1] * inv_n - mean * mean;
    alpha = rsqrtf(var + 1e-5f);
    beta = -mean * alpha;
  }
  float s1 = 0.f, s2 = 0.f;
#pragma unroll
  for (int i = 0; i < 4; ++i) {
    const int token = m0 + wmt + i * 16 + fr;
#pragma unroll
    for (int j = 0; j < 4; ++j) {
      const int ch0 = wnc + j * 16 + fg * 4;
      const int dd0 = n0g + ch0;
      const f32x4 bz = *(const f32x4*)(bias + (CONVT ? ch0 : dd0));
      f32x4 v = acc[i][j];
      if constexpr (LNF) {
        const f32x4 csv = *(const f32x4*)(cs + dd0);
#pragma unroll
        for (int r = 0; r < 4; ++r) v[r] = v[r] * alpha + beta * csv[r];
      }
      v += bz;
      if constexpr (ACT == 1) {
#pragma unroll
        for (int r = 0; r < 4; ++r) v[r] = fmaxf(v[r], 0.f);
      }
      if constexpr (ACT == 2) {
#pragma unroll
        for (int r = 0; r < 4; ++r) v[r] = gelu_erf(v[r]);
      }
      if constexpr (STATS) {
#pragma unroll
        for (int r = 0; r < 4; ++r) { s1 += v[r]; s2 += v[r] * v[r]; }
      }
      u16x4 sv;
#pragma unroll
      for (int r = 0; r < 4; ++r) sv[r] = f2bf(v[r]);
      if constexpr (CONVT) {
        const int ns = token >> 12, hy = (token >> 6) & 63, wy = token & 63;
        const int kl = blockIdx.y;
        const int opix = ((ns * 128 + 2 * hy + (kl >> 1)) << 7) + 2 * wy + (kl & 1);
        *(u16x4*)(out + (size_t)opix * 128 + ch0) = sv;
      } else {
        *(u16x4*)(out + (size_t)token * ostride + dd0) = sv;
      }
    }
  }
  if constexpr (STATS) {
#pragma unroll
    for (int off = 32; off > 0; off >>= 1) {
      s1 += __shfl_down(s1, off); s2 += __shfl_down(s2, off);
    }
    if (lane == 0) { red[wid] = s1; red[4 + wid] = s2; }
    __syncthreads();
    const int s = m0 >> 14;
    if (tid == 0)  atomicAdd(&pso[2 * s],     red[0] + red[1] + red[2] + red[3]);
    if (tid == 64) atomicAdd(&pso[2 * s + 1], red[4] + red[5] + red[6] + red[7]);
  }
}

// ---------------------------------------------------------------------------
// dual3_k: fused final THREE GEMMs.
//   pass0: gx = uv_x @ g1w4 + g1b4 ; y1g = bf16(gx * y1) -> LDS tile
//   pass1: y_out = y1g@w3 + b3 + y0           -> outy fp32 NCHW
//   pass2: x_out = (x1*gy)@w4 + b4 + y_out + x0 -> outx fp32 NCHW
// LDS tile [128 tok][136 ch] u16 with byte^((tok&7)<<4) XOR swizzle.
// ---------------------------------------------------------------------------
__global__ __launch_bounds__(256, 2) void dual3_k(
    const u16* __restrict__ uv, const u16* __restrict__ g1w4b,
    const float* __restrict__ g1b4, const u16* __restrict__ y1,
    const u16* __restrict__ x1, const u16* __restrict__ gy,
    const u16* __restrict__ w3b, const u16* __restrict__ w4b,
    const float* __restrict__ b3, const float* __restrict__ b4,
    const u16* __restrict__ y0, const u16* __restrict__ x0,
    float* __restrict__ outy, float* __restrict__ outx) {
  __shared__ u16 Ls[128 * 136];
  const int tid = threadIdx.x;
  const int m0 = blockIdx.x * 128;
  const int wid = tid >> 6, lane = tid & 63, fr = lane & 15, fg = lane >> 4;
  const int wmt = (wid & 1) * 64, wnc = (wid >> 1) * 64;

  f32x4 acc[4][4] = {};
  u16x4 y9[4][4];

  // ---- pass 0: gx = uv @ g1w4 (CIN=256), y1g -> LDS
  {
    const u16* Arow = uv + (size_t)(m0 + wmt + fr) * 256;
    const u16* Brow = g1w4b + (size_t)(wnc + fr) * 256;
    u16x8 a[4][4];
#pragma unroll
    for (int h = 0; h < 2; ++h) {
#pragma unroll
      for (int ks = 0; ks < 4; ++ks) {
        const int kb = (h * 4 + ks) * 32 + fg * 8;
#pragma unroll
        for (int i = 0; i < 4; ++i)
          a[ks][i] = *(const u16x8*)(Arow + (size_t)i * 16 * 256 + kb);
      }
#pragma unroll
      for (int ks = 0; ks < 4; ++ks) {
        const int kb = (h * 4 + ks) * 32 + fg * 8;
        u16x8 b_[4];
#pragma unroll
        for (int j = 0; j < 4; ++j)
          b_[j] = *(const u16x8*)(Brow + (size_t)j * 16 * 256 + kb);
#pragma unroll
        for (int i = 0; i < 4; ++i)
#pragma unroll
          for (int j = 0; j < 4; ++j) acc[i][j] = mfma16(b_[j], a[ks][i], acc[i][j]);
      }
    }
    // epilogue 0: y1g = bf16((gx + b) * y1) -> swizzled LDS
    u16x4 mv[4][4];
#pragma unroll
    for (int i = 0; i < 4; ++i) {
      const int token = m0 + wmt + i * 16 + fr;
#pragma unroll
      for (int j = 0; j < 4; ++j)
        mv[i][j] = *(const u16x4*)(y1 + (size_t)token * 128 + wnc + j * 16 + fg * 4);
    }
#pragma unroll
    for (int i = 0; i < 4; ++i) {
      const int tok = wmt + i * 16 + fr;
#pragma unroll
      for (int j = 0; j < 4; ++j) {
        const int ch0 = wnc + j * 16 + fg * 4;
        const f32x4 bz = *(const f32x4*)(g1b4 + ch0);
        u16x4 sv;
#pragma unroll
        for (int r = 0; r < 4; ++r)
          sv[r] = f2bf((acc[i][j][r] + bz[r]) * bf2f(mv[i][j][r]));
        const int byte = (tok * 272 + ch0 * 2) ^ ((tok & 7) << 4);
        *(u16x4*)((char*)Ls + byte) = sv;
        acc[i][j] = f32x4{0.f, 0.f, 0.f, 0.f};
      }
    }
  }
  __syncthreads();

  // ---- pass 1: acc = y1g @ w3 (A from swizzled LDS)
  {
    const u16* Brow = w3b + (size_t)(wnc + fr) * 128;
#pragma unroll
    for (int ks = 0; ks < 4; ++ks) {
      const int kb = ks * 32 + fg * 8;
      u16x8 a_[4], b_[4];
#pragma unroll
      for (int i = 0; i < 4; ++i) {
        const int tok = wmt + i * 16 + fr;
        const int byte = (tok * 272 + kb * 2) ^ ((tok & 7) << 4);
        a_[i] = *(const u16x8*)((const char*)Ls + byte);
      }
#pragma unroll
      for (int j = 0; j < 4; ++j) b_[j] = *(const u16x8*)(Brow + (size_t)j * 16 * 128 + kb);
#pragma unroll
      for (int i = 0; i < 4; ++i)
#pragma unroll
        for (int j = 0; j < 4; ++j) acc[i][j] = mfma16(b_[j], a_[i], acc[i][j]);
    }
  }
  // epilogue 1: v = acc + b3 + y0 -> outy fp32 NCHW; keep bf16 copy
  {
    u16x4 scv[4][4];
#pragma unroll
    for (int i = 0; i < 4; ++i) {
      const int token = m0 + wmt + i * 16 + fr;
#pragma unroll
      for (int j = 0; j < 4; ++j)
        scv[i][j] = *(const u16x4*)(y0 + (size_t)token * 128 + wnc + j * 16 + fg * 4);
    }
#pragma unroll
    for (int i = 0; i < 4; ++i) {
      const int token = m0 + wmt + i * 16 + fr;
      const int ns = token >> 14, p = token & 16383;
#pragma unroll
      for (int j = 0; j < 4; ++j) {
        const int ch0 = wnc + j * 16 + fg * 4;
        const f32x4 bz = *(const f32x4*)(b3 + ch0);
        f32x4 v = acc[i][j];
#pragma unroll
        for (int r = 0; r < 4; ++r) {
          v[r] += bz[r] + bf2f(scv[i][j][r]);
          outy[((size_t)(ns * 128 + ch0 + r) << 14) + p] = v[r];
          y9[i][j][r] = f2bf(v[r]);
        }
        acc[i][j] = f32x4{0.f, 0.f, 0.f, 0.f};
      }
    }
  }
  // ---- pass 2: acc = (x1*gy) @ w4
  {
    const u16* Arow  = x1 + (size_t)(m0 + wmt + fr) * 128;
    const u16* Arow2 = gy + (size_t)(m0 + wmt + fr) * 128;
    const u16* Brow  = w4b + (size_t)(wnc + fr) * 128;
    u16x8 a[4][4], a2[4][4];
#pragma unroll
    for (int ks = 0; ks < 4; ++ks) {
      const int kb = ks * 32 + fg * 8;
#pragma unroll
      for (int i = 0; i < 4; ++i) {
        a[ks][i]  = *(const u16x8*)(Arow  + (size_t)i * 16 * 128 + kb);
        a2[ks][i] = *(const u16x8*)(Arow2 + (size_t)i * 16 * 128 + kb);
      }
    }
#pragma unroll
    for (int ks = 0; ks < 4; ++ks) {
      const int kb = ks * 32 + fg * 8;
      u16x8 b_[4];
#pragma unroll
      for (int j = 0; j < 4; ++j) b_[j] = *(const u16x8*)(Brow + (size_t)j * 16 * 128 + kb);
      u16x8 am[4];
#pragma unroll
      for (int i = 0; i < 4; ++i) {
#pragma unroll
        for (int j = 0; j < 8; ++j) am[i][j] = f2bf(bf2f(a[ks][i][j]) * bf2f(a2[ks][i][j]));
      }
#pragma unroll
      for (int i = 0; i < 4; ++i)
#pragma unroll
        for (int j = 0; j < 4; ++j) acc[i][j] = mfma16(b_[j], am[i], acc[i][j]);
    }
  }
  // epilogue 2: x_out = acc + b4 + y9 + x0 -> outx fp32 NCHW
  {
    u16x4 scv[4][4];
#pragma unroll
    for (int i = 0; i < 4; ++i) {
      const int token = m0 + wmt + i * 16 + fr;
#pragma unroll
      for (int j = 0; j < 4; ++j)
        scv[i][j] = *(const u16x4*)(x0 + (size_t)token * 128 + wnc + j * 16 + fg * 4);
    }
#pragma unroll
    for (int i = 0; i < 4; ++i) {
      const int token = m0 + wmt + i * 16 + fr;
      const int ns = token >> 14, p = token & 16383;
#pragma unroll
      for (int j = 0; j < 4; ++j) {
        const int ch0 = wnc + j * 16 + fg * 4;
        const f32x4 bz = *(const f32x4*)(b4 + ch0);
        f32x4 v = acc[i][j];
#pragma unroll
        for (int r = 0; r < 4; ++r) {
          v[r] += bz[r] + bf2f(y9[i][j][r]) + bf2f(scv[i][j][r]);
          outx[((size_t)(ns * 128 + ch0 + r) << 14) + p] = v[r];
        }
      }
    }
  }
}

// ---------------------------------------------------------------------------
// mlp2_k: spatial gating MLPs on NHWC 't' [131072][256].  (bounds relaxed)
// ---------------------------------------------------------------------------
template <int MODE>
__global__ __launch_bounds__(512, 2) void mlp2_k(const u16* __restrict__ tin,
                                                 const u16* __restrict__ Wtb,
                                                 const float* __restrict__ b,
                                                 u16* __restrict__ uvout) {
  constexpr int KP = 72;
  __shared__ u16 Vs[128 * KP];
  const int q2 = blockIdx.x, ns = blockIdx.y;
  const int tid = threadIdx.x;
  constexpr int coff = MODE ? 128 : 0;
  const int wid = tid >> 6, lane = tid & 63, fr = lane & 15, fg = lane >> 4;
  const int wdc = (wid >> 1) * 64;   // d offset
  const int wcc = (wid & 1) * 64;    // c offset

  int pbase, prow, pcol;
  if constexpr (MODE == 0) {
    pbase = ns * 16384 + (q2 >> 3) * 128 + (q2 & 7);
    prow = 8 * 128; pcol = 8;
  } else {
    pbase = ns * 16384 + (q2 >> 3) * 16 * 128 + (q2 & 7) * 16;
    prow = 128; pcol = 1;
  }
  auto pix = [&](int q) { return pbase + (q >> 4) * prow + (q & 15) * pcol; };

  f32x4 acc[4][4] = {};

  for (int kc = 0; kc < 256; kc += 64) {
    if (kc) __syncthreads();
#pragma unroll
    for (int it = 0; it < 2; ++it) {
      const int idx = tid + it * 512;     // < 1024 = 16 c8 x 64 k
      const int c8 = idx >> 6, k = idx & 63;
      u16x8 tv = *(const u16x8*)(tin + (size_t)pix(kc + k) * 256 + coff + c8 * 8);
#pragma unroll
      for (int j = 0; j < 8; ++j) Vs[(c8 * 8 + j) * KP + k] = tv[j];
    }
    __syncthreads();
#pragma unroll
    for (int ks = 0; ks < 2; ++ks) {
      const int kbl = ks * 32 + fg * 8;
      const int kbg = kc + kbl;
      u16x8 v_[4], w_[4];
#pragma unroll
      for (int i = 0; i < 4; ++i) v_[i] = *(const u16x8*)(Vs + (wcc + i * 16 + fr) * KP + kbl);
#pragma unroll
      for (int j = 0; j < 4; ++j) w_[j] = *(const u16x8*)(Wtb + (size_t)(wdc + j * 16 + fr) * 256 + kbg);
#pragma unroll
      for (int i = 0; i < 4; ++i)
#pragma unroll
        for (int j = 0; j < 4; ++j) acc[i][j] = mfma16(v_[i], w_[j], acc[i][j]);
    }
  }
#pragma unroll
  for (int j = 0; j < 4; ++j) {
    const int d = wdc + j * 16 + fr;
    const float bd = b[d];
    const size_t obase = (size_t)pix(d) * 256 + coff;
#pragma unroll
    for (int i = 0; i < 4; ++i) {
      const int c4 = wcc + i * 16 + fg * 4;
      u16x4 sv;
#pragma unroll
      for (int r = 0; r < 4; ++r) sv[r] = f2bf(acc[i][j][r] + bd);
      *(u16x4*)(uvout + obase + c4) = sv;
    }
  }
}

// ---------------------------------------------------------------------------
extern "C" void kernel_launch(void* const* d_in, const int* in_sizes, int n_in,
                              void* d_out, int out_size, void* d_ws, size_t ws_size,
                              hipStream_t stream) {
  (void)in_sizes; (void)n_in; (void)out_size; (void)ws_size;
  const float* xf   = (const float*)d_in[0];
  const float* yf   = (const float*)d_in[1];
  const float* wtf  = (const float*)d_in[2];
  const float* btf  = (const float*)d_in[3];
  const float* wc1f = (const float*)d_in[4];
  const float* bc1f = (const float*)d_in[5];
  const float* wc2f = (const float*)d_in[6];
  const float* bc2f = (const float*)d_in[7];
  const float* wl1f = (const float*)d_in[8];
  const float* bl1f = (const float*)d_in[9];
  const float* wl2f = (const float*)d_in[10];
  const float* bl2f = (const float*)d_in[11];
  const float* wl3f = (const float*)d_in[12];
  const float* bl3f = (const float*)d_in[13];
  const float* wl4f = (const float*)d_in[14];
  const float* bl4f = (const float*)d_in[15];
  const float* g1w1 = (const float*)d_in[16];
  const float* g1b1 = (const float*)d_in[17];
  const float* g1w2 = (const float*)d_in[18];
  const float* g1b2 = (const float*)d_in[19];
  const float* g1w3 = (const float*)d_in[20];
  const float* g1b3 = (const float*)d_in[21];
  const float* g1w4 = (const float*)d_in[22];
  const float* g1b4 = (const float*)d_in[23];
  const float* g2w1 = (const float*)d_in[24];
  const float* g2b1 = (const float*)d_in[25];
  const float* g2w2 = (const float*)d_in[26];
  const float* g2b2 = (const float*)d_in[27];
  const float* g2w3 = (const float*)d_in[28];
  const float* g2b3 = (const float*)d_in[29];
  const float* g2w4 = (const float*)d_in[30];
  const float* g2b4 = (const float*)d_in[31];

  constexpr int T16 = 16777216;
  u16* WS  = (u16*)d_ws;
  u16* x0b = WS;
  u16* x1b = WS + (size_t)T16;
  u16* y0b = WS + (size_t)2 * T16;
  u16* y1b = WS + (size_t)3 * T16;
  u16* gyb = WS + (size_t)4 * T16;
  u16* uvb = WS + (size_t)5 * T16; // 2*T16; early aliases xh/yh
  u16* xh  = uvb;
  u16* yh  = uvb + (size_t)T16;
  float* fb = (float*)(WS + (size_t)7 * T16);
  float* cs = fb;
  float* ps = fb + 1024;
  u16* wb   = (u16*)(fb + 1024 + 64);
  float* ps0 = ps, *ps1 = ps + 16, *ps2 = ps + 32, *ps3 = ps + 48;

  const u16* wc1b = wb;
  const u16* wc2b = wb + 16384;
  const u16* wl1b = wb + 32768;
  const u16* wl2b = wb + 49152;
  const u16* wl3b = wb + 65536;
  const u16* wl4b = wb + 81920;
  const u16* g1w1b = wb + 98304;
  const u16* g2w1b = wb + 131072;
  const u16* g1w4b = wb + 163840;
  const u16* g2w4b = wb + 196608;
  const u16* g1w2b = wb + 229376;
  const u16* g2w2b = wb + 294912;
  const u16* g1w3b = wb + 360448;
  const u16* g2w3b = wb + 425984;
  const u16* wtb   = wb + 491520;

  u16* tb    = (u16*)d_out;        // u16 scratch: yup, then gating tensor t
  float* outx = (float*)d_out;
  float* outy = (float*)d_out + (size_t)T16;

  const dim3 B256(256), B512(512);

  // 1) transforms + one-shot weight prep
  tr_k<<<dim3(256, 4, 8), B256, 0, stream>>>(xf, xh, 128, 14);
  tr_k<<<dim3(64, 8, 8),  B256, 0, stream>>>(yf, yh, 256, 12);
  prep_k<<<dim3(2437), B256, 0, stream>>>(
      wc1f, wc2f, wl1f, wl2f, wl3f, wl4f, g1w1, g2w1, g1w4, g2w4,
      g1w2, g2w2, g1w3, g2w3, wtf, wb, cs, ps);

  // 2) ConvT(k=2,s=2)+bt+relu -> yup (tb, NHWC)
  gemm4_k<256, 0, 1, 1, 0><<<dim3(256, 4), B256, 0, stream>>>(
      yh, wtb, btf, nullptr, nullptr, tb, 128, nullptr);
  // 3) x0 = relu(xh@wc1+bc1); y0 = relu(yup@wc2+bc2)
  gemm4_k<128, 0, 1, 0, 1><<<dim3(1024, 1), B256, 0, stream>>>(
      xh, wc1b, bc1f, nullptr, nullptr, x0b, 128, ps0);
  gemm4_k<128, 0, 1, 0, 1><<<dim3(1024, 1), B256, 0, stream>>>(
      tb, wc2b, bc2f, nullptr, nullptr, y0b, 128, ps1);

  // 4) y1 = gelu(LN(y0)@wl2+bl2)
  gemm4_k<128, 1, 2, 0, 1><<<dim3(1024, 1), B256, 0, stream>>>(
      y0b, wl2b, bl2f, ps1, cs + 256, y1b, 128, ps3);
  // 5) y gating (g2)
  gemm4_k<128, 1, 2, 0, 0><<<dim3(1024, 2), B256, 0, stream>>>(
      y1b, g2w1b, g2b1, ps3, cs + 768, tb, 256, nullptr);
  mlp2_k<0><<<dim3(64, 8), B512, 0, stream>>>(tb, g2w2b, g2b2, uvb);
  mlp2_k<1><<<dim3(64, 8), B512, 0, stream>>>(tb, g2w3b, g2b3, uvb);
  gemm4_k<256, 0, 0, 0, 0><<<dim3(1024, 1), B256, 0, stream>>>(
      uvb, g2w4b, g2b4, nullptr, nullptr, gyb, 128, nullptr);

  // 6) x1 = gelu(LN(x0)@wl1+bl1)
  gemm4_k<128, 1, 2, 0, 1><<<dim3(1024, 1), B256, 0, stream>>>(
      x0b, wl1b, bl1f, ps0, cs, x1b, 128, ps2);
  // 7) x gating (g1)
  gemm4_k<128, 1, 2, 0, 0><<<dim3(1024, 2), B256, 0, stream>>>(
      x1b, g1w1b, g1b1, ps2, cs + 512, tb, 256, nullptr);
  mlp2_k<0><<<dim3(64, 8), B512, 0, stream>>>(tb, g1w2b, g1b2, uvb);
  mlp2_k<1><<<dim3(64, 8), B512, 0, stream>>>(tb, g1w3b, g1b3, uvb);

  // 8+9+10) fused: gx in-reg, y_out -> outy, x_out -> outx (fp32 NCHW)
  dual3_k<<<dim3(1024), B256, 0, stream>>>(
      uvb, g1w4b, g1b4, y1b, x1b, gyb, wl3b, wl4b, bl3f, bl4f,
      y0b, x0b, outy, outx);
}

// Round 7
// 611.231 us; speedup vs baseline: 1.4056x; 1.1095x over previous
//
#include <hip/hip_runtime.h>
#include <hip/hip_bf16.h>

// ---------------------------------------------------------------------------
// CrossGatingBlock on MI355X (gfx950).  Round 7: traffic reduction.
// - mlp3_k fuses t = gelu(LN(y1)@g_w1+b1) into the spatial MLP (t never
//   materialized; 64KB XOR-swizzled LDS tile between the two GEMM stages).
// - gemmX_k / gemmY_k read fp32 NCHW inputs directly (in-kernel LDS
//   transpose) -> tr_k round-trips eliminated.
// - gemm4/dual3 retained from r6.
// ---------------------------------------------------------------------------

typedef unsigned short u16;
typedef __bf16 bf16x8 __attribute__((ext_vector_type(8)));
typedef u16    u16x8  __attribute__((ext_vector_type(8)));
typedef u16    u16x4  __attribute__((ext_vector_type(4)));
typedef float  f32x4  __attribute__((ext_vector_type(4)));

__device__ __forceinline__ float bf2f(u16 u) {
  union { float f; unsigned int i; } v; v.i = ((unsigned int)u) << 16; return v.f;
}
__device__ __forceinline__ u16 f2bf(float f) {   // RNE
  union { float f; unsigned int i; } v; v.f = f;
  unsigned int x = v.i;
  return (u16)((x + 0x7fffu + ((x >> 16) & 1u)) >> 16);
}
__device__ __forceinline__ f32x4 mfma16(u16x8 a, u16x8 b, f32x4 c) {
  return __builtin_amdgcn_mfma_f32_16x16x32_bf16(
      __builtin_bit_cast(bf16x8, a), __builtin_bit_cast(bf16x8, b), c, 0, 0, 0);
}
__device__ __forceinline__ float gelu_erf(float v) {
  return 0.5f * v * (1.0f + erff(v * 0.70710678118654752f));
}

// ---------------------------------------------------------------------------
// prep_k: all weight transposes (fp32 [k][d] -> bf16 [d][k]) + 4 LN colsums
// + stats zeroing in one dispatch.  grid 2437, block 256.
// ---------------------------------------------------------------------------
__global__ __launch_bounds__(256) void prep_k(
    const float* __restrict__ wc1f, const float* __restrict__ wc2f,
    const float* __restrict__ wl1f, const float* __restrict__ wl2f,
    const float* __restrict__ wl3f, const float* __restrict__ wl4f,
    const float* __restrict__ g1w1, const float* __restrict__ g2w1,
    const float* __restrict__ g1w4, const float* __restrict__ g2w4,
    const float* __restrict__ g1w2, const float* __restrict__ g2w2,
    const float* __restrict__ g1w3, const float* __restrict__ g2w3,
    const float* __restrict__ wtf,
    u16* __restrict__ wb, float* __restrict__ cs, float* __restrict__ ps) {
  const int b = blockIdx.x, t = threadIdx.x;
  if (b < 384) {                       // 6x [128][128]
    const float* src = b < 64 ? wc1f : b < 128 ? wc2f : b < 192 ? wl1f
                     : b < 256 ? wl2f : b < 320 ? wl3f : wl4f;
    const int w = b >> 6;
    const int i = ((b & 63) << 8) + t;           // < 16384
    const int d = i >> 7, c = i & 127;
    wb[w * 16384 + i] = f2bf(src[c * 128 + d]);
  } else if (b < 640) {                // g1w1/g2w1 [128][256] -> [256][128]
    const float* src = b < 512 ? g1w1 : g2w1;
    const int base = b < 512 ? 98304 : 131072;
    const int i = (((b - (b < 512 ? 384 : 512)) << 8) + t);  // < 32768
    const int d = i >> 7, c = i & 127;
    wb[base + i] = f2bf(src[c * 256 + d]);
  } else if (b < 896) {                // g1w4/g2w4 [256][128] -> [128][256]
    const float* src = b < 768 ? g1w4 : g2w4;
    const int base = b < 768 ? 163840 : 196608;
    const int i = (((b - (b < 768 ? 640 : 768)) << 8) + t);  // < 32768
    const int d = i >> 8, c = i & 255;
    wb[base + i] = f2bf(src[c * 128 + d]);
  } else if (b < 1920) {               // 4x [256][256] transpose
    const int w = (b - 896) >> 8;                 // 0..3
    const float* src = w == 0 ? g1w2 : w == 1 ? g2w2 : w == 2 ? g1w3 : g2w3;
    const int base = 229376 + w * 65536;
    const int i = (((b - 896) & 255) << 8) + t;   // < 65536
    const int d = i >> 8, g = i & 255;
    wb[base + i] = f2bf(src[g * 256 + d]);
  } else if (b < 2432) {               // wtb[kl*128+o][c] from wt(c,o,kh,kw)
    const int i = ((b - 1920) << 8) + t;          // < 131072
    const int c = i & 255, r = i >> 8, o = r & 127, kl = r >> 7;
    wb[491520 + i] = f2bf(wtf[(c * 128 + o) * 4 + kl]);
  } else if (b < 2436) {               // colsums (bf16-rounded)
    const int w = b - 2432;
    const float* src = w == 0 ? wl1f : w == 1 ? wl2f : w == 2 ? g1w1 : g2w1;
    const int cout = w < 2 ? 128 : 256;
    if (t < cout) {
      float s = 0.f;
      for (int c = 0; c < 128; ++c) s += bf2f(f2bf(src[c * cout + t]));
      cs[w * 256 + t] = s;
    }
  } else {                             // zero stats slots
    if (t < 64) ps[t] = 0.f;
  }
}

// ---------------------------------------------------------------------------
// gemmX_k: x0 = relu(x_nchw_fp32 @ wc1 + bc1) + LN stats.  A transposed
// in-kernel via LDS (pitch 136, 2-way-free).  CIN=128.
// ---------------------------------------------------------------------------
__global__ __launch_bounds__(256, 2) void gemmX_k(
    const float* __restrict__ X, const u16* __restrict__ Wt,
    const float* __restrict__ bias, u16* __restrict__ out,
    float* __restrict__ pso) {
  __shared__ u16 As[128 * 136];
  __shared__ float red[8];
  const int tid = threadIdx.x;
  const int m0 = blockIdx.x * 128;
  const int ns = m0 >> 14, pb = m0 & 16383;
  const int wid = tid >> 6, lane = tid & 63, fr = lane & 15, fg = lane >> 4;
  const int wmt = (wid & 1) * 64, wnc = (wid >> 1) * 64;

  // stage A: [tok][c] bf16, lanes write consecutive c (conflict-free)
#pragma unroll
  for (int it = 0; it < 16; ++it) {
    const int idx = it * 256 + tid;          // < 4096
    const int c = idx & 127, t4 = idx >> 7;  // t4 0..31
    const f32x4 v = *(const f32x4*)(X + (((size_t)(ns * 128 + c)) << 14) + pb + t4 * 4);
#pragma unroll
    for (int r = 0; r < 4; ++r) As[(t4 * 4 + r) * 136 + c] = f2bf(v[r]);
  }
  __syncthreads();

  f32x4 acc[4][4] = {};
  const u16* Brow = Wt + (size_t)(wnc + fr) * 128;
  u16x8 a[4][4];
#pragma unroll
  for (int ks = 0; ks < 4; ++ks) {
    const int kb = ks * 32 + fg * 8;
#pragma unroll
    for (int i = 0; i < 4; ++i)
      a[ks][i] = *(const u16x8*)(As + (wmt + i * 16 + fr) * 136 + kb);
  }
#pragma unroll
  for (int ks = 0; ks < 4; ++ks) {
    const int kb = ks * 32 + fg * 8;
    u16x8 b_[4];
#pragma unroll
    for (int j = 0; j < 4; ++j)
      b_[j] = *(const u16x8*)(Brow + (size_t)j * 16 * 128 + kb);
#pragma unroll
    for (int i = 0; i < 4; ++i)
#pragma unroll
      for (int j = 0; j < 4; ++j) acc[i][j] = mfma16(b_[j], a[ks][i], acc[i][j]);
  }

  float s1 = 0.f, s2 = 0.f;
#pragma unroll
  for (int i = 0; i < 4; ++i) {
    const int token = m0 + wmt + i * 16 + fr;
#pragma unroll
    for (int j = 0; j < 4; ++j) {
      const int ch0 = wnc + j * 16 + fg * 4;
      const f32x4 bz = *(const f32x4*)(bias + ch0);
      f32x4 v = acc[i][j];
      u16x4 sv;
#pragma unroll
      for (int r = 0; r < 4; ++r) {
        v[r] = fmaxf(v[r] + bz[r], 0.f);
        s1 += v[r]; s2 += v[r] * v[r];
        sv[r] = f2bf(v[r]);
      }
      *(u16x4*)(out + (size_t)token * 128 + ch0) = sv;
    }
  }
#pragma unroll
  for (int off = 32; off > 0; off >>= 1) {
    s1 += __shfl_down(s1, off); s2 += __shfl_down(s2, off);
  }
  if (lane == 0) { red[wid] = s1; red[4 + wid] = s2; }
  __syncthreads();
  if (tid == 0)  atomicAdd(&pso[2 * ns],     red[0] + red[1] + red[2] + red[3]);
  if (tid == 64) atomicAdd(&pso[2 * ns + 1], red[4] + red[5] + red[6] + red[7]);
}

// ---------------------------------------------------------------------------
// gemmY_k: ConvT(k=2,s=2)+bt+relu from y fp32 NCHW directly.  CIN=256.
// A transposed in-kernel via 64KB XOR-swizzled LDS.  blockIdx.y = kl.
// ---------------------------------------------------------------------------
__global__ __launch_bounds__(256, 2) void gemmY_k(
    const float* __restrict__ Y, const u16* __restrict__ Wt,
    const float* __restrict__ bias, u16* __restrict__ out) {
  __shared__ u16 As[128 * 256];              // [tok][c], byte ^= (tok&7)<<4
  const int tid = threadIdx.x;
  const int m0 = blockIdx.x * 128;
  const int n0g = blockIdx.y * 128;
  const int ns = m0 >> 12, pb = m0 & 4095;
  const int wid = tid >> 6, lane = tid & 63, fr = lane & 15, fg = lane >> 4;
  const int wmt = (wid & 1) * 64, wnc = (wid >> 1) * 64;
  const int xorl = (fr & 7) << 4;

#pragma unroll
  for (int it = 0; it < 32; ++it) {
    const int idx = it * 256 + tid;           // < 8192
    const int c = idx & 255, t4 = idx >> 8;   // t4 0..31
    const f32x4 v = *(const f32x4*)(Y + (((size_t)(ns * 256 + c)) << 12) + pb + t4 * 4);
#pragma unroll
    for (int r = 0; r < 4; ++r) {
      const int tok = t4 * 4 + r;
      const int byte = (tok * 512 + c * 2) ^ ((tok & 7) << 4);
      *(u16*)((char*)As + byte) = f2bf(v[r]);
    }
  }
  __syncthreads();

  f32x4 acc[4][4] = {};
  const u16* Brow = Wt + (size_t)(n0g + wnc + fr) * 256;
#pragma unroll
  for (int h = 0; h < 2; ++h) {
    u16x8 a[4][4];
#pragma unroll
    for (int ks = 0; ks < 4; ++ks) {
      const int kb = (h * 4 + ks) * 32 + fg * 8;
#pragma unroll
      for (int i = 0; i < 4; ++i) {
        const int tok = wmt + i * 16 + fr;
        const int byte = (tok * 512 + kb * 2) ^ xorl;
        a[ks][i] = *(const u16x8*)((const char*)As + byte);
      }
    }
#pragma unroll
    for (int ks = 0; ks < 4; ++ks) {
      const int kb = (h * 4 + ks) * 32 + fg * 8;
      u16x8 b_[4];
#pragma unroll
      for (int j = 0; j < 4; ++j)
        b_[j] = *(const u16x8*)(Brow + (size_t)j * 16 * 256 + kb);
#pragma unroll
      for (int i = 0; i < 4; ++i)
#pragma unroll
        for (int j = 0; j < 4; ++j) acc[i][j] = mfma16(b_[j], a[ks][i], acc[i][j]);
    }
  }

  // ConvT scatter epilogue (relu)
#pragma unroll
  for (int i = 0; i < 4; ++i) {
    const int token = m0 + wmt + i * 16 + fr;
    const int nsY = token >> 12, hy = (token >> 6) & 63, wy = token & 63;
    const int kl = blockIdx.y;
    const int opix = ((nsY * 128 + 2 * hy + (kl >> 1)) << 7) + 2 * wy + (kl & 1);
#pragma unroll
    for (int j = 0; j < 4; ++j) {
      const int ch0 = wnc + j * 16 + fg * 4;
      const f32x4 bz = *(const f32x4*)(bias + ch0);
      u16x4 sv;
#pragma unroll
      for (int r = 0; r < 4; ++r) sv[r] = f2bf(fmaxf(acc[i][j][r] + bz[r], 0.f));
      *(u16x4*)(out + (size_t)opix * 128 + ch0) = sv;
    }
  }
}

// ---------------------------------------------------------------------------
// gemm4_k: barrier-free GEMM on bf16 NHWC A.  out[t][d]=EPI(sum A[t][c]W[c][d]).
// (r6 structure: full-half A preload, swapped orientation.)
// ---------------------------------------------------------------------------
template <int CIN, int LNF, int ACT, int STATS>
__global__ __launch_bounds__(256, 2) void gemm4_k(
    const u16* __restrict__ A1,
    const u16* __restrict__ Wt,
    const float* __restrict__ bias,
    const float* __restrict__ pst, const float* __restrict__ cs,
    u16* __restrict__ out,
    float* __restrict__ pso) {
  __shared__ float red[8];
  const int tid = threadIdx.x;
  const int m0 = blockIdx.x * 128;
  const int wid = tid >> 6, lane = tid & 63, fr = lane & 15, fg = lane >> 4;
  const int wmt = (wid & 1) * 64, wnc = (wid >> 1) * 64;

  f32x4 acc[4][4] = {};
  const u16* Arow = A1 + (size_t)(m0 + wmt + fr) * CIN;
  const u16* Brow = Wt + (size_t)(wnc + fr) * CIN;

  constexpr int NH = CIN / 128;
  u16x8 a[4][4];
#pragma unroll
  for (int h = 0; h < NH; ++h) {
#pragma unroll
    for (int ks = 0; ks < 4; ++ks) {
      const int kb = (h * 4 + ks) * 32 + fg * 8;
#pragma unroll
      for (int i = 0; i < 4; ++i)
        a[ks][i] = *(const u16x8*)(Arow + (size_t)i * 16 * CIN + kb);
    }
#pragma unroll
    for (int ks = 0; ks < 4; ++ks) {
      const int kb = (h * 4 + ks) * 32 + fg * 8;
      u16x8 b_[4];
#pragma unroll
      for (int j = 0; j < 4; ++j)
        b_[j] = *(const u16x8*)(Brow + (size_t)j * 16 * CIN + kb);
#pragma unroll
      for (int i = 0; i < 4; ++i)
#pragma unroll
        for (int j = 0; j < 4; ++j) acc[i][j] = mfma16(b_[j], a[ks][i], acc[i][j]);
    }
  }

  float alpha = 1.f, beta = 0.f;
  if constexpr (LNF) {
    const int s = m0 >> 14;
    const float inv_n = 1.f / 2097152.f;
    const float mean = pst[2 * s] * inv_n;
    const float var = pst[2 * s + 1] * inv_n - mean * mean;
    alpha = rsqrtf(var + 1e-5f);
    beta = -mean * alpha;
  }
  float s1 = 0.f, s2 = 0.f;
#pragma unroll
  for (int i = 0; i < 4; ++i) {
    const int token = m0 + wmt + i * 16 + fr;
#pragma unroll
    for (int j = 0; j < 4; ++j) {
      const int ch0 = wnc + j * 16 + fg * 4;
      const f32x4 bz = *(const f32x4*)(bias + ch0);
      f32x4 v = acc[i][j];
      if constexpr (LNF) {
        const f32x4 csv = *(const f32x4*)(cs + ch0);
#pragma unroll
        for (int r = 0; r < 4; ++r) v[r] = v[r] * alpha + beta * csv[r];
      }
      v += bz;
      if constexpr (ACT == 1) {
#pragma unroll
        for (int r = 0; r < 4; ++r) v[r] = fmaxf(v[r], 0.f);
      }
      if constexpr (ACT == 2) {
#pragma unroll
        for (int r = 0; r < 4; ++r) v[r] = gelu_erf(v[r]);
      }
      if constexpr (STATS) {
#pragma unroll
        for (int r = 0; r < 4; ++r) { s1 += v[r]; s2 += v[r] * v[r]; }
      }
      u16x4 sv;
#pragma unroll
      for (int r = 0; r < 4; ++r) sv[r] = f2bf(v[r]);
      *(u16x4*)(out + (size_t)token * 128 + ch0) = sv;
    }
  }
  if constexpr (STATS) {
#pragma unroll
    for (int off = 32; off > 0; off >>= 1) {
      s1 += __shfl_down(s1, off); s2 += __shfl_down(s2, off);
    }
    if (lane == 0) { red[wid] = s1; red[4 + wid] = s2; }
    __syncthreads();
    const int s = m0 >> 14;
    if (tid == 0)  atomicAdd(&pso[2 * s],     red[0] + red[1] + red[2] + red[3]);
    if (tid == 64) atomicAdd(&pso[2 * s + 1], red[4] + red[5] + red[6] + red[7]);
  }
}

// ---------------------------------------------------------------------------
// mlp3_k: FUSED gating t + spatial MLP.  Per block (ns, q2):
//   stage A: t[g][c] = gelu(LN(y1[T(g)])@w1[:,coff+c] + b1)  -> Ts[c][g] (LDS)
//   stage B: uv[T(d)][coff+c] = sum_g Ts[c][g] * w2[g][d] + b2[d]
// Ts = 64KB, byte ^= ((c&7)<<4) XOR swizzle.  512 threads (8 waves).
// MODE 0: grid MLP (u, ch 0:128); MODE 1: block MLP (v, ch 128:256).
// ---------------------------------------------------------------------------
template <int MODE>
__global__ __launch_bounds__(512, 2) void mlp3_k(
    const u16* __restrict__ y1, const u16* __restrict__ w1b,
    const float* __restrict__ b1, const float* __restrict__ pst,
    const float* __restrict__ csb,
    const u16* __restrict__ w2b, const float* __restrict__ b2,
    u16* __restrict__ uvout) {
  __shared__ u16 Ts[128 * 256];              // [c][g]
  const int q2 = blockIdx.x, ns = blockIdx.y;
  const int tid = threadIdx.x;
  constexpr int coff = MODE ? 128 : 0;
  const int wid = tid >> 6, lane = tid & 63, fr = lane & 15, fg = lane >> 4;
  const int xorl = (fr & 7) << 4;

  int pbase, prow, pcol;
  if constexpr (MODE == 0) {    // q=(gh*16+gw), fixed p2=(ph*8+pw)
    pbase = ns * 16384 + (q2 >> 3) * 128 + (q2 & 7);
    prow = 1024; pcol = 8;
  } else {                      // block cell fixed, q=(ph*16+pw)
    pbase = ns * 16384 + (q2 >> 3) * 2048 + (q2 & 7) * 16;
    prow = 128; pcol = 1;
  }
  auto pix = [&](int q) { return pbase + (q >> 4) * prow + (q & 15) * pcol; };

  // ---------------- stage A ----------------
  {
    const int wgt = (wid >> 1) * 64;     // g offset: 4 groups
    const int wc  = (wid & 1) * 64;      // c offset: 2 groups
    const float inv_n = 1.f / 2097152.f;
    const float mean = pst[2 * ns] * inv_n;
    const float var = pst[2 * ns + 1] * inv_n - mean * mean;
    const float alpha = rsqrtf(var + 1e-5f);
    const float beta = -mean * alpha;

    f32x4 acc[4][4] = {};
    const u16* ar[4];
#pragma unroll
    for (int i = 0; i < 4; ++i)
      ar[i] = y1 + (size_t)pix(wgt + i * 16 + fr) * 128;
    const u16* br = w1b + (size_t)(coff + wc + fr) * 128;

    u16x8 a[4][4];
#pragma unroll
    for (int ks = 0; ks < 4; ++ks) {
      const int kb = ks * 32 + fg * 8;
#pragma unroll
      for (int i = 0; i < 4; ++i) a[ks][i] = *(const u16x8*)(ar[i] + kb);
    }
#pragma unroll
    for (int ks = 0; ks < 4; ++ks) {
      const int kb = ks * 32 + fg * 8;
      u16x8 b_[4];
#pragma unroll
      for (int j = 0; j < 4; ++j)
        b_[j] = *(const u16x8*)(br + (size_t)j * 16 * 128 + kb);
#pragma unroll
      for (int i = 0; i < 4; ++i)
#pragma unroll
        for (int j = 0; j < 4; ++j) acc[i][j] = mfma16(a[ks][i], b_[j], acc[i][j]);
    }
    // row = g (fg*4+r), col = c (fr): write Ts[c][g0..g0+3]
#pragma unroll
    for (int j = 0; j < 4; ++j) {
      const int c = wc + j * 16 + fr;
      const float cv = csb[coff + c];
      const float bz = b1[coff + c];
#pragma unroll
      for (int i = 0; i < 4; ++i) {
        const int g0 = wgt + i * 16 + fg * 4;
        u16x4 sv;
#pragma unroll
        for (int r = 0; r < 4; ++r)
          sv[r] = f2bf(gelu_erf(acc[i][j][r] * alpha + beta * cv + bz));
        const int byte = (c * 512 + g0 * 2) ^ xorl;
        *(u16x4*)((char*)Ts + byte) = sv;
      }
    }
  }
  __syncthreads();

  // ---------------- stage B ----------------
  {
    const int wcs = (wid >> 2) * 64;     // c offset: 2 groups
    const int wds = (wid & 3) * 64;      // d offset: 4 groups
    f32x4 acc[4][4] = {};                // [i: c][j: d]
    const u16* br = w2b + (size_t)(wds + fr) * 256;
#pragma unroll
    for (int h = 0; h < 2; ++h) {
      u16x8 a[4][4];
#pragma unroll
      for (int ks = 0; ks < 4; ++ks) {
        const int kb = (h * 4 + ks) * 32 + fg * 8;
#pragma unroll
        for (int i = 0; i < 4; ++i) {
          const int c = wcs + i * 16 + fr;
          const int byte = (c * 512 + kb * 2) ^ xorl;
          a[ks][i] = *(const u16x8*)((const char*)Ts + byte);
        }
      }
#pragma unroll
      for (int ks = 0; ks < 4; ++ks) {
        const int kb = (h * 4 + ks) * 32 + fg * 8;
        u16x8 b_[4];
#pragma unroll
        for (int j = 0; j < 4; ++j)
          b_[j] = *(const u16x8*)(br + (size_t)j * 16 * 256 + kb);
#pragma unroll
        for (int i = 0; i < 4; ++i)
#pragma unroll
          for (int j = 0; j < 4; ++j) acc[i][j] = mfma16(a[ks][i], b_[j], acc[i][j]);
      }
    }
    // row = c (fg*4+r), col = d (fr): store 4 consecutive channels at pix(d)
#pragma unroll
    for (int j = 0; j < 4; ++j) {
      const int d = wds + j * 16 + fr;
      const float bz = b2[d];
      const size_t ob = (size_t)pix(d) * 256 + coff;
#pragma unroll
      for (int i = 0; i < 4; ++i) {
        const int c0 = wcs + i * 16 + fg * 4;
        u16x4 sv;
#pragma unroll
        for (int r = 0; r < 4; ++r) sv[r] = f2bf(acc[i][j][r] + bz);
        *(u16x4*)(uvout + ob + c0) = sv;
      }
    }
  }
}

// ---------------------------------------------------------------------------
// dual3_k: fused final THREE GEMMs (unchanged from r6).
// ---------------------------------------------------------------------------
__global__ __launch_bounds__(256, 2) void dual3_k(
    const u16* __restrict__ uv, const u16* __restrict__ g1w4b,
    const float* __restrict__ g1b4, const u16* __restrict__ y1,
    const u16* __restrict__ x1, const u16* __restrict__ gy,
    const u16* __restrict__ w3b, const u16* __restrict__ w4b,
    const float* __restrict__ b3, const float* __restrict__ b4,
    const u16* __restrict__ y0, const u16* __restrict__ x0,
    float* __restrict__ outy, float* __restrict__ outx) {
  __shared__ u16 Ls[128 * 136];
  const int tid = threadIdx.x;
  const int m0 = blockIdx.x * 128;
  const int wid = tid >> 6, lane = tid & 63, fr = lane & 15, fg = lane >> 4;
  const int wmt = (wid & 1) * 64, wnc = (wid >> 1) * 64;

  f32x4 acc[4][4] = {};
  u16x4 y9[4][4];

  // ---- pass 0: gx = uv @ g1w4 (CIN=256), y1g -> LDS
  {
    const u16* Arow = uv + (size_t)(m0 + wmt + fr) * 256;
    const u16* Brow = g1w4b + (size_t)(wnc + fr) * 256;
    u16x8 a[4][4];
#pragma unroll
    for (int h = 0; h < 2; ++h) {
#pragma unroll
      for (int ks = 0; ks < 4; ++ks) {
        const int kb = (h * 4 + ks) * 32 + fg * 8;
#pragma unroll
        for (int i = 0; i < 4; ++i)
          a[ks][i] = *(const u16x8*)(Arow + (size_t)i * 16 * 256 + kb);
      }
#pragma unroll
      for (int ks = 0; ks < 4; ++ks) {
        const int kb = (h * 4 + ks) * 32 + fg * 8;
        u16x8 b_[4];
#pragma unroll
        for (int j = 0; j < 4; ++j)
          b_[j] = *(const u16x8*)(Brow + (size_t)j * 16 * 256 + kb);
#pragma unroll
        for (int i = 0; i < 4; ++i)
#pragma unroll
          for (int j = 0; j < 4; ++j) acc[i][j] = mfma16(b_[j], a[ks][i], acc[i][j]);
      }
    }
    u16x4 mv[4][4];
#pragma unroll
    for (int i = 0; i < 4; ++i) {
      const int token = m0 + wmt + i * 16 + fr;
#pragma unroll
      for (int j = 0; j < 4; ++j)
        mv[i][j] = *(const u16x4*)(y1 + (size_t)token * 128 + wnc + j * 16 + fg * 4);
    }
#pragma unroll
    for (int i = 0; i < 4; ++i) {
      const int tok = wmt + i * 16 + fr;
#pragma unroll
      for (int j = 0; j < 4; ++j) {
        const int ch0 = wnc + j * 16 + fg * 4;
        const f32x4 bz = *(const f32x4*)(g1b4 + ch0);
        u16x4 sv;
#pragma unroll
        for (int r = 0; r < 4; ++r)
          sv[r] = f2bf((acc[i][j][r] + bz[r]) * bf2f(mv[i][j][r]));
        const int byte = (tok * 272 + ch0 * 2) ^ ((tok & 7) << 4);
        *(u16x4*)((char*)Ls + byte) = sv;
        acc[i][j] = f32x4{0.f, 0.f, 0.f, 0.f};
      }
    }
  }
  __syncthreads();

  // ---- pass 1: acc = y1g @ w3 (A from swizzled LDS)
  {
    const u16* Brow = w3b + (size_t)(wnc + fr) * 128;
#pragma unroll
    for (int ks = 0; ks < 4; ++ks) {
      const int kb = ks * 32 + fg * 8;
      u16x8 a_[4], b_[4];
#pragma unroll
      for (int i = 0; i < 4; ++i) {
        const int tok = wmt + i * 16 + fr;
        const int byte = (tok * 272 + kb * 2) ^ ((tok & 7) << 4);
        a_[i] = *(const u16x8*)((const char*)Ls + byte);
      }
#pragma unroll
      for (int j = 0; j < 4; ++j) b_[j] = *(const u16x8*)(Brow + (size_t)j * 16 * 128 + kb);
#pragma unroll
      for (int i = 0; i < 4; ++i)
#pragma unroll
        for (int j = 0; j < 4; ++j) acc[i][j] = mfma16(b_[j], a_[i], acc[i][j]);
    }
  }
  {
    u16x4 scv[4][4];
#pragma unroll
    for (int i = 0; i < 4; ++i) {
      const int token = m0 + wmt + i * 16 + fr;
#pragma unroll
      for (int j = 0; j < 4; ++j)
        scv[i][j] = *(const u16x4*)(y0 + (size_t)token * 128 + wnc + j * 16 + fg * 4);
    }
#pragma unroll
    for (int i = 0; i < 4; ++i) {
      const int token = m0 + wmt + i * 16 + fr;
      const int ns = token >> 14, p = token & 16383;
#pragma unroll
      for (int j = 0; j < 4; ++j) {
        const int ch0 = wnc + j * 16 + fg * 4;
        const f32x4 bz = *(const f32x4*)(b3 + ch0);
        f32x4 v = acc[i][j];
#pragma unroll
        for (int r = 0; r < 4; ++r) {
          v[r] += bz[r] + bf2f(scv[i][j][r]);
          outy[((size_t)(ns * 128 + ch0 + r) << 14) + p] = v[r];
          y9[i][j][r] = f2bf(v[r]);
        }
        acc[i][j] = f32x4{0.f, 0.f, 0.f, 0.f};
      }
    }
  }
  // ---- pass 2: acc = (x1*gy) @ w4
  {
    const u16* Arow  = x1 + (size_t)(m0 + wmt + fr) * 128;
    const u16* Arow2 = gy + (size_t)(m0 + wmt + fr) * 128;
    const u16* Brow  = w4b + (size_t)(wnc + fr) * 128;
    u16x8 a[4][4], a2[4][4];
#pragma unroll
    for (int ks = 0; ks < 4; ++ks) {
      const int kb = ks * 32 + fg * 8;
#pragma unroll
      for (int i = 0; i < 4; ++i) {
        a[ks][i]  = *(const u16x8*)(Arow  + (size_t)i * 16 * 128 + kb);
        a2[ks][i] = *(const u16x8*)(Arow2 + (size_t)i * 16 * 128 + kb);
      }
    }
#pragma unroll
    for (int ks = 0; ks < 4; ++ks) {
      const int kb = ks * 32 + fg * 8;
      u16x8 b_[4];
#pragma unroll
      for (int j = 0; j < 4; ++j) b_[j] = *(const u16x8*)(Brow + (size_t)j * 16 * 128 + kb);
      u16x8 am[4];
#pragma unroll
      for (int i = 0; i < 4; ++i) {
#pragma unroll
        for (int j = 0; j < 8; ++j) am[i][j] = f2bf(bf2f(a[ks][i][j]) * bf2f(a2[ks][i][j]));
      }
#pragma unroll
      for (int i = 0; i < 4; ++i)
#pragma unroll
        for (int j = 0; j < 4; ++j) acc[i][j] = mfma16(b_[j], am[i], acc[i][j]);
    }
  }
  {
    u16x4 scv[4][4];
#pragma unroll
    for (int i = 0; i < 4; ++i) {
      const int token = m0 + wmt + i * 16 + fr;
#pragma unroll
      for (int j = 0; j < 4; ++j)
        scv[i][j] = *(const u16x4*)(x0 + (size_t)token * 128 + wnc + j * 16 + fg * 4);
    }
#pragma unroll
    for (int i = 0; i < 4; ++i) {
      const int token = m0 + wmt + i * 16 + fr;
      const int ns = token >> 14, p = token & 16383;
#pragma unroll
      for (int j = 0; j < 4; ++j) {
        const int ch0 = wnc + j * 16 + fg * 4;
        const f32x4 bz = *(const f32x4*)(b4 + ch0);
        f32x4 v = acc[i][j];
#pragma unroll
        for (int r = 0; r < 4; ++r) {
          v[r] += bz[r] + bf2f(y9[i][j][r]) + bf2f(scv[i][j][r]);
          outx[((size_t)(ns * 128 + ch0 + r) << 14) + p] = v[r];
        }
      }
    }
  }
}

// ---------------------------------------------------------------------------
extern "C" void kernel_launch(void* const* d_in, const int* in_sizes, int n_in,
                              void* d_out, int out_size, void* d_ws, size_t ws_size,
                              hipStream_t stream) {
  (void)in_sizes; (void)n_in; (void)out_size; (void)ws_size;
  const float* xf   = (const float*)d_in[0];
  const float* yf   = (const float*)d_in[1];
  const float* wtf  = (const float*)d_in[2];
  const float* btf  = (const float*)d_in[3];
  const float* wc1f = (const float*)d_in[4];
  const float* bc1f = (const float*)d_in[5];
  const float* wc2f = (const float*)d_in[6];
  const float* bc2f = (const float*)d_in[7];
  const float* wl1f = (const float*)d_in[8];
  const float* bl1f = (const float*)d_in[9];
  const float* wl2f = (const float*)d_in[10];
  const float* bl2f = (const float*)d_in[11];
  const float* wl3f = (const float*)d_in[12];
  const float* bl3f = (const float*)d_in[13];
  const float* wl4f = (const float*)d_in[14];
  const float* bl4f = (const float*)d_in[15];
  const float* g1w1 = (const float*)d_in[16];
  const float* g1b1 = (const float*)d_in[17];
  const float* g1w2 = (const float*)d_in[18];
  const float* g1b2 = (const float*)d_in[19];
  const float* g1w3 = (const float*)d_in[20];
  const float* g1b3 = (const float*)d_in[21];
  const float* g1w4 = (const float*)d_in[22];
  const float* g1b4 = (const float*)d_in[23];
  const float* g2w1 = (const float*)d_in[24];
  const float* g2b1 = (const float*)d_in[25];
  const float* g2w2 = (const float*)d_in[26];
  const float* g2b2 = (const float*)d_in[27];
  const float* g2w3 = (const float*)d_in[28];
  const float* g2b3 = (const float*)d_in[29];
  const float* g2w4 = (const float*)d_in[30];
  const float* g2b4 = (const float*)d_in[31];

  constexpr int T16 = 16777216;
  u16* WS  = (u16*)d_ws;
  u16* x0b = WS;
  u16* x1b = WS + (size_t)T16;
  u16* y0b = WS + (size_t)2 * T16;
  u16* y1b = WS + (size_t)3 * T16;
  u16* gyb = WS + (size_t)4 * T16;
  u16* uvb = WS + (size_t)5 * T16;   // 2*T16
  float* fb = (float*)(WS + (size_t)7 * T16);
  float* cs = fb;                    // [0]=wl1 [256]=wl2 [512]=g1w1 [768]=g2w1
  float* ps = fb + 1024;             // stats slots (64 floats)
  u16* wb   = (u16*)(fb + 1024 + 64);
  float* ps0 = ps, *ps1 = ps + 16, *ps2 = ps + 32, *ps3 = ps + 48;

  const u16* wc1b = wb;
  const u16* wc2b = wb + 16384;
  const u16* wl1b = wb + 32768;
  const u16* wl2b = wb + 49152;
  const u16* wl3b = wb + 65536;
  const u16* wl4b = wb + 81920;
  const u16* g1w1b = wb + 98304;
  const u16* g2w1b = wb + 131072;
  const u16* g1w4b = wb + 163840;
  const u16* g2w4b = wb + 196608;
  const u16* g1w2b = wb + 229376;
  const u16* g2w2b = wb + 294912;
  const u16* g1w3b = wb + 360448;
  const u16* g2w3b = wb + 425984;
  const u16* wtb   = wb + 491520;

  u16* tb    = (u16*)d_out;          // yup scratch (dead before final writes)
  float* outx = (float*)d_out;
  float* outy = (float*)d_out + (size_t)T16;

  const dim3 B256(256), B512(512);

  // 1) one-shot weight prep
  prep_k<<<dim3(2437), B256, 0, stream>>>(
      wc1f, wc2f, wl1f, wl2f, wl3f, wl4f, g1w1, g2w1, g1w4, g2w4,
      g1w2, g2w2, g1w3, g2w3, wtf, wb, cs, ps);

  // 2) ConvT direct from y fp32 -> yup (tb, NHWC bf16)
  gemmY_k<<<dim3(256, 4), B256, 0, stream>>>(yf, wtb, btf, tb);
  // 3) x0 = relu(x@wc1+bc1) direct from x fp32  [stats->ps0]
  gemmX_k<<<dim3(1024), B256, 0, stream>>>(xf, wc1b, bc1f, x0b, ps0);
  //    y0 = relu(yup@wc2+bc2)  [stats->ps1]
  gemm4_k<128, 0, 1, 1><<<dim3(1024), B256, 0, stream>>>(
      tb, wc2b, bc2f, nullptr, nullptr, y0b, ps1);

  // 4) y1 = gelu(LN(y0)@wl2+bl2)  [stats->ps3]
  gemm4_k<128, 1, 2, 1><<<dim3(1024), B256, 0, stream>>>(
      y0b, wl2b, bl2f, ps1, cs + 256, y1b, ps3);
  // 5) y gating: fused t+grid-MLP and t+block-MLP
  mlp3_k<0><<<dim3(64, 8), B512, 0, stream>>>(
      y1b, g2w1b, g2b1, ps3, cs + 768, g2w2b, g2b2, uvb);
  mlp3_k<1><<<dim3(64, 8), B512, 0, stream>>>(
      y1b, g2w1b, g2b1, ps3, cs + 768, g2w3b, g2b3, uvb);
  //    gy = uv @ g2w4 + g2b4
  gemm4_k<256, 0, 0, 0><<<dim3(1024), B256, 0, stream>>>(
      uvb, g2w4b, g2b4, nullptr, nullptr, gyb, nullptr);

  // 6) x1 = gelu(LN(x0)@wl1+bl1)  [stats->ps2]
  gemm4_k<128, 1, 2, 1><<<dim3(1024), B256, 0, stream>>>(
      x0b, wl1b, bl1f, ps0, cs, x1b, ps2);
  // 7) x gating
  mlp3_k<0><<<dim3(64, 8), B512, 0, stream>>>(
      x1b, g1w1b, g1b1, ps2, cs + 512, g1w2b, g1b2, uvb);
  mlp3_k<1><<<dim3(64, 8), B512, 0, stream>>>(
      x1b, g1w1b, g1b1, ps2, cs + 512, g1w3b, g1b3, uvb);

  // 8+9+10) fused: gx in-reg, y_out -> outy, x_out -> outx (fp32 NCHW)
  dual3_k<<<dim3(1024), B256, 0, stream>>>(
      uvb, g1w4b, g1b4, y1b, x1b, gyb, wl3b, wl4b, bl3f, bl4f,
      y0b, x0b, outy, outx);
}

// Round 8
// 570.591 us; speedup vs baseline: 1.5057x; 1.0712x over previous
//
#include <hip/hip_runtime.h>
#include <hip/hip_bf16.h>

// ---------------------------------------------------------------------------
// CrossGatingBlock on MI355X (gfx950).  Round 8.
// - mlp3b: stage C fuses the g_w4 GEMM into the spatial-MLP kernel.  uv is
//   never materialized: mode0 writes bf16 partial g (+bias), mode1 completes
//   it in place (disjoint pixel sets; stream-ordered).
// - gemmY2: ConvT(k2,s2)+bt+relu+wc2+bc2+relu+stats fused; yup eliminated.
// - dual5: LDS-free, barrier-free 2-pass finale (A = y1*gx then x1*gy as
//   elementwise fragment products; y_out in regs).
// ---------------------------------------------------------------------------

typedef unsigned short u16;
typedef __bf16 bf16x8 __attribute__((ext_vector_type(8)));
typedef u16    u16x8  __attribute__((ext_vector_type(8)));
typedef u16    u16x4  __attribute__((ext_vector_type(4)));
typedef float  f32x4  __attribute__((ext_vector_type(4)));

__device__ __forceinline__ float bf2f(u16 u) {
  union { float f; unsigned int i; } v; v.i = ((unsigned int)u) << 16; return v.f;
}
__device__ __forceinline__ u16 f2bf(float f) {   // RNE
  union { float f; unsigned int i; } v; v.f = f;
  unsigned int x = v.i;
  return (u16)((x + 0x7fffu + ((x >> 16) & 1u)) >> 16);
}
__device__ __forceinline__ f32x4 mfma16(u16x8 a, u16x8 b, f32x4 c) {
  return __builtin_amdgcn_mfma_f32_16x16x32_bf16(
      __builtin_bit_cast(bf16x8, a), __builtin_bit_cast(bf16x8, b), c, 0, 0, 0);
}
__device__ __forceinline__ float gelu_erf(float v) {
  return 0.5f * v * (1.0f + erff(v * 0.70710678118654752f));
}

// ---------------------------------------------------------------------------
// prep_k: all weight transposes (fp32 [k][d] -> bf16 [d][k]) + 4 LN colsums
// + stats zeroing in one dispatch.  grid 2437, block 256.
// ---------------------------------------------------------------------------
__global__ __launch_bounds__(256) void prep_k(
    const float* __restrict__ wc1f, const float* __restrict__ wc2f,
    const float* __restrict__ wl1f, const float* __restrict__ wl2f,
    const float* __restrict__ wl3f, const float* __restrict__ wl4f,
    const float* __restrict__ g1w1, const float* __restrict__ g2w1,
    const float* __restrict__ g1w4, const float* __restrict__ g2w4,
    const float* __restrict__ g1w2, const float* __restrict__ g2w2,
    const float* __restrict__ g1w3, const float* __restrict__ g2w3,
    const float* __restrict__ wtf,
    u16* __restrict__ wb, float* __restrict__ cs, float* __restrict__ ps) {
  const int b = blockIdx.x, t = threadIdx.x;
  if (b < 384) {                       // 6x [128][128]
    const float* src = b < 64 ? wc1f : b < 128 ? wc2f : b < 192 ? wl1f
                     : b < 256 ? wl2f : b < 320 ? wl3f : wl4f;
    const int w = b >> 6;
    const int i = ((b & 63) << 8) + t;           // < 16384
    const int d = i >> 7, c = i & 127;
    wb[w * 16384 + i] = f2bf(src[c * 128 + d]);
  } else if (b < 640) {                // g1w1/g2w1 [128][256] -> [256][128]
    const float* src = b < 512 ? g1w1 : g2w1;
    const int base = b < 512 ? 98304 : 131072;
    const int i = (((b - (b < 512 ? 384 : 512)) << 8) + t);  // < 32768
    const int d = i >> 7, c = i & 127;
    wb[base + i] = f2bf(src[c * 256 + d]);
  } else if (b < 896) {                // g1w4/g2w4 [256][128] -> [128][256]
    const float* src = b < 768 ? g1w4 : g2w4;
    const int base = b < 768 ? 163840 : 196608;
    const int i = (((b - (b < 768 ? 640 : 768)) << 8) + t);  // < 32768
    const int d = i >> 8, c = i & 255;
    wb[base + i] = f2bf(src[c * 128 + d]);
  } else if (b < 1920) {               // 4x [256][256] transpose
    const int w = (b - 896) >> 8;                 // 0..3
    const float* src = w == 0 ? g1w2 : w == 1 ? g2w2 : w == 2 ? g1w3 : g2w3;
    const int base = 229376 + w * 65536;
    const int i = (((b - 896) & 255) << 8) + t;   // < 65536
    const int d = i >> 8, g = i & 255;
    wb[base + i] = f2bf(src[g * 256 + d]);
  } else if (b < 2432) {               // wtb[kl*128+o][c] from wt(c,o,kh,kw)
    const int i = ((b - 1920) << 8) + t;          // < 131072
    const int c = i & 255, r = i >> 8, o = r & 127, kl = r >> 7;
    wb[491520 + i] = f2bf(wtf[(c * 128 + o) * 4 + kl]);
  } else if (b < 2436) {               // colsums (bf16-rounded)
    const int w = b - 2432;
    const float* src = w == 0 ? wl1f : w == 1 ? wl2f : w == 2 ? g1w1 : g2w1;
    const int cout = w < 2 ? 128 : 256;
    if (t < cout) {
      float s = 0.f;
      for (int c = 0; c < 128; ++c) s += bf2f(f2bf(src[c * cout + t]));
      cs[w * 256 + t] = s;
    }
  } else {                             // zero stats slots
    if (t < 64) ps[t] = 0.f;
  }
}

// ---------------------------------------------------------------------------
// gemmX_k: x0 = relu(x_nchw_fp32 @ wc1 + bc1) + LN stats.  (unchanged r7)
// ---------------------------------------------------------------------------
__global__ __launch_bounds__(256, 2) void gemmX_k(
    const float* __restrict__ X, const u16* __restrict__ Wt,
    const float* __restrict__ bias, u16* __restrict__ out,
    float* __restrict__ pso) {
  __shared__ u16 As[128 * 136];
  __shared__ float red[8];
  const int tid = threadIdx.x;
  const int m0 = blockIdx.x * 128;
  const int ns = m0 >> 14, pb = m0 & 16383;
  const int wid = tid >> 6, lane = tid & 63, fr = lane & 15, fg = lane >> 4;
  const int wmt = (wid & 1) * 64, wnc = (wid >> 1) * 64;

#pragma unroll
  for (int it = 0; it < 16; ++it) {
    const int idx = it * 256 + tid;          // < 4096
    const int c = idx & 127, t4 = idx >> 7;  // t4 0..31
    const f32x4 v = *(const f32x4*)(X + (((size_t)(ns * 128 + c)) << 14) + pb + t4 * 4);
#pragma unroll
    for (int r = 0; r < 4; ++r) As[(t4 * 4 + r) * 136 + c] = f2bf(v[r]);
  }
  __syncthreads();

  f32x4 acc[4][4] = {};
  const u16* Brow = Wt + (size_t)(wnc + fr) * 128;
  u16x8 a[4][4];
#pragma unroll
  for (int ks = 0; ks < 4; ++ks) {
    const int kb = ks * 32 + fg * 8;
#pragma unroll
    for (int i = 0; i < 4; ++i)
      a[ks][i] = *(const u16x8*)(As + (wmt + i * 16 + fr) * 136 + kb);
  }
#pragma unroll
  for (int ks = 0; ks < 4; ++ks) {
    const int kb = ks * 32 + fg * 8;
    u16x8 b_[4];
#pragma unroll
    for (int j = 0; j < 4; ++j)
      b_[j] = *(const u16x8*)(Brow + (size_t)j * 16 * 128 + kb);
#pragma unroll
    for (int i = 0; i < 4; ++i)
#pragma unroll
      for (int j = 0; j < 4; ++j) acc[i][j] = mfma16(b_[j], a[ks][i], acc[i][j]);
  }

  float s1 = 0.f, s2 = 0.f;
#pragma unroll
  for (int i = 0; i < 4; ++i) {
    const int token = m0 + wmt + i * 16 + fr;
#pragma unroll
    for (int j = 0; j < 4; ++j) {
      const int ch0 = wnc + j * 16 + fg * 4;
      const f32x4 bz = *(const f32x4*)(bias + ch0);
      f32x4 v = acc[i][j];
      u16x4 sv;
#pragma unroll
      for (int r = 0; r < 4; ++r) {
        v[r] = fmaxf(v[r] + bz[r], 0.f);
        s1 += v[r]; s2 += v[r] * v[r];
        sv[r] = f2bf(v[r]);
      }
      *(u16x4*)(out + (size_t)token * 128 + ch0) = sv;
    }
  }
#pragma unroll
  for (int off = 32; off > 0; off >>= 1) {
    s1 += __shfl_down(s1, off); s2 += __shfl_down(s2, off);
  }
  if (lane == 0) { red[wid] = s1; red[4 + wid] = s2; }
  __syncthreads();
  if (tid == 0)  atomicAdd(&pso[2 * ns],     red[0] + red[1] + red[2] + red[3]);
  if (tid == 64) atomicAdd(&pso[2 * ns + 1], red[4] + red[5] + red[6] + red[7]);
}

// ---------------------------------------------------------------------------
// gemmY2_k: FUSED  y0 = relu( relu(ConvT(y)+bt) @ wc2 + bc2 ) + LN stats.
// 64 y-tokens per block (grid 512).  y fp32 NCHW -> As (swizzled LDS);
// per kl: conv tile (K=256) -> Cs; conv1x1 (K=128) -> y0 at scattered opix.
// ---------------------------------------------------------------------------
__global__ __launch_bounds__(256, 2) void gemmY2_k(
    const float* __restrict__ Y, const u16* __restrict__ Wtb,
    const float* __restrict__ bt, const u16* __restrict__ Wc2,
    const float* __restrict__ bc2, u16* __restrict__ out,
    float* __restrict__ pso) {
  __shared__ u16 As[64 * 256];    // [tok][c], byte ^= (tok&7)<<4   (32KB)
  __shared__ u16 Cs[64 * 136];    // [tok][o]                        (17KB)
  __shared__ float red[8];
  const int tid = threadIdx.x;
  const int m0 = blockIdx.x * 64;            // y-token base
  const int ns = m0 >> 12, pb = m0 & 4095;
  const int wid = tid >> 6, lane = tid & 63, fr = lane & 15, fg = lane >> 4;
  const int tokg = (wid & 1) * 32;           // 2 token groups of 32
  const int chg  = (wid >> 1) * 64;          // 2 channel groups of 64
  const int xorl = (fr & 7) << 4;

  // stage As: transpose y fp32 NCHW -> bf16 [tok][256]
#pragma unroll
  for (int it = 0; it < 16; ++it) {
    const int idx = it * 256 + tid;          // < 4096
    const int c = idx & 255, t4 = idx >> 8;  // t4 0..15
    const f32x4 v = *(const f32x4*)(Y + (((size_t)(ns * 256 + c)) << 12) + pb + t4 * 4);
#pragma unroll
    for (int r = 0; r < 4; ++r) {
      const int tok = t4 * 4 + r;
      const int byte = (tok * 512 + c * 2) ^ ((tok & 7) << 4);
      *(u16*)((char*)As + byte) = f2bf(v[r]);
    }
  }
  __syncthreads();

  float s1 = 0.f, s2 = 0.f;
  for (int kl = 0; kl < 4; ++kl) {
    if (kl) __syncthreads();                 // protect Cs from prior reads
    // conv: acc1[tok 2x16][o 4x16] = As @ wtb_kl  (K=256)
    f32x4 acc1[2][4] = {};
    {
      const u16* Brow = Wtb + (size_t)(kl * 128 + chg + fr) * 256;
#pragma unroll
      for (int ks = 0; ks < 8; ++ks) {
        const int kb = ks * 32 + fg * 8;
        u16x8 a_[2], b_[4];
#pragma unroll
        for (int i = 0; i < 2; ++i) {
          const int tok = tokg + i * 16 + fr;
          const int byte = (tok * 512 + kb * 2) ^ xorl;
          a_[i] = *(const u16x8*)((const char*)As + byte);
        }
#pragma unroll
        for (int j = 0; j < 4; ++j)
          b_[j] = *(const u16x8*)(Brow + (size_t)j * 16 * 256 + kb);
#pragma unroll
        for (int i = 0; i < 2; ++i)
#pragma unroll
          for (int j = 0; j < 4; ++j) acc1[i][j] = mfma16(b_[j], a_[i], acc1[i][j]);
      }
    }
    // epilogue conv: relu(acc1 + bt) -> Cs[tok][o]
#pragma unroll
    for (int i = 0; i < 2; ++i) {
      const int tok = tokg + i * 16 + fr;
#pragma unroll
      for (int j = 0; j < 4; ++j) {
        const int o0 = chg + j * 16 + fg * 4;
        const f32x4 bz = *(const f32x4*)(bt + o0);
        u16x4 sv;
#pragma unroll
        for (int r = 0; r < 4; ++r) sv[r] = f2bf(fmaxf(acc1[i][j][r] + bz[r], 0.f));
        *(u16x4*)(Cs + tok * 136 + o0) = sv;
      }
    }
    __syncthreads();
    // conv1x1: acc2 = Cs @ wc2 (K=128), relu, stats, scatter-store
    f32x4 acc2[2][4] = {};
    {
      const u16* Brow = Wc2 + (size_t)(chg + fr) * 128;
#pragma unroll
      for (int ks = 0; ks < 4; ++ks) {
        const int kb = ks * 32 + fg * 8;
        u16x8 a_[2], b_[4];
#pragma unroll
        for (int i = 0; i < 2; ++i)
          a_[i] = *(const u16x8*)(Cs + (tokg + i * 16 + fr) * 136 + kb);
#pragma unroll
        for (int j = 0; j < 4; ++j)
          b_[j] = *(const u16x8*)(Brow + (size_t)j * 16 * 128 + kb);
#pragma unroll
        for (int i = 0; i < 2; ++i)
#pragma unroll
          for (int j = 0; j < 4; ++j) acc2[i][j] = mfma16(b_[j], a_[i], acc2[i][j]);
      }
    }
#pragma unroll
    for (int i = 0; i < 2; ++i) {
      const int ytok = m0 + tokg + i * 16 + fr;
      const int hy = (ytok >> 6) & 63, wy = ytok & 63;
      const int opix = ((ns * 128 + 2 * hy + (kl >> 1)) << 7) + 2 * wy + (kl & 1);
#pragma unroll
      for (int j = 0; j < 4; ++j) {
        const int ch0 = chg + j * 16 + fg * 4;
        const f32x4 bz = *(const f32x4*)(bc2 + ch0);
        u16x4 sv;
#pragma unroll
        for (int r = 0; r < 4; ++r) {
          float v = fmaxf(acc2[i][j][r] + bz[r], 0.f);
          s1 += v; s2 += v * v;
          sv[r] = f2bf(v);
        }
        *(u16x4*)(out + (size_t)opix * 128 + ch0) = sv;
      }
    }
  }
#pragma unroll
  for (int off = 32; off > 0; off >>= 1) {
    s1 += __shfl_down(s1, off); s2 += __shfl_down(s2, off);
  }
  if (lane == 0) { red[wid] = s1; red[4 + wid] = s2; }
  __syncthreads();
  if (tid == 0)  atomicAdd(&pso[2 * ns],     red[0] + red[1] + red[2] + red[3]);
  if (tid == 64) atomicAdd(&pso[2 * ns + 1], red[4] + red[5] + red[6] + red[7]);
}

// ---------------------------------------------------------------------------
// gemm4_k: barrier-free CIN=128 GEMM (y1/x1 producers).  (r6 structure)
// ---------------------------------------------------------------------------
template <int LNF>
__global__ __launch_bounds__(256, 2) void gemm4_k(
    const u16* __restrict__ A1, const u16* __restrict__ Wt,
    const float* __restrict__ bias,
    const float* __restrict__ pst, const float* __restrict__ cs,
    u16* __restrict__ out, float* __restrict__ pso) {
  __shared__ float red[8];
  const int tid = threadIdx.x;
  const int m0 = blockIdx.x * 128;
  const int wid = tid >> 6, lane = tid & 63, fr = lane & 15, fg = lane >> 4;
  const int wmt = (wid & 1) * 64, wnc = (wid >> 1) * 64;

  f32x4 acc[4][4] = {};
  const u16* Arow = A1 + (size_t)(m0 + wmt + fr) * 128;
  const u16* Brow = Wt + (size_t)(wnc + fr) * 128;

  u16x8 a[4][4];
#pragma unroll
  for (int ks = 0; ks < 4; ++ks) {
    const int kb = ks * 32 + fg * 8;
#pragma unroll
    for (int i = 0; i < 4; ++i)
      a[ks][i] = *(const u16x8*)(Arow + (size_t)i * 16 * 128 + kb);
  }
#pragma unroll
  for (int ks = 0; ks < 4; ++ks) {
    const int kb = ks * 32 + fg * 8;
    u16x8 b_[4];
#pragma unroll
    for (int j = 0; j < 4; ++j)
      b_[j] = *(const u16x8*)(Brow + (size_t)j * 16 * 128 + kb);
#pragma unroll
    for (int i = 0; i < 4; ++i)
#pragma unroll
      for (int j = 0; j < 4; ++j) acc[i][j] = mfma16(b_[j], a[ks][i], acc[i][j]);
  }

  float alpha = 1.f, beta = 0.f;
  if constexpr (LNF) {
    const int s = m0 >> 14;
    const float inv_n = 1.f / 2097152.f;
    const float mean = pst[2 * s] * inv_n;
    const float var = pst[2 * s + 1] * inv_n - mean * mean;
    alpha = rsqrtf(var + 1e-5f);
    beta = -mean * alpha;
  }
  float s1 = 0.f, s2 = 0.f;
#pragma unroll
  for (int i = 0; i < 4; ++i) {
    const int token = m0 + wmt + i * 16 + fr;
#pragma unroll
    for (int j = 0; j < 4; ++j) {
      const int ch0 = wnc + j * 16 + fg * 4;
      const f32x4 bz = *(const f32x4*)(bias + ch0);
      const f32x4 csv = *(const f32x4*)(cs + ch0);
      f32x4 v = acc[i][j];
      u16x4 sv;
#pragma unroll
      for (int r = 0; r < 4; ++r) {
        v[r] = v[r] * alpha + beta * csv[r] + bz[r];
        v[r] = gelu_erf(v[r]);
        s1 += v[r]; s2 += v[r] * v[r];
        sv[r] = f2bf(v[r]);
      }
      *(u16x4*)(out + (size_t)token * 128 + ch0) = sv;
    }
  }
#pragma unroll
  for (int off = 32; off > 0; off >>= 1) {
    s1 += __shfl_down(s1, off); s2 += __shfl_down(s2, off);
  }
  if (lane == 0) { red[wid] = s1; red[4 + wid] = s2; }
  __syncthreads();
  const int s = m0 >> 14;
  if (tid == 0)  atomicAdd(&pso[2 * s],     red[0] + red[1] + red[2] + red[3]);
  if (tid == 64) atomicAdd(&pso[2 * s + 1], red[4] + red[5] + red[6] + red[7]);
}

// ---------------------------------------------------------------------------
// mlp3b_k: FUSED gating chain for one channel-half:
//   stage A: t[g][c] = gelu(LN(y1[P(g)])@w1[:,coff+c]+b1)      -> Ts (LDS)
//   stage B: m[d][c]  = sum_g t[g][c] w2[g][d] + b2[d]          (in regs)
//            -> Ts reused as Ts2[d][c]
//   stage C: gpart[P(d)][o] (+)= sum_c m[d][c] w4[coff+c][o] (+b4 if MODE0)
// MODE 0 writes g partial; MODE 1 adds MODE 0's partial in place.
// ---------------------------------------------------------------------------
template <int MODE>
__global__ __launch_bounds__(512, 2) void mlp3b_k(
    const u16* __restrict__ y1, const u16* __restrict__ w1b,
    const float* __restrict__ b1, const float* __restrict__ pst,
    const float* __restrict__ csb,
    const u16* __restrict__ w2b, const float* __restrict__ b2,
    const u16* __restrict__ w4b, const float* __restrict__ b4,
    u16* __restrict__ gout) {
  __shared__ u16 Ts[34816];     // A/B: [c 128][g 256] (64KB); C: [d 256][136]
  const int q2 = blockIdx.x, ns = blockIdx.y;
  const int tid = threadIdx.x;
  constexpr int coff = MODE ? 128 : 0;
  const int wid = tid >> 6, lane = tid & 63, fr = lane & 15, fg = lane >> 4;
  const int xorl = (fr & 7) << 4;

  int pbase, prow, pcol;
  if constexpr (MODE == 0) {    // q=(gh*16+gw), fixed p2=(ph*8+pw)
    pbase = ns * 16384 + (q2 >> 3) * 128 + (q2 & 7);
    prow = 1024; pcol = 8;
  } else {                      // block cell fixed, q=(ph*16+pw)
    pbase = ns * 16384 + (q2 >> 3) * 2048 + (q2 & 7) * 16;
    prow = 128; pcol = 1;
  }
  auto pix = [&](int q) { return pbase + (q >> 4) * prow + (q & 15) * pcol; };

  // ---------------- stage A: t -> Ts[c][g] ----------------
  {
    const int wgt = (wid >> 1) * 64;     // g: 4 groups
    const int wc  = (wid & 1) * 64;      // c: 2 groups
    const float inv_n = 1.f / 2097152.f;
    const float mean = pst[2 * ns] * inv_n;
    const float var = pst[2 * ns + 1] * inv_n - mean * mean;
    const float alpha = rsqrtf(var + 1e-5f);
    const float beta = -mean * alpha;

    f32x4 acc[4][4] = {};
    const u16* ar[4];
#pragma unroll
    for (int i = 0; i < 4; ++i)
      ar[i] = y1 + (size_t)pix(wgt + i * 16 + fr) * 128;
    const u16* br = w1b + (size_t)(coff + wc + fr) * 128;

    u16x8 a[4][4];
#pragma unroll
    for (int ks = 0; ks < 4; ++ks) {
      const int kb = ks * 32 + fg * 8;
#pragma unroll
      for (int i = 0; i < 4; ++i) a[ks][i] = *(const u16x8*)(ar[i] + kb);
    }
#pragma unroll
    for (int ks = 0; ks < 4; ++ks) {
      const int kb = ks * 32 + fg * 8;
      u16x8 b_[4];
#pragma unroll
      for (int j = 0; j < 4; ++j)
        b_[j] = *(const u16x8*)(br + (size_t)j * 16 * 128 + kb);
#pragma unroll
      for (int i = 0; i < 4; ++i)
#pragma unroll
        for (int j = 0; j < 4; ++j) acc[i][j] = mfma16(a[ks][i], b_[j], acc[i][j]);
    }
    // D row = g (fg*4+r), col = c (fr): write Ts[c][g0..3]
#pragma unroll
    for (int j = 0; j < 4; ++j) {
      const int c = wc + j * 16 + fr;
      const float cv = csb[coff + c];
      const float bz = b1[coff + c];
#pragma unroll
      for (int i = 0; i < 4; ++i) {
        const int g0 = wgt + i * 16 + fg * 4;
        u16x4 sv;
#pragma unroll
        for (int r = 0; r < 4; ++r)
          sv[r] = f2bf(gelu_erf(acc[i][j][r] * alpha + beta * cv + bz));
        const int byte = (c * 512 + g0 * 2) ^ xorl;
        *(u16x4*)((char*)Ts + byte) = sv;
      }
    }
  }
  __syncthreads();

  // ---------------- stage B: m[d][c] in regs ----------------
  f32x4 accB[4][4];             // [i: c-sub][j: d-sub]
  const int wcs = (wid >> 2) * 64;     // c: 2 groups
  const int wds = (wid & 3) * 64;      // d: 4 groups
  {
#pragma unroll
    for (int i = 0; i < 4; ++i)
#pragma unroll
      for (int j = 0; j < 4; ++j) accB[i][j] = f32x4{0.f, 0.f, 0.f, 0.f};
    const u16* br = w2b + (size_t)(wds + fr) * 256;
#pragma unroll
    for (int h = 0; h < 2; ++h) {
      u16x8 a[4][4];
#pragma unroll
      for (int ks = 0; ks < 4; ++ks) {
        const int kb = (h * 4 + ks) * 32 + fg * 8;
#pragma unroll
        for (int i = 0; i < 4; ++i) {
          const int c = wcs + i * 16 + fr;
          const int byte = (c * 512 + kb * 2) ^ xorl;
          a[ks][i] = *(const u16x8*)((const char*)Ts + byte);
        }
      }
#pragma unroll
      for (int ks = 0; ks < 4; ++ks) {
        const int kb = (h * 4 + ks) * 32 + fg * 8;
        u16x8 b_[4];
#pragma unroll
        for (int j = 0; j < 4; ++j)
          b_[j] = *(const u16x8*)(br + (size_t)j * 16 * 256 + kb);
#pragma unroll
        for (int i = 0; i < 4; ++i)
#pragma unroll
          for (int j = 0; j < 4; ++j) accB[i][j] = mfma16(a[ks][i], b_[j], accB[i][j]);
      }
    }
  }
  __syncthreads();              // all Ts reads done before re-use as Ts2

  // write m -> Ts2[d][c]: D row = c (fg*4+r), col = d (fr)
#pragma unroll
  for (int j = 0; j < 4; ++j) {
    const int d = wds + j * 16 + fr;
    const float bz = b2[d];
#pragma unroll
    for (int i = 0; i < 4; ++i) {
      const int c0 = wcs + i * 16 + fg * 4;
      u16x4 sv;
#pragma unroll
      for (int r = 0; r < 4; ++r) sv[r] = f2bf(accB[i][j][r] + bz);
      *(u16x4*)(Ts + d * 136 + c0) = sv;
    }
  }
  __syncthreads();

  // ---------------- stage C: gpart = Ts2 @ w4half ----------------
  {
    const int wp = (wid >> 1) * 64;    // pixel-d: 4 groups
    const int wo = (wid & 1) * 64;     // o: 2 groups
    f32x4 accC[4][4] = {};             // [i: pix][j: o]
    const u16* br = w4b + (size_t)(wo + fr) * 256 + coff;
#pragma unroll
    for (int ks = 0; ks < 4; ++ks) {
      const int kb = ks * 32 + fg * 8;
      u16x8 a_[4], b_[4];
#pragma unroll
      for (int i = 0; i < 4; ++i)
        a_[i] = *(const u16x8*)(Ts + (wp + i * 16 + fr) * 136 + kb);
#pragma unroll
      for (int j = 0; j < 4; ++j)
        b_[j] = *(const u16x8*)(br + (size_t)j * 16 * 256 + kb);
#pragma unroll
      for (int i = 0; i < 4; ++i)
#pragma unroll
        for (int j = 0; j < 4; ++j) accC[i][j] = mfma16(b_[j], a_[i], accC[i][j]);
    }
    // D row = o (fg*4+r), col = pix (fr)
#pragma unroll
    for (int i = 0; i < 4; ++i) {
      const size_t pg = (size_t)pix(wp + i * 16 + fr) * 128;
#pragma unroll
      for (int j = 0; j < 4; ++j) {
        const int o0 = wo + j * 16 + fg * 4;
        f32x4 v = accC[i][j];
        u16x4 sv;
        if constexpr (MODE == 0) {
          const f32x4 bz = *(const f32x4*)(b4 + o0);
#pragma unroll
          for (int r = 0; r < 4; ++r) sv[r] = f2bf(v[r] + bz[r]);
        } else {
          const u16x4 pv = *(const u16x4*)(gout + pg + o0);
#pragma unroll
          for (int r = 0; r < 4; ++r) sv[r] = f2bf(v[r] + bf2f(pv[r]));
        }
        *(u16x4*)(gout + pg + o0) = sv;
      }
    }
  }
}

// ---------------------------------------------------------------------------
// dual5_k: LDS-free, barrier-free finale.
//   y_out = (y1*gx)@w3 + b3 + y0        -> outy fp32 NCHW
//   x_out = (x1*gy)@w4 + b4 + y_out + x0 -> outx fp32 NCHW
// ---------------------------------------------------------------------------
__global__ __launch_bounds__(256, 2) void dual5_k(
    const u16* __restrict__ y1, const u16* __restrict__ gx,
    const u16* __restrict__ x1, const u16* __restrict__ gy,
    const u16* __restrict__ w3b, const u16* __restrict__ w4b,
    const float* __restrict__ b3, const float* __restrict__ b4,
    const u16* __restrict__ y0, const u16* __restrict__ x0,
    float* __restrict__ outy, float* __restrict__ outx) {
  const int tid = threadIdx.x;
  const int m0 = blockIdx.x * 128;
  const int wid = tid >> 6, lane = tid & 63, fr = lane & 15, fg = lane >> 4;
  const int wmt = (wid & 1) * 64, wnc = (wid >> 1) * 64;

  f32x4 acc[4][4] = {};
  u16x4 y9[4][4];

  // ---- pass 1: acc = (y1*gx) @ w3
  {
    const u16* Arow  = y1 + (size_t)(m0 + wmt + fr) * 128;
    const u16* Arow2 = gx + (size_t)(m0 + wmt + fr) * 128;
    const u16* Brow  = w3b + (size_t)(wnc + fr) * 128;
    u16x8 a[4][4], a2[4][4];
#pragma unroll
    for (int ks = 0; ks < 4; ++ks) {
      const int kb = ks * 32 + fg * 8;
#pragma unroll
      for (int i = 0; i < 4; ++i) {
        a[ks][i]  = *(const u16x8*)(Arow  + (size_t)i * 16 * 128 + kb);
        a2[ks][i] = *(const u16x8*)(Arow2 + (size_t)i * 16 * 128 + kb);
      }
    }
#pragma unroll
    for (int ks = 0; ks < 4; ++ks) {
      const int kb = ks * 32 + fg * 8;
      u16x8 b_[4];
#pragma unroll
      for (int j = 0; j < 4; ++j) b_[j] = *(const u16x8*)(Brow + (size_t)j * 16 * 128 + kb);
      u16x8 am[4];
#pragma unroll
      for (int i = 0; i < 4; ++i)
#pragma unroll
        for (int j = 0; j < 8; ++j) am[i][j] = f2bf(bf2f(a[ks][i][j]) * bf2f(a2[ks][i][j]));
#pragma unroll
      for (int i = 0; i < 4; ++i)
#pragma unroll
        for (int j = 0; j < 4; ++j) acc[i][j] = mfma16(b_[j], am[i], acc[i][j]);
    }
  }
  // epilogue 1
  {
    u16x4 scv[4][4];
#pragma unroll
    for (int i = 0; i < 4; ++i) {
      const int token = m0 + wmt + i * 16 + fr;
#pragma unroll
      for (int j = 0; j < 4; ++j)
        scv[i][j] = *(const u16x4*)(y0 + (size_t)token * 128 + wnc + j * 16 + fg * 4);
    }
#pragma unroll
    for (int i = 0; i < 4; ++i) {
      const int token = m0 + wmt + i * 16 + fr;
      const int ns = token >> 14, p = token & 16383;
#pragma unroll
      for (int j = 0; j < 4; ++j) {
        const int ch0 = wnc + j * 16 + fg * 4;
        const f32x4 bz = *(const f32x4*)(b3 + ch0);
        f32x4 v = acc[i][j];
#pragma unroll
        for (int r = 0; r < 4; ++r) {
          v[r] += bz[r] + bf2f(scv[i][j][r]);
          outy[((size_t)(ns * 128 + ch0 + r) << 14) + p] = v[r];
          y9[i][j][r] = f2bf(v[r]);
        }
        acc[i][j] = f32x4{0.f, 0.f, 0.f, 0.f};
      }
    }
  }
  // ---- pass 2: acc = (x1*gy) @ w4
  {
    const u16* Arow  = x1 + (size_t)(m0 + wmt + fr) * 128;
    const u16* Arow2 = gy + (size_t)(m0 + wmt + fr) * 128;
    const u16* Brow  = w4b + (size_t)(wnc + fr) * 128;
    u16x8 a[4][4], a2[4][4];
#pragma unroll
    for (int ks = 0; ks < 4; ++ks) {
      const int kb = ks * 32 + fg * 8;
#pragma unroll
      for (int i = 0; i < 4; ++i) {
        a[ks][i]  = *(const u16x8*)(Arow  + (size_t)i * 16 * 128 + kb);
        a2[ks][i] = *(const u16x8*)(Arow2 + (size_t)i * 16 * 128 + kb);
      }
    }
#pragma unroll
    for (int ks = 0; ks < 4; ++ks) {
      const int kb = ks * 32 + fg * 8;
      u16x8 b_[4];
#pragma unroll
      for (int j = 0; j < 4; ++j) b_[j] = *(const u16x8*)(Brow + (size_t)j * 16 * 128 + kb);
      u16x8 am[4];
#pragma unroll
      for (int i = 0; i < 4; ++i)
#pragma unroll
        for (int j = 0; j < 8; ++j) am[i][j] = f2bf(bf2f(a[ks][i][j]) * bf2f(a2[ks][i][j]));
#pragma unroll
      for (int i = 0; i < 4; ++i)
#pragma unroll
        for (int j = 0; j < 4; ++j) acc[i][j] = mfma16(b_[j], am[i], acc[i][j]);
    }
  }
  // epilogue 2
  {
    u16x4 scv[4][4];
#pragma unroll
    for (int i = 0; i < 4; ++i) {
      const int token = m0 + wmt + i * 16 + fr;
#pragma unroll
      for (int j = 0; j < 4; ++j)
        scv[i][j] = *(const u16x4*)(x0 + (size_t)token * 128 + wnc + j * 16 + fg * 4);
    }
#pragma unroll
    for (int i = 0; i < 4; ++i) {
      const int token = m0 + wmt + i * 16 + fr;
      const int ns = token >> 14, p = token & 16383;
#pragma unroll
      for (int j = 0; j < 4; ++j) {
        const int ch0 = wnc + j * 16 + fg * 4;
        const f32x4 bz = *(const f32x4*)(b4 + ch0);
        f32x4 v = acc[i][j];
#pragma unroll
        for (int r = 0; r < 4; ++r) {
          v[r] += bz[r] + bf2f(y9[i][j][r]) + bf2f(scv[i][j][r]);
          outx[((size_t)(ns * 128 + ch0 + r) << 14) + p] = v[r];
        }
      }
    }
  }
}

// ---------------------------------------------------------------------------
extern "C" void kernel_launch(void* const* d_in, const int* in_sizes, int n_in,
                              void* d_out, int out_size, void* d_ws, size_t ws_size,
                              hipStream_t stream) {
  (void)in_sizes; (void)n_in; (void)out_size; (void)ws_size;
  const float* xf   = (const float*)d_in[0];
  const float* yf   = (const float*)d_in[1];
  const float* wtf  = (const float*)d_in[2];
  const float* btf  = (const float*)d_in[3];
  const float* wc1f = (const float*)d_in[4];
  const float* bc1f = (const float*)d_in[5];
  const float* wc2f = (const float*)d_in[6];
  const float* bc2f = (const float*)d_in[7];
  const float* wl1f = (const float*)d_in[8];
  const float* bl1f = (const float*)d_in[9];
  const float* wl2f = (const float*)d_in[10];
  const float* bl2f = (const float*)d_in[11];
  const float* wl3f = (const float*)d_in[12];
  const float* bl3f = (const float*)d_in[13];
  const float* wl4f = (const float*)d_in[14];
  const float* bl4f = (const float*)d_in[15];
  const float* g1w1 = (const float*)d_in[16];
  const float* g1b1 = (const float*)d_in[17];
  const float* g1w2 = (const float*)d_in[18];
  const float* g1b2 = (const float*)d_in[19];
  const float* g1w3 = (const float*)d_in[20];
  const float* g1b3 = (const float*)d_in[21];
  const float* g1w4 = (const float*)d_in[22];
  const float* g1b4 = (const float*)d_in[23];
  const float* g2w1 = (const float*)d_in[24];
  const float* g2b1 = (const float*)d_in[25];
  const float* g2w2 = (const float*)d_in[26];
  const float* g2b2 = (const float*)d_in[27];
  const float* g2w3 = (const float*)d_in[28];
  const float* g2b3 = (const float*)d_in[29];
  const float* g2w4 = (const float*)d_in[30];
  const float* g2b4 = (const float*)d_in[31];

  constexpr int T16 = 16777216;
  u16* WS  = (u16*)d_ws;
  u16* x0b = WS;
  u16* x1b = WS + (size_t)T16;
  u16* y0b = WS + (size_t)2 * T16;
  u16* y1b = WS + (size_t)3 * T16;
  u16* gyb = WS + (size_t)4 * T16;
  u16* gxb = WS + (size_t)5 * T16;
  float* fb = (float*)(WS + (size_t)6 * T16);
  float* cs = fb;                    // [0]=wl1 [256]=wl2 [512]=g1w1 [768]=g2w1
  float* ps = fb + 1024;             // stats slots
  u16* wb   = (u16*)(fb + 1024 + 64);
  float* ps0 = ps, *ps1 = ps + 16, *ps2 = ps + 32, *ps3 = ps + 48;

  const u16* wc1b = wb;
  const u16* wc2b = wb + 16384;
  const u16* wl1b = wb + 32768;
  const u16* wl2b = wb + 49152;
  const u16* wl3b = wb + 65536;
  const u16* wl4b = wb + 81920;
  const u16* g1w1b = wb + 98304;
  const u16* g2w1b = wb + 131072;
  const u16* g1w4b = wb + 163840;
  const u16* g2w4b = wb + 196608;
  const u16* g1w2b = wb + 229376;
  const u16* g2w2b = wb + 294912;
  const u16* g1w3b = wb + 360448;
  const u16* g2w3b = wb + 425984;
  const u16* wtb   = wb + 491520;

  float* outx = (float*)d_out;
  float* outy = (float*)d_out + (size_t)T16;

  const dim3 B256(256), B512(512);

  // 1) one-shot weight prep
  prep_k<<<dim3(2437), B256, 0, stream>>>(
      wc1f, wc2f, wl1f, wl2f, wl3f, wl4f, g1w1, g2w1, g1w4, g2w4,
      g1w2, g2w2, g1w3, g2w3, wtf, wb, cs, ps);

  // 2) y0 = relu(relu(ConvT(y)+bt)@wc2+bc2)  [stats->ps1]
  gemmY2_k<<<dim3(512), B256, 0, stream>>>(yf, wtb, btf, wc2b, bc2f, y0b, ps1);
  // 3) x0 = relu(x@wc1+bc1)  [stats->ps0]
  gemmX_k<<<dim3(1024), B256, 0, stream>>>(xf, wc1b, bc1f, x0b, ps0);

  // 4) y1 = gelu(LN(y0)@wl2+bl2)  [stats->ps3]
  gemm4_k<1><<<dim3(1024), B256, 0, stream>>>(
      y0b, wl2b, bl2f, ps1, cs + 256, y1b, ps3);
  // 5) y gating -> gy  (u-half partial, then v-half completes)
  mlp3b_k<0><<<dim3(64, 8), B512, 0, stream>>>(
      y1b, g2w1b, g2b1, ps3, cs + 768, g2w2b, g2b2, g2w4b, g2b4, gyb);
  mlp3b_k<1><<<dim3(64, 8), B512, 0, stream>>>(
      y1b, g2w1b, g2b1, ps3, cs + 768, g2w3b, g2b3, g2w4b, g2b4, gyb);

  // 6) x1 = gelu(LN(x0)@wl1+bl1)  [stats->ps2]
  gemm4_k<1><<<dim3(1024), B256, 0, stream>>>(
      x0b, wl1b, bl1f, ps0, cs, x1b, ps2);
  // 7) x gating -> gx
  mlp3b_k<0><<<dim3(64, 8), B512, 0, stream>>>(
      x1b, g1w1b, g1b1, ps2, cs + 512, g1w2b, g1b2, g1w4b, g1b4, gxb);
  mlp3b_k<1><<<dim3(64, 8), B512, 0, stream>>>(
      x1b, g1w1b, g1b1, ps2, cs + 512, g1w3b, g1b3, g1w4b, g1b4, gxb);

  // 8) finale: y_out -> outy, x_out -> outx (fp32 NCHW)
  dual5_k<<<dim3(1024), B256, 0, stream>>>(
      y1b, gxb, x1b, gyb, wl3b, wl4b, bl3f, bl4f, y0b, x0b, outy, outx);
}